// Round 10
// baseline (550.490 us; speedup 1.0000x reference)
//
#include <hip/hip_runtime.h>

#define PI_F     3.14159265358979323846f
#define TWOPI_F  6.28318530717958647692f
#define HPI_F    1.57079632679489661923f

constexpr int fftT(int N){ return N>=512 ? 256 : (N/2 < 64 ? 64 : N/2); }

// S-slot layout (doubles), replicated REP times (replica stride SL_TOT)
#define SL_ACE 340          // 16 x 41
#define SL_ACR 996          // 4 x 41
#define SL_ALP 1160         // 41
#define SL_TOT 1280
#define REP 8

__device__ __forceinline__ float fcoord(int k, int n){
  int s = k ^ (n>>1);
  return (float)(s - (n>>1)) / (float)(n>>1);
}
__device__ __forceinline__ float lograd(int kr, int kc, int n){
  if (kr==0 && kc==0) return log2f(2.0f/(float)n);
  float x = fcoord(kc,n), y = fcoord(kr,n);
  return 0.5f*log2f(x*x+y*y);
}
__device__ __forceinline__ float rc_sin(float lr, float shift){
  float t = fminf(fmaxf(lr+shift,0.f),1.f); return __sinf(HPI_F*t);
}
__device__ __forceinline__ float rc_cos(float lr, float shift){
  float t = fminf(fmaxf(lr+shift,0.f),1.f); return __cosf(HPI_F*t);
}
// cumulative lowpass mask to reach scale s: prod_{m=0..s} rc_cos(lr, 1-m)
__device__ __forceinline__ float cumlo(float lr, int s){
  float cl = rc_cos(lr, 1.f);
  for (int m=1;m<=s;m++) cl *= rc_cos(lr, 1.f-(float)m);
  return cl;
}
__device__ __forceinline__ float bandang(float ang, int b){
  float th = ang - 0.25f*PI_F*(float)b;
  float u = th + PI_F;
  u -= TWOPI_F*floorf(u*(1.0f/TWOPI_F));
  float thw = u - PI_F;
  float c = __cosf(th);
  return (fabsf(thw) < HPI_F) ? (1.7888543819998317f*c*c*c) : 0.0f;
}
__device__ __forceinline__ int lagIdx(int di, int dj){
  if (dj < 0 || (dj==0 && di<0)){ di=-di; dj=-dj; }
  return dj==0 ? 36+di : (dj-1)*9 + (di+4);
}
__device__ __forceinline__ void atomAddD(double* p, double v){
  unsafeAtomicAdd(p, v);
}
template<int NS>
__device__ __forceinline__ void blockAccumN(double* base, const float* vals, float* red){
  const int lane = threadIdx.x & 63, wid = threadIdx.x >> 6;
  const int nw = (int)(blockDim.x >> 6);
  #pragma unroll
  for (int k=0;k<NS;k++){
    float v = vals[k];
    #pragma unroll
    for (int o=32;o>0;o>>=1) v += __shfl_down(v,o);
    if (lane==0) red[k*nw+wid]=v;
  }
  __syncthreads();
  const int rep = (int)((blockIdx.x ^ (blockIdx.y<<1) ^ (blockIdx.z<<2)) & 7) * SL_TOT;
  if ((int)threadIdx.x < NS){
    float s=0.f;
    for (int w2=0;w2<nw;w2++) s += red[(int)threadIdx.x*nw+w2];
    atomAddD(base+rep+(int)threadIdx.x,(double)s);
  }
  __syncthreads();
}

// ---------------- batched descriptor FFT -------------------------------------
// pre: 0 cplx slab, 1 real row, 3 him from F, 4 hi0 from F, 6 padlp from F,
//      7 bands-multi from F (nb bands, mask cache reuse), 8 padband-multi from F
// post: 0 store (band-offset), 1 sum|x|,x^2, 2 store(re,mag)+summag,
//       3 store+moments, 4 parentred
struct ImgD { const float2* src; float2* dst; double* slots; int pre, post, b, ss; float scale; int nb; };
struct BArgs { ImgD img[6]; const float* rsrc; const float2* F; const float2* aux; float dirsign; };

#define TWI(k) ((k)+((k)>>4))

template<int N>
__global__ __launch_bounds__(fftT(N)) void k_fftB(BArgs a){
  constexpr int T = fftT(N);
  constexpr int LG = (N==1024)?10:(N==512)?9:(N==256)?8:(N==128)?7:6;
  constexpr int NE = N/T;
  __shared__ float2 sm[2][N];
  __shared__ float2 tw[N/2 + N/32];
  __shared__ float red[13*4];
  const ImgD d = a.img[blockIdx.y];
  const int row = blockIdx.x, tid = threadIdx.x;
  bool zrow=false;

  for (int k=tid;k<N/2;k+=T){
    float sn,cs; __sincosf(TWOPI_F*(float)k/(float)N,&sn,&cs);
    tw[TWI(k)]=make_float2(cs,sn);
  }

  const int NB = (d.pre==7 || d.pre==8) ? d.nb : 1;
  float2 vv[NE]; float lrm[NE]; float angv[NE];

  if (d.pre==7){
    const int KC = row + ((row < N/2)? 0 : (1024-N));
    const float2* Fr = a.F + (size_t)KC*1024;
    #pragma unroll
    for (int e=0;e<NE;e++){
      int i = tid + e*T;
      int KR = i + ((i < N/2)? 0 : (1024-N));
      float2 v = Fr[KR];
      float lr = lograd(i,row,N);
      lrm[e] = cumlo(lr,d.ss)*rc_sin(lr,2.f);
      angv[e] = atan2f(fcoord(i,N), fcoord(row,N));
      vv[e] = make_float2(-v.y, v.x);     // (-1j)^3 = +i
    }
  } else if (d.pre==8){
    constexpr int M=N/2, Q=N/4;
    const int fi = (row<Q)? row : (row>=N-Q ? row-M : -1);
    if (fi<0) zrow=true;
    else {
      const int KC = fi + ((fi < M/2)? 0 : (1024-M));
      const float2* Fr = a.F + (size_t)KC*1024;
      #pragma unroll
      for (int e=0;e<NE;e++){
        int i = tid + e*T;
        int fj = (i<Q)? i : (i>=N-Q ? i-M : -1);
        if (fj<0){ lrm[e]=0.f; angv[e]=0.f; vv[e]=make_float2(0.f,0.f); }
        else {
          int KR = fj + ((fj < M/2)? 0 : (1024-M));
          float2 v = Fr[KR];
          float lr = lograd(fj,fi,M);
          lrm[e] = cumlo(lr,d.ss+1)*rc_sin(lr,2.f);
          angv[e] = atan2f(fcoord(fj,M), fcoord(fi,M));
          vv[e] = make_float2(-v.y, v.x);
        }
      }
    }
  }

  for (int bi=0; bi<NB; ++bi){
    __syncthreads();
    // ---- load into sm[0]
    if (d.pre==7 || d.pre==8){
      if (!zrow){
        #pragma unroll
        for (int e=0;e<NE;e++){
          int i = tid + e*T;
          float m = lrm[e]*bandang(angv[e], d.b+bi);
          sm[0][i]=make_float2(vv[e].x*m, vv[e].y*m);
        }
      } else if (bi==0){
        for (int i=tid;i<N;i+=T) sm[0][i]=make_float2(0.f,0.f);
      }
    } else switch(d.pre){
      case 0: {
        const float2* sp = d.src + (size_t)row*N;
        for (int i=tid;i<N;i+=T) sm[0][i]=sp[i];
      } break;
      case 1: {
        const float* rp = a.rsrc + (size_t)row*N;
        for (int i=tid;i<N;i+=T) sm[0][i]=make_float2(rp[i],0.f);
      } break;
      case 3: {
        const int KC = row + ((row < N/2)? 0 : (1024-N));
        const float2* Fr = a.F + (size_t)KC*1024;
        for (int i=tid;i<N;i+=T){
          int KR = i + ((i < N/2)? 0 : (1024-N));
          float2 v = Fr[KR];
          float lr = lograd(i,row,N);
          float m = cumlo(lr,d.ss)*rc_sin(lr,2.f);
          sm[0][i]=make_float2(v.x*m, v.y*m);
        }
      } break;
      case 4: {
        const float2* Fr = a.F + (size_t)row*1024;
        for (int i=tid;i<N;i+=T){
          float2 v = Fr[i];
          float m = rc_sin(lograd(i,row,N),1.f);
          sm[0][i]=make_float2(v.x*m, v.y*m);
        }
      } break;
      case 6: {
        constexpr int M=N/2, Q=N/4;
        const int fi = (row<Q)? row : (row>=N-Q ? row-M : -1);
        if (fi<0){
          for (int i=tid;i<N;i+=T) sm[0][i]=make_float2(0.f,0.f);
          zrow=true;
        } else {
          const int KC = fi + ((fi < M/2)? 0 : (1024-M));
          const float2* Fr = a.F + (size_t)KC*1024;
          for (int i=tid;i<N;i+=T){
            int fj = (i<Q)? i : (i>=N-Q ? i-M : -1);
            float2 r = make_float2(0.f,0.f);
            if (fj>=0 && !(fi==0 && fj==0)){
              int KR = fj + ((fj < M/2)? 0 : (1024-M));
              float2 v = Fr[KR];
              float m = cumlo(lograd(fj,fi,M),4);
              r = make_float2(v.x*m, v.y*m);
            }
            sm[0][i]=r;
          }
        }
      } break;
    }

    int cur=0;
    if (!zrow){
      const float ds = a.dirsign;
      int ls2 = 0;
      for (; ls2+2<=LG; ls2+=2){
        const int Ns = 1<<ls2;
        __syncthreads();
        for (int j=tid; j<N/4; j+=T){
          const int m = j & (Ns-1);
          const int base = ((j>>ls2)<<(ls2+2)) + m;
          float2 x0 = sm[cur][j];
          float2 x1 = sm[cur][j+N/4];
          float2 x2 = sm[cur][j+N/2];
          float2 x3 = sm[cur][j+3*(N/4)];
          float2 w = tw[TWI(m<<(LG-2-ls2))];
          float w1x=w.x, w1y=ds*w.y;
          float w2x = w1x*w1x - w1y*w1y, w2y = 2.f*w1x*w1y;
          float w3x = w2x*w1x - w2y*w1y, w3y = w2x*w1y + w2y*w1x;
          float2 b = make_float2(x1.x*w1x - x1.y*w1y, x1.x*w1y + x1.y*w1x);
          float2 c = make_float2(x2.x*w2x - x2.y*w2y, x2.x*w2y + x2.y*w2x);
          float2 e = make_float2(x3.x*w3x - x3.y*w3y, x3.x*w3y + x3.y*w3x);
          float t0x=x0.x+c.x, t0y=x0.y+c.y;
          float t1x=x0.x-c.x, t1y=x0.y-c.y;
          float t2x=b.x+e.x,  t2y=b.y+e.y;
          float t3x=b.x-e.x,  t3y=b.y-e.y;
          float rtx=-ds*t3y,  rty=ds*t3x;
          sm[cur^1][base]          = make_float2(t0x+t2x, t0y+t2y);
          sm[cur^1][base+Ns]       = make_float2(t1x+rtx, t1y+rty);
          sm[cur^1][base+2*Ns]     = make_float2(t0x-t2x, t0y-t2y);
          sm[cur^1][base+3*Ns]     = make_float2(t1x-rtx, t1y-rty);
        }
        cur ^= 1;
      }
      if (LG & 1){
        const int ls = LG-1, Ns = 1<<ls;
        __syncthreads();
        for (int j=tid; j<N/2; j+=T){
          const int m = j & (Ns-1);
          const int base = ((j>>ls)<<(ls+1)) + m;
          float2 va = sm[cur][j];
          float2 vb = sm[cur][j+N/2];
          float2 w = tw[TWI(m)];
          float wy = ds*w.y;
          float2 bw = make_float2(vb.x*w.x - vb.y*wy, vb.x*wy + vb.y*w.x);
          sm[cur^1][base]    = make_float2(va.x+bw.x, va.y+bw.y);
          sm[cur^1][base+Ns] = make_float2(va.x-bw.x, va.y-bw.y);
        }
        cur ^= 1;
      }
    }
    __syncthreads();

    const float sc = d.scale;
    switch(d.post){
      case 0: {
        float2* dp = d.dst + (size_t)bi*N*N + (size_t)row*N;
        for (int i=tid;i<N;i+=T){ float2 v=sm[cur][i]; dp[i]=make_float2(v.x*sc,v.y*sc); }
      } break;
      case 1: {
        float a1=0.f,a2=0.f;
        for (int i=tid;i<N;i+=T){ float v=sm[cur][i].x*sc; a1+=fabsf(v); a2+=v*v; }
        float vals[2]={a1,a2};
        blockAccumN<2>(d.slots, vals, red);
      } break;
      case 2: {   // store (re, mag)
        float2* dp = d.dst + (size_t)row*N;
        float am=0.f;
        for (int i=tid;i<N;i+=T){
          float2 v=sm[cur][i]; v.x*=sc; v.y*=sc;
          float m = sqrtf(v.x*v.x+v.y*v.y);
          dp[i]=make_float2(v.x, m);
          am += m;
        }
        float vals[1]={am};
        blockAccumN<1>(d.slots, vals, red);
      } break;
      case 3: {
        float2* dp = d.dst + (size_t)row*N;
        float s2=0.f,s3=0.f,s4=0.f;
        for (int i=tid;i<N;i+=T){
          float2 v=sm[cur][i]; v.x*=sc; v.y*=sc; dp[i]=v;
          float x=v.x, x2=x*x; s2+=x2; s3+=x2*x; s4+=x2*x2;
        }
        float vals[3]={s2,s3,s4};
        blockAccumN<3>(d.slots, vals, red);
      } break;
      case 4: {   // parent reduction; aux bands hold (re, mag)
        const float2* B = a.aux;
        constexpr size_t N2 = (size_t)N*N;
        float acc[13];
        #pragma unroll
        for (int k=0;k<13;k++) acc[k]=0.f;
        for (int i=tid;i<N;i+=T){
          float2 p=sm[cur][i]; p.x*=sc; p.y*=sc;
          float m = sqrtf(p.x*p.x+p.y*p.y);
          float rp=0.f, ip=0.f;
          if (m>0.f){ rp=(p.y*p.y-p.x*p.x)/m; ip=2.f*p.x*p.y/m; }
          size_t pos = (size_t)row*N + i;
          acc[0]+=m;
          #pragma unroll
          for (int k=0;k<4;k++){
            float2 z = B[k*N2+pos];
            acc[1+k]+=z.y*m; acc[5+k]+=z.x*rp; acc[9+k]+=z.x*ip;
          }
        }
        blockAccumN<13>(d.slots, acc, red);
      } break;
    }
  }
}

// multi-base in-place batched square transpose
struct TArgs { float2* base[6]; int n; };
__global__ void k_trip(TArgs t){
  int bi = blockIdx.x, bj = blockIdx.y;
  if (bj < bi) return;
  const int n = t.n;
  float2* img = t.base[blockIdx.z];
  __shared__ float2 t0[32][33], t1[32][33];
  int r0=bi*32, c0=bj*32;
  for (int dy=threadIdx.y; dy<32; dy+=8){
    t0[dy][threadIdx.x] = img[(size_t)(r0+dy)*n + c0 + threadIdx.x];
    if (bi!=bj) t1[dy][threadIdx.x] = img[(size_t)(c0+dy)*n + r0 + threadIdx.x];
  }
  __syncthreads();
  for (int dy=threadIdx.y; dy<32; dy+=8){
    img[(size_t)(c0+dy)*n + r0 + threadIdx.x] = t0[threadIdx.x][dy];
    if (bi!=bj) img[(size_t)(r0+dy)*n + c0 + threadIdx.x] = t1[threadIdx.x][dy];
  }
}

// multi-base direct circular autocorrelation (41 unique 9x9 lags)
// thread owns 2 adjacent columns x 8 rows; float2 (8B-aligned) LDS reads
// z==5: fused gram (global grid-stride, 20 products over 4 (re,mag) slabs)
struct AArgs { const float2* base[6]; double* slots[6]; int n, lgn, nmag; };
__global__ __launch_bounds__(256) void k_ac(AArgs a){
  __shared__ float red[41*4];
  __shared__ __align__(16) float t[72][74];
  const int z = blockIdx.z;
  const int n = a.n;
  if (z==5){
    const float2* B = a.base[5];
    const size_t n2 = (size_t)n*n;
    float p[20];
    #pragma unroll
    for (int i=0;i<20;i++) p[i]=0.f;
    const size_t nbk = (size_t)gridDim.x*gridDim.y;
    const size_t bid = (size_t)blockIdx.y*gridDim.x + blockIdx.x;
    for (size_t i = bid*256 + threadIdx.x; i<n2; i += nbk*256){
      float2 z0=B[i], z1=B[i+n2], z2=B[i+2*n2], z3=B[i+3*n2];
      float m0=z0.y, m1=z1.y, m2=z2.y, m3=z3.y;
      float r0=z0.x, r1=z1.x, r2=z2.x, r3=z3.x;
      p[0]+=m0*m0; p[1]+=m0*m1; p[2]+=m0*m2; p[3]+=m0*m3;
      p[4]+=m1*m1; p[5]+=m1*m2; p[6]+=m1*m3;
      p[7]+=m2*m2; p[8]+=m2*m3; p[9]+=m3*m3;
      p[10]+=r0*r0; p[11]+=r0*r1; p[12]+=r0*r2; p[13]+=r0*r3;
      p[14]+=r1*r1; p[15]+=r1*r2; p[16]+=r1*r3;
      p[17]+=r2*r2; p[18]+=r2*r3; p[19]+=r3*r3;
    }
    blockAccumN<20>(a.slots[5], p, red);
    return;
  }
  const float2* img = a.base[z];
  const bool mag = z < a.nmag;
  const int lgn = a.lgn;
  const int ty0 = blockIdx.y*64, tx0 = blockIdx.x*64;
  for (int idx = threadIdx.x; idx < 72*72; idx += 256){
    int ly = idx/72, lx = idx-ly*72;
    int gy = (ty0 + ly - 4) & (n-1), gx = (tx0 + lx - 4) & (n-1);
    float2 v = img[((size_t)gy<<lgn) + gx];
    t[ly][lx] = mag ? v.y : v.x;
  }
  __syncthreads();
  float acc[41];
  #pragma unroll
  for (int k=0;k<41;k++) acc[k]=0.f;
  const int c  = threadIdx.x & 31;
  const int rg = threadIdx.x >> 5;
  const int x0 = 4 + 2*c;
  #pragma unroll
  for (int k=0;k<8;k++){
    const int y = 4 + rg + 8*k;
    const float2 c2 = *(const float2*)&t[y][x0];
    #pragma unroll
    for (int di=-4; di<=4; ++di){
      const float* rp = &t[y+di][x0];
      const float2 ra  = *(const float2*)rp;
      const float2 rb  = *(const float2*)(rp+2);
      const float2 rc2 = *(const float2*)(rp+4);
      const float r0=ra.x, r1=ra.y, r2=rb.x, r3=rb.y, r4=rc2.x, r5=rc2.y;
      if (di>=0) acc[36+di] += c2.x*r0 + c2.y*r1;
      acc[di+4]      += c2.x*r1 + c2.y*r2;
      acc[9+di+4]    += c2.x*r2 + c2.y*r3;
      acc[18+di+4]   += c2.x*r3 + c2.y*r4;
      acc[27+di+4]   += c2.x*r4 + c2.y*r5;
    }
  }
  blockAccumN<41>(a.slots[z], acc, red);
}

// ---------------- misc kernels ----------------------------------------------
__global__ void k_init(double* S, float* out, int nout){
  int i = blockIdx.x*blockDim.x + threadIdx.x;
  if (i < REP*SL_TOT) S[i]=0.0;
  if (i < nout) out[i]=0.f;
}
__global__ __launch_bounds__(256) void k_imgstats(const float4* __restrict__ x, float* PB){
  float s1=0.f,s2=0.f,s3=0.f,s4=0.f, mn=3.4e38f, mx=-3.4e38f;
  const int base = blockIdx.x*1024 + threadIdx.x;
  #pragma unroll
  for (int it=0; it<4; ++it){
    float4 v = x[base + it*256];
    float vs[4]={v.x,v.y,v.z,v.w};
    #pragma unroll
    for (int k=0;k<4;k++){
      float t=vs[k], t2=t*t;
      s1+=t; s2+=t2; s3+=t2*t; s4+=t2*t2;
      mn=fminf(mn,t); mx=fmaxf(mx,t);
    }
  }
  __shared__ float wr[6][4];
  int lane=threadIdx.x&63, wid=threadIdx.x>>6;
  float sums[4]={s1,s2,s3,s4};
  #pragma unroll
  for (int k=0;k<4;k++){
    float v=sums[k];
    for (int o=32;o>0;o>>=1) v+=__shfl_down(v,o);
    if (lane==0) wr[k][wid]=v;
  }
  { float v=mn; for (int o=32;o>0;o>>=1) v=fminf(v,__shfl_down(v,o)); if(lane==0) wr[4][wid]=v; }
  { float v=mx; for (int o=32;o>0;o>>=1) v=fmaxf(v,__shfl_down(v,o)); if(lane==0) wr[5][wid]=v; }
  __syncthreads();
  if (threadIdx.x<4)  PB[blockIdx.x*8+threadIdx.x] = wr[threadIdx.x][0]+wr[threadIdx.x][1]+wr[threadIdx.x][2]+wr[threadIdx.x][3];
  if (threadIdx.x==4) PB[blockIdx.x*8+4] = fminf(fminf(wr[4][0],wr[4][1]),fminf(wr[4][2],wr[4][3]));
  if (threadIdx.x==5) PB[blockIdx.x*8+5] = fmaxf(fmaxf(wr[5][0],wr[5][1]),fmaxf(wr[5][2],wr[5][3]));
}
__global__ void k_crx3(const float2* __restrict__ RP, const float2* __restrict__ B3, double* S){
  float a[35];
  #pragma unroll
  for (int i=0;i<35;i++) a[i]=0.f;
  int stride = gridDim.x*blockDim.x;
  for (int idx=blockIdx.x*blockDim.x+threadIdx.x; idx<16384; idx+=stride){
    int u=idx>>7, v=idx&127;
    float P0=RP[idx].x;
    float P1=RP[(u<<7) | ((v-1)&127)].x;
    float P2=RP[(u<<7) | ((v+1)&127)].x;
    float P3=RP[(((u-1)&127)<<7) | v].x;
    float P4=RP[(((u+1)&127)<<7) | v].x;
    float P[5]={P0,P1,P2,P3,P4};
    float R[4];
    #pragma unroll
    for (int b=0;b<4;b++) R[b]=B3[b*16384 + (v<<7) + u].x;
    #pragma unroll
    for (int i=0;i<4;i++)
      #pragma unroll
      for (int j=0;j<5;j++) a[i*5+j]+=R[i]*P[j];
    int k=20;
    #pragma unroll
    for (int i=0;i<5;i++)
      #pragma unroll
      for (int j=i;j<5;j++){ a[k]+=P[i]*P[j]; k++; }
  }
  __shared__ float red[35*4];
  float lo[20], hi[15];
  #pragma unroll
  for (int k=0;k<20;k++) lo[k]=a[k];
  #pragma unroll
  for (int k=0;k<15;k++) hi[k]=a[20+k];
  blockAccumN<20>(S+280, lo, red);
  blockAccumN<15>(S+300, hi, red);
}

// in-place unnormalized inverse 2D FFT in LDS, separated planes, stride S
template<int LG>
__device__ void ifft2_lds(float* re, float* im, const float2* tw, int S){
  constexpr int N=1<<LG, H=N>>1;
  const int tid=threadIdx.x, T=256;
  for (int ls=LG-1; ls>=0; --ls){
    const int h=1<<ls;
    __syncthreads();
    for (int t=tid; t<N*H; t+=T){
      int r=t>>(LG-1), j=t&(H-1);
      int m=j&(h-1);
      int i0=r*S + ((j>>ls)<<(ls+1)) + m, i1=i0+h;
      float ar=re[i0], ai=im[i0], br=re[i1], bi=im[i1];
      re[i0]=ar+br; im[i0]=ai+bi;
      float dr=ar-br, di=ai-bi;
      float2 w=tw[m<<(LG-1-ls)];
      re[i1]=dr*w.x - di*w.y;
      im[i1]=dr*w.y + di*w.x;
    }
  }
  __syncthreads();
  for (int t=tid;t<N*N;t+=T){
    int r=t>>LG, j=t&(N-1);
    int jb=(int)(__brev((unsigned)j)>>(32-LG));
    if (j<jb){
      int p=r*S+j, q=r*S+jb;
      float x=re[p]; re[p]=re[q]; re[q]=x;
      x=im[p]; im[p]=im[q]; im[q]=x;
    }
  }
  for (int ls=LG-1; ls>=0; --ls){
    const int h=1<<ls;
    __syncthreads();
    for (int t=tid; t<N*H; t+=T){
      int c=t>>(LG-1), j=t&(H-1);
      int m=j&(h-1);
      int i0=(((j>>ls)<<(ls+1))+m)*S + c, i1=i0+h*S;
      float ar=re[i0], ai=im[i0], br=re[i1], bi=im[i1];
      re[i0]=ar+br; im[i0]=ai+bi;
      float dr=ar-br, di=ai-bi;
      float2 w=tw[m<<(LG-1-ls)];
      re[i1]=dr*w.x - di*w.y;
      im[i1]=dr*w.y + di*w.x;
    }
  }
  __syncthreads();
  for (int t=tid;t<N*N;t+=T){
    int c=t>>LG, j=t&(N-1);
    int jb=(int)(__brev((unsigned)j)>>(32-LG));
    if (j<jb){
      int p=j*S+c, q=jb*S+c;
      float x=re[p]; re[p]=re[q]; re[q]=x;
      x=im[p]; im[p]=im[q]; im[q]=x;
    }
  }
  __syncthreads();
}

// fused 64x64 tail: lowpass (absdev) + imlp (moments + 41-lag AC)
__global__ __launch_bounds__(256) void k_tail64(const float2* __restrict__ F, double* S){
  __shared__ float re[64*65];
  __shared__ float im[64*65];
  __shared__ float2 tw[32];
  __shared__ float red[41*4];
  __shared__ float shmu;
  const int tid=threadIdx.x;
  const float sc=1.f/4096.f;
  for (int k=tid;k<32;k+=256){
    float sn,cs; __sincosf(TWOPI_F*(float)k/64.f,&sn,&cs);
    tw[k]=make_float2(cs,sn);
  }
  // ---- lowpass ----
  for (int t=tid;t<4096;t+=256){
    int a2=t>>6, b=t&63;
    int KR = b + ((b<32)?0:960);
    int KC = a2 + ((a2<32)?0:960);
    float2 v = F[(size_t)KC*1024+KR];
    float m = cumlo(lograd(b,a2,64),4);
    re[a2*65+b]=v.x*m; im[a2*65+b]=v.y*m;
  }
  ifft2_lds<6>(re,im,tw,65);
  {
    int lane=tid&63, wid=tid>>6;
    float s1=0.f;
    for (int t=tid;t<4096;t+=256) s1 += re[(t>>6)*65+(t&63)];
    float v=s1; for (int o=32;o>0;o>>=1) v+=__shfl_down(v,o);
    if (lane==0) red[wid]=v;
    __syncthreads();
    if (tid==0) shmu=(red[0]+red[1]+red[2]+red[3])*(sc*sc);
    __syncthreads();
    float mu=shmu, adc=0.f;
    for (int t=tid;t<4096;t+=256) adc += fabsf(re[(t>>6)*65+(t&63)]*sc - mu);
    v=adc; for (int o=32;o>0;o>>=1) v+=__shfl_down(v,o);
    if (lane==0) red[wid]=v;
    __syncthreads();
    if (tid==0) S[23]=(double)(red[0]+red[1]+red[2]+red[3]);
    __syncthreads();
  }
  // ---- imlp ----
  for (int t=tid;t<4096;t+=256){
    int a2=t>>6, b=t&63;
    int KR = b + ((b<32)?0:960);
    int KC = a2 + ((a2<32)?0:960);
    float2 v = F[(size_t)KC*1024+KR];
    float lr = lograd(b,a2,64);
    float m = cumlo(lr,4)*rc_cos(lr,1.f);
    if (t==0) m=0.f;
    re[a2*65+b]=v.x*m; im[a2*65+b]=v.y*m;
  }
  ifft2_lds<6>(re,im,tw,65);
  {
    float s2=0.f,s3=0.f,s4=0.f;
    float acc[41];
    #pragma unroll
    for (int k=0;k<41;k++) acc[k]=0.f;
    for (int p=tid;p<4096;p+=256){
      int y=p>>6, x=p&63;
      float m0u=re[y*65+x];
      float m0=m0u*sc, m02=m0*m0;
      s2+=m02; s3+=m02*m0; s4+=m02*m02;
      #pragma unroll
      for (int dj=1;dj<=4;dj++)
        #pragma unroll
        for (int di=-4;di<=4;di++)
          acc[(dj-1)*9+di+4] += m0u * re[((y+dj)&63)*65 + ((x+di)&63)];
      #pragma unroll
      for (int di=0;di<=4;di++)
        acc[36+di] += m0u * re[y*65 + ((x+di)&63)];
    }
    #pragma unroll
    for (int k=0;k<41;k++) acc[k]*=sc*sc;
    float mom[3]={s2,s3,s4};
    blockAccumN<3>(S+36, mom, red);
    blockAccumN<41>(S+SL_ALP, acc, red);
  }
}

__global__ __launch_bounds__(256) void k_final(const double* __restrict__ S,
                                               const float* __restrict__ PB, float* out){
  __shared__ double SD[SL_TOT];
  __shared__ double sh[6];
  __shared__ double wrD[4][4];
  __shared__ float  wrF[2][4];
  const int tid = threadIdx.x;
  for (int k=tid;k<SL_TOT;k+=256){
    double v=0.0;
    #pragma unroll
    for (int r=0;r<REP;r++) v += S[(size_t)r*SL_TOT+k];
    SD[k]=v;
  }
  {
    int lane=tid&63, wid=tid>>6;
    double p0=PB[tid*8+0], p1=PB[tid*8+1], p2=PB[tid*8+2], p3=PB[tid*8+3];
    float pn=PB[tid*8+4], px=PB[tid*8+5];
    for (int o=32;o>0;o>>=1){ p0+=__shfl_down(p0,o); p1+=__shfl_down(p1,o); p2+=__shfl_down(p2,o); p3+=__shfl_down(p3,o); }
    if (lane==0){ wrD[0][wid]=p0; wrD[1][wid]=p1; wrD[2][wid]=p2; wrD[3][wid]=p3; }
    { float v=pn; for (int o=32;o>0;o>>=1) v=fminf(v,__shfl_down(v,o)); if(lane==0) wrF[0][wid]=v; }
    { float v=px; for (int o=32;o>0;o>>=1) v=fmaxf(v,__shfl_down(v,o)); if(lane==0) wrF[1][wid]=v; }
    __syncthreads();
    if (tid==0){
      for (int k=0;k<4;k++) sh[k]=wrD[k][0]+wrD[k][1]+wrD[k][2]+wrD[k][3];
      sh[4]=(double)fminf(fminf(wrF[0][0],wrF[0][1]),fminf(wrF[0][2],wrF[0][3]));
      sh[5]=(double)fmaxf(fmaxf(wrF[1][0],wrF[1][1]),fmaxf(wrF[1][2],wrF[1][3]));
    }
    __syncthreads();
  }
  const double npix[4]={1048576.0,262144.0,65536.0,16384.0};
  for (int e=tid; e<81*16; e+=256){
    int w=e>>4, s=(e>>2)&3, b=e&3;
    int i=w/9, j=w-i*9;
    int k=lagIdx(i-4,j-4);
    double n2=npix[s];
    double mu=SD[6+s*4+b]/n2;
    out[24+(w*4+s)*4+b]=(float)(SD[SL_ACE+(s*4+b)*41+k]/n2 - mu*mu);
  }
  for (int e=tid; e<81*4; e+=256){
    int w=e>>2, s=e&3;
    int i=w/9, j=w-i*9;
    int k=lagIdx(i-4,j-4);
    out[1330+w*5+s]=(float)(SD[SL_ACR+s*41+k]/(2.0*npix[s]));
  }
  for (int w=tid; w<81; w+=256){
    int i=w/9, j=w-i*9;
    int k=lagIdx(i-4,j-4);
    out[1330+w*5+4]=(float)(SD[SL_ALP+k]/4096.0);
  }
  for (int e=tid; e<64; e+=256){
    int s=e>>4, i=(e>>2)&3, j=e&3;
    int a2=i<j?i:j, bb=i<j?j:i;
    int p=a2*(7-a2)/2+bb;
    double n2=npix[s];
    double Si=SD[6+s*4+i], Sj=SD[6+s*4+j];
    out[1735+(i*4+j)*5+s]=(float)((SD[40+s*20+p]-Si*Sj/n2)/n2);
    out[1879+(i*8+j)*5+s]=(float)(SD[40+s*20+10+p]/n2);
  }
  for (int e=tid; e<48; e+=256){
    int s=e>>4, j=(e>>2)&3, i=e&3;
    double n2=npix[s];
    int pb=120+(s*4+j)*13;
    double Smj=SD[pb];
    double Si=SD[6+s*4+i];
    out[1815+(i*4+j)*4+s]=(float)((SD[pb+1+i]-Si*Smj/n2)/n2);
    out[2199+(i*8+j)*4+s]=(float)(SD[pb+5+i]/n2);
    out[2199+(i*8+(j+4))*4+s]=(float)(SD[pb+9+i]/n2);
  }
  for (int e=tid; e<20; e+=256){
    int i=e/5, j=e%5;
    out[2199+(i*8+j)*4+3]=(float)(SD[280+i*5+j]/16384.0);
  }
  for (int e=tid; e<25; e+=256){
    int i=e/5, j=e%5;
    int a2=i<j?i:j, bb=i<j?j:i;
    int p=a2*(9-a2)/2+bb;
    out[1879+(i*8+j)*5+4]=(float)(SD[300+p]/4096.0);
  }
  if (tid==0){
    const double N0=1048576.0;
    double sum=sh[0], s2=sh[1], s3=sh[2], s4=sh[3];
    double mean0=sum/N0;
    double var0=(s2 - sum*mean0)/(N0-1.0);
    double m3 = s3 - 3.0*mean0*s2 + 2.0*N0*mean0*mean0*mean0;
    double m4 = s4 - 4.0*mean0*s3 + 6.0*mean0*mean0*s2 - 3.0*N0*mean0*mean0*mean0*mean0;
    out[0]=(float)mean0; out[1]=(float)var0;
    out[2]=(float)((m3/N0)/(var0*sqrt(var0)));
    out[3]=(float)((m4/N0)/(var0*var0));
    out[4]=(float)sh[4]; out[5]=(float)sh[5];
    out[6]=(float)(SD[4]/N0);
    for (int s=0;s<4;s++) for (int b=0;b<4;b++) out[7+s*4+b]=(float)(SD[6+s*4+b]/npix[s]);
    out[23]=(float)(SD[23]/4096.0);
    for (int s=0;s<4;s++){
      double n2=npix[s];
      double vari=SD[24+s*3]/(2.0*n2);
      int ok=(vari/var0>1e-6);
      out[1320+s]= ok? (float)(0.5*(SD[25+s*3]/n2)/(vari*sqrt(vari))) : 0.f;
      out[1325+s]= ok? (float)(0.5*(SD[26+s*3]/n2)/(vari*vari)) : 3.f;
    }
    { double vari=SD[36]/4096.0; int ok=(vari/var0>1e-6);
      out[1324]= ok? (float)((SD[37]/4096.0)/(vari*sqrt(vari))) : 0.f;
      out[1329]= ok? (float)((SD[38]/4096.0)/(vari*vari)) : 3.f; }
    out[2455]=(float)(SD[5]/N0);
  }
}

// ---------------- host orchestration -----------------------------------------
static void launchB(int n, int nimg, const BArgs& a, hipStream_t st){
  switch(n){
    case 1024: k_fftB<1024><<<dim3(1024,nimg),fftT(1024),0,st>>>(a); break;
    case 512:  k_fftB<512 ><<<dim3(512 ,nimg),fftT(512 ),0,st>>>(a); break;
    case 256:  k_fftB<256 ><<<dim3(256 ,nimg),fftT(256 ),0,st>>>(a); break;
    case 128:  k_fftB<128 ><<<dim3(128 ,nimg),fftT(128 ),0,st>>>(a); break;
  }
}

extern "C" void kernel_launch(void* const* d_in, const int* in_sizes, int n_in,
                              void* d_out, int out_size, void* d_ws, size_t ws_size,
                              hipStream_t stream){
  const float* im = (const float*)d_in[0];
  float* out = (float*)d_out;
  char* w = (char*)d_ws;
  float2* F   = (float2*)w;                         // 8 MB: imdft^T
  float2* CA4 = (float2*)(w + ((size_t)8<<20));     // 32 MB: 4 bands
  float2* CC  = (float2*)(w + ((size_t)40<<20));    // 8 MB: unor
  float2* CB4 = (float2*)(w + ((size_t)48<<20));    // 16 MB: hi0 / parents / rp
  size_t off = (size_t)64<<20;
  double* S = (double*)(w+off);
  float* PB = (float*)(w+off+(size_t)REP*SL_TOT*8);

  k_init<<<40,256,0,stream>>>(S,out,2456);
  k_imgstats<<<256,256,0,stream>>>((const float4*)im,PB);

  // forward fft2 -> F^T
  { BArgs a{}; a.rsrc=im; a.dirsign=-1.f;
    a.img[0]=ImgD{nullptr,F,nullptr,1,0,0,0,1.f,1};
    launchB(1024,1,a,stream); }
  { TArgs t{}; t.base[0]=F; t.n=1024;
    k_trip<<<dim3(32,32,1),dim3(32,8),0,stream>>>(t); }
  { BArgs a{}; a.dirsign=-1.f;
    a.img[0]=ImgD{F,F,nullptr,0,0,0,0,1.f,1};
    launchB(1024,1,a,stream); }

  for (int s=0;s<4;s++){
    const int n=1024>>s, nt=n/32, n2=n*n, lg=10-s;
    const float inv=1.f/(float)n;
    // pass1: bands (multi, mask-reuse) + unor (+ hi0 at s=0)
    { BArgs a{}; a.F=F; a.dirsign=1.f;
      a.img[0]=ImgD{nullptr,CA4,nullptr,7,0,0,s,inv,4};
      a.img[1]=ImgD{nullptr,CC,nullptr,3,0,0,s,inv,1};
      if (s==0) a.img[2]=ImgD{nullptr,CB4,nullptr,4,0,0,0,inv,1};
      launchB(n,(s==0)?3:2,a,stream); }
    { TArgs t{}; t.n=n;
      for (int b=0;b<4;b++) t.base[b]=CA4+(size_t)b*n2;
      t.base[4]=CC; if (s==0) t.base[5]=CB4;
      k_trip<<<dim3(nt,nt,(s==0)?6:5),dim3(32,8),0,stream>>>(t); }
    // pass2: column FFT + per-image reductions/stores
    { BArgs a{}; a.dirsign=1.f;
      for (int b=0;b<4;b++) a.img[b]=ImgD{CA4+(size_t)b*n2,CA4+(size_t)b*n2,S+6+s*4+b,0,2,0,0,inv,1};
      a.img[4]=ImgD{CC,CC,S+24+s*3,0,3,0,0,inv,1};
      if (s==0) a.img[5]=ImgD{CB4,nullptr,S+4,0,1,0,0,inv,1};
      launchB(n,(s==0)?6:5,a,stream); }
    // autocorr (bands z=0..3, unor z=4) + fused gram (z=5)
    { AArgs aa{}; aa.n=n; aa.lgn=lg; aa.nmag=4;
      for (int b=0;b<4;b++){ aa.base[b]=CA4+(size_t)b*n2; aa.slots[b]=S+SL_ACE+(size_t)(s*4+b)*41; }
      aa.base[4]=CC; aa.slots[4]=S+SL_ACR+(size_t)s*41;
      aa.base[5]=CA4; aa.slots[5]=S+40+(size_t)s*20;
      k_ac<<<dim3(n/64,n/64,6),256,0,stream>>>(aa); }
    if (s<3){
      const int nb = (s==0)? 2 : 4;
      for (int b0=0;b0<4;b0+=nb){
        { BArgs a{}; a.F=F; a.dirsign=1.f;
          a.img[0]=ImgD{nullptr,CB4,nullptr,8,0,b0,s,inv,nb};
          launchB(n,1,a,stream); }
        { TArgs t{}; t.n=n;
          for (int i=0;i<nb;i++) t.base[i]=CB4+(size_t)i*n2;
          k_trip<<<dim3(nt,nt,nb),dim3(32,8),0,stream>>>(t); }
        { BArgs a{}; a.dirsign=1.f; a.aux=CA4;
          for (int i=0;i<nb;i++) a.img[i]=ImgD{CB4+(size_t)i*n2,nullptr,S+120+(size_t)(s*4+b0+i)*13,0,4,0,0,inv,1};
          launchB(n,nb,a,stream); }
      }
    } else {
      k_tail64<<<1,256,0,stream>>>(F,S);
      { BArgs a{}; a.F=F; a.dirsign=1.f;
        a.img[0]=ImgD{nullptr,CB4,nullptr,6,0,0,4,1.f/128.f,1};
        launchB(128,1,a,stream); }
      { TArgs t{}; t.base[0]=CB4; t.n=128;
        k_trip<<<dim3(4,4,1),dim3(32,8),0,stream>>>(t); }
      { BArgs a{}; a.dirsign=1.f;
        a.img[0]=ImgD{CB4,CB4,nullptr,0,0,0,0,1.f/128.f,1};
        launchB(128,1,a,stream); }
      k_crx3<<<64,256,0,stream>>>(CB4,CA4,S);
    }
  }
  k_final<<<1,256,0,stream>>>(S,PB,out);
  (void)in_sizes; (void)n_in; (void)out_size; (void)ws_size;
}

// Round 11
// 516.259 us; speedup vs baseline: 1.0663x; 1.0663x over previous
//
#include <hip/hip_runtime.h>

#define PI_F     3.14159265358979323846f
#define TWOPI_F  6.28318530717958647692f
#define HPI_F    1.57079632679489661923f

constexpr int fftT(int N){ return N>=512 ? 256 : (N/2 < 64 ? 64 : N/2); }

// S-slot layout (doubles), replicated REP times (replica stride SL_TOT)
#define SL_ACE 340          // 16 x 41
#define SL_ACR 996          // 4 x 41
#define SL_ALP 1160         // 41
#define SL_TOT 1280
#define REP 8

__device__ __forceinline__ float fcoord(int k, int n){
  int s = k ^ (n>>1);
  return (float)(s - (n>>1)) / (float)(n>>1);
}
__device__ __forceinline__ float lograd(int kr, int kc, int n){
  if (kr==0 && kc==0) return log2f(2.0f/(float)n);
  float x = fcoord(kc,n), y = fcoord(kr,n);
  return 0.5f*log2f(x*x+y*y);
}
__device__ __forceinline__ float rc_sin(float lr, float shift){
  float t = fminf(fmaxf(lr+shift,0.f),1.f); return __sinf(HPI_F*t);
}
__device__ __forceinline__ float rc_cos(float lr, float shift){
  float t = fminf(fmaxf(lr+shift,0.f),1.f); return __cosf(HPI_F*t);
}
// cumulative lowpass mask to reach scale s: prod_{m=0..s} rc_cos(lr, 1-m)
__device__ __forceinline__ float cumlo(float lr, int s){
  float cl = rc_cos(lr, 1.f);
  for (int m=1;m<=s;m++) cl *= rc_cos(lr, 1.f-(float)m);
  return cl;
}
__device__ __forceinline__ float bandang(float ang, int b){
  float th = ang - 0.25f*PI_F*(float)b;
  float u = th + PI_F;
  u -= TWOPI_F*floorf(u*(1.0f/TWOPI_F));
  float thw = u - PI_F;
  float c = __cosf(th);
  return (fabsf(thw) < HPI_F) ? (1.7888543819998317f*c*c*c) : 0.0f;
}
__device__ __forceinline__ int lagIdx(int di, int dj){
  if (dj < 0 || (dj==0 && di<0)){ di=-di; dj=-dj; }
  return dj==0 ? 36+di : (dj-1)*9 + (di+4);
}
__device__ __forceinline__ void atomAddD(double* p, double v){
  unsafeAtomicAdd(p, v);
}
template<int NS>
__device__ __forceinline__ void blockAccumN(double* base, const float* vals, float* red){
  const int lane = threadIdx.x & 63, wid = threadIdx.x >> 6;
  const int nw = (int)(blockDim.x >> 6);
  #pragma unroll
  for (int k=0;k<NS;k++){
    float v = vals[k];
    #pragma unroll
    for (int o=32;o>0;o>>=1) v += __shfl_down(v,o);
    if (lane==0) red[k*nw+wid]=v;
  }
  __syncthreads();
  const int rep = (int)((blockIdx.x ^ (blockIdx.y<<1) ^ (blockIdx.z<<2)) & 7) * SL_TOT;
  if ((int)threadIdx.x < NS){
    float s=0.f;
    for (int w2=0;w2<nw;w2++) s += red[(int)threadIdx.x*nw+w2];
    atomAddD(base+rep+(int)threadIdx.x,(double)s);
  }
  __syncthreads();
}

// ---------------- batched descriptor FFT -------------------------------------
// pre: 0 cplx slab, 1 real row, 3 him from F, 4 hi0 from F, 6 padlp from F,
//      7 bands-multi from F (nb bands, mask cache reuse), 8 padband-multi from F
// post: 0 store (band-offset), 1 sum|x|,x^2, 2 store(re,mag)+summag,
//       3 store+moments, 4 parentred
struct ImgD { const float2* src; float2* dst; double* slots; int pre, post, b, ss; float scale; int nb; };
struct BArgs { ImgD img[6]; const float* rsrc; const float2* F; const float2* aux; float dirsign; };

#define TWI(k) ((k)+((k)>>4))

template<int N>
__global__ __launch_bounds__(fftT(N)) void k_fftB(BArgs a){
  constexpr int T = fftT(N);
  constexpr int LG = (N==1024)?10:(N==512)?9:(N==256)?8:(N==128)?7:6;
  constexpr int NE = N/T;
  __shared__ float2 sm[2][N];
  __shared__ float2 tw[N/2 + N/32];
  __shared__ float red[13*4];
  const ImgD d = a.img[blockIdx.y];
  const int row = blockIdx.x, tid = threadIdx.x;
  bool zrow=false;

  for (int k=tid;k<N/2;k+=T){
    float sn,cs; __sincosf(TWOPI_F*(float)k/(float)N,&sn,&cs);
    tw[TWI(k)]=make_float2(cs,sn);
  }

  const int NB = (d.pre==7 || d.pre==8) ? d.nb : 1;
  float2 vv[NE]; float lrm[NE]; float angv[NE];

  if (d.pre==7){
    const int KC = row + ((row < N/2)? 0 : (1024-N));
    const float2* Fr = a.F + (size_t)KC*1024;
    #pragma unroll
    for (int e=0;e<NE;e++){
      int i = tid + e*T;
      int KR = i + ((i < N/2)? 0 : (1024-N));
      float2 v = Fr[KR];
      float lr = lograd(i,row,N);
      lrm[e] = cumlo(lr,d.ss)*rc_sin(lr,2.f);
      angv[e] = atan2f(fcoord(i,N), fcoord(row,N));
      vv[e] = make_float2(-v.y, v.x);     // (-1j)^3 = +i
    }
  } else if (d.pre==8){
    constexpr int M=N/2, Q=N/4;
    const int fi = (row<Q)? row : (row>=N-Q ? row-M : -1);
    if (fi<0) zrow=true;
    else {
      const int KC = fi + ((fi < M/2)? 0 : (1024-M));
      const float2* Fr = a.F + (size_t)KC*1024;
      #pragma unroll
      for (int e=0;e<NE;e++){
        int i = tid + e*T;
        int fj = (i<Q)? i : (i>=N-Q ? i-M : -1);
        if (fj<0){ lrm[e]=0.f; angv[e]=0.f; vv[e]=make_float2(0.f,0.f); }
        else {
          int KR = fj + ((fj < M/2)? 0 : (1024-M));
          float2 v = Fr[KR];
          float lr = lograd(fj,fi,M);
          lrm[e] = cumlo(lr,d.ss+1)*rc_sin(lr,2.f);
          angv[e] = atan2f(fcoord(fj,M), fcoord(fi,M));
          vv[e] = make_float2(-v.y, v.x);
        }
      }
    }
  }

  for (int bi=0; bi<NB; ++bi){
    __syncthreads();
    // ---- load into sm[0]
    if (d.pre==7 || d.pre==8){
      if (!zrow){
        #pragma unroll
        for (int e=0;e<NE;e++){
          int i = tid + e*T;
          float m = lrm[e]*bandang(angv[e], d.b+bi);
          sm[0][i]=make_float2(vv[e].x*m, vv[e].y*m);
        }
      } else if (bi==0){
        for (int i=tid;i<N;i+=T) sm[0][i]=make_float2(0.f,0.f);
      }
    } else switch(d.pre){
      case 0: {
        const float2* sp = d.src + (size_t)row*N;
        for (int i=tid;i<N;i+=T) sm[0][i]=sp[i];
      } break;
      case 1: {
        const float* rp = a.rsrc + (size_t)row*N;
        for (int i=tid;i<N;i+=T) sm[0][i]=make_float2(rp[i],0.f);
      } break;
      case 3: {
        const int KC = row + ((row < N/2)? 0 : (1024-N));
        const float2* Fr = a.F + (size_t)KC*1024;
        for (int i=tid;i<N;i+=T){
          int KR = i + ((i < N/2)? 0 : (1024-N));
          float2 v = Fr[KR];
          float lr = lograd(i,row,N);
          float m = cumlo(lr,d.ss)*rc_sin(lr,2.f);
          sm[0][i]=make_float2(v.x*m, v.y*m);
        }
      } break;
      case 4: {
        const float2* Fr = a.F + (size_t)row*1024;
        for (int i=tid;i<N;i+=T){
          float2 v = Fr[i];
          float m = rc_sin(lograd(i,row,N),1.f);
          sm[0][i]=make_float2(v.x*m, v.y*m);
        }
      } break;
      case 6: {
        constexpr int M=N/2, Q=N/4;
        const int fi = (row<Q)? row : (row>=N-Q ? row-M : -1);
        if (fi<0){
          for (int i=tid;i<N;i+=T) sm[0][i]=make_float2(0.f,0.f);
          zrow=true;
        } else {
          const int KC = fi + ((fi < M/2)? 0 : (1024-M));
          const float2* Fr = a.F + (size_t)KC*1024;
          for (int i=tid;i<N;i+=T){
            int fj = (i<Q)? i : (i>=N-Q ? i-M : -1);
            float2 r = make_float2(0.f,0.f);
            if (fj>=0 && !(fi==0 && fj==0)){
              int KR = fj + ((fj < M/2)? 0 : (1024-M));
              float2 v = Fr[KR];
              float m = cumlo(lograd(fj,fi,M),4);
              r = make_float2(v.x*m, v.y*m);
            }
            sm[0][i]=r;
          }
        }
      } break;
    }

    int cur=0;
    if (!zrow){
      const float ds = a.dirsign;
      int ls2 = 0;
      for (; ls2+2<=LG; ls2+=2){
        const int Ns = 1<<ls2;
        __syncthreads();
        for (int j=tid; j<N/4; j+=T){
          const int m = j & (Ns-1);
          const int base = ((j>>ls2)<<(ls2+2)) + m;
          float2 x0 = sm[cur][j];
          float2 x1 = sm[cur][j+N/4];
          float2 x2 = sm[cur][j+N/2];
          float2 x3 = sm[cur][j+3*(N/4)];
          float2 w = tw[TWI(m<<(LG-2-ls2))];
          float w1x=w.x, w1y=ds*w.y;
          float w2x = w1x*w1x - w1y*w1y, w2y = 2.f*w1x*w1y;
          float w3x = w2x*w1x - w2y*w1y, w3y = w2x*w1y + w2y*w1x;
          float2 b = make_float2(x1.x*w1x - x1.y*w1y, x1.x*w1y + x1.y*w1x);
          float2 c = make_float2(x2.x*w2x - x2.y*w2y, x2.x*w2y + x2.y*w2x);
          float2 e = make_float2(x3.x*w3x - x3.y*w3y, x3.x*w3y + x3.y*w3x);
          float t0x=x0.x+c.x, t0y=x0.y+c.y;
          float t1x=x0.x-c.x, t1y=x0.y-c.y;
          float t2x=b.x+e.x,  t2y=b.y+e.y;
          float t3x=b.x-e.x,  t3y=b.y-e.y;
          float rtx=-ds*t3y,  rty=ds*t3x;
          sm[cur^1][base]          = make_float2(t0x+t2x, t0y+t2y);
          sm[cur^1][base+Ns]       = make_float2(t1x+rtx, t1y+rty);
          sm[cur^1][base+2*Ns]     = make_float2(t0x-t2x, t0y-t2y);
          sm[cur^1][base+3*Ns]     = make_float2(t1x-rtx, t1y-rty);
        }
        cur ^= 1;
      }
      if (LG & 1){
        const int ls = LG-1, Ns = 1<<ls;
        __syncthreads();
        for (int j=tid; j<N/2; j+=T){
          const int m = j & (Ns-1);
          const int base = ((j>>ls)<<(ls+1)) + m;
          float2 va = sm[cur][j];
          float2 vb = sm[cur][j+N/2];
          float2 w = tw[TWI(m)];
          float wy = ds*w.y;
          float2 bw = make_float2(vb.x*w.x - vb.y*wy, vb.x*wy + vb.y*w.x);
          sm[cur^1][base]    = make_float2(va.x+bw.x, va.y+bw.y);
          sm[cur^1][base+Ns] = make_float2(va.x-bw.x, va.y-bw.y);
        }
        cur ^= 1;
      }
    }
    __syncthreads();

    const float sc = d.scale;
    switch(d.post){
      case 0: {
        float2* dp = d.dst + (size_t)bi*N*N + (size_t)row*N;
        for (int i=tid;i<N;i+=T){ float2 v=sm[cur][i]; dp[i]=make_float2(v.x*sc,v.y*sc); }
      } break;
      case 1: {
        float a1=0.f,a2=0.f;
        for (int i=tid;i<N;i+=T){ float v=sm[cur][i].x*sc; a1+=fabsf(v); a2+=v*v; }
        float vals[2]={a1,a2};
        blockAccumN<2>(d.slots, vals, red);
      } break;
      case 2: {   // store (re, mag)
        float2* dp = d.dst + (size_t)row*N;
        float am=0.f;
        for (int i=tid;i<N;i+=T){
          float2 v=sm[cur][i]; v.x*=sc; v.y*=sc;
          float m = sqrtf(v.x*v.x+v.y*v.y);
          dp[i]=make_float2(v.x, m);
          am += m;
        }
        float vals[1]={am};
        blockAccumN<1>(d.slots, vals, red);
      } break;
      case 3: {
        float2* dp = d.dst + (size_t)row*N;
        float s2=0.f,s3=0.f,s4=0.f;
        for (int i=tid;i<N;i+=T){
          float2 v=sm[cur][i]; v.x*=sc; v.y*=sc; dp[i]=v;
          float x=v.x, x2=x*x; s2+=x2; s3+=x2*x; s4+=x2*x2;
        }
        float vals[3]={s2,s3,s4};
        blockAccumN<3>(d.slots, vals, red);
      } break;
      case 4: {   // parent reduction; aux bands hold (re, mag)
        const float2* B = a.aux;
        constexpr size_t N2 = (size_t)N*N;
        float acc[13];
        #pragma unroll
        for (int k=0;k<13;k++) acc[k]=0.f;
        for (int i=tid;i<N;i+=T){
          float2 p=sm[cur][i]; p.x*=sc; p.y*=sc;
          float m = sqrtf(p.x*p.x+p.y*p.y);
          float rp=0.f, ip=0.f;
          if (m>0.f){ rp=(p.y*p.y-p.x*p.x)/m; ip=2.f*p.x*p.y/m; }
          size_t pos = (size_t)row*N + i;
          acc[0]+=m;
          #pragma unroll
          for (int k=0;k<4;k++){
            float2 z = B[k*N2+pos];
            acc[1+k]+=z.y*m; acc[5+k]+=z.x*rp; acc[9+k]+=z.x*ip;
          }
        }
        blockAccumN<13>(d.slots, acc, red);
      } break;
    }
  }
}

// multi-base in-place batched square transpose
struct TArgs { float2* base[6]; int n; };
__global__ void k_trip(TArgs t){
  int bi = blockIdx.x, bj = blockIdx.y;
  if (bj < bi) return;
  const int n = t.n;
  float2* img = t.base[blockIdx.z];
  __shared__ float2 t0[32][33], t1[32][33];
  int r0=bi*32, c0=bj*32;
  for (int dy=threadIdx.y; dy<32; dy+=8){
    t0[dy][threadIdx.x] = img[(size_t)(r0+dy)*n + c0 + threadIdx.x];
    if (bi!=bj) t1[dy][threadIdx.x] = img[(size_t)(c0+dy)*n + r0 + threadIdx.x];
  }
  __syncthreads();
  for (int dy=threadIdx.y; dy<32; dy+=8){
    img[(size_t)(c0+dy)*n + r0 + threadIdx.x] = t0[threadIdx.x][dy];
    if (bi!=bj) img[(size_t)(r0+dy)*n + c0 + threadIdx.x] = t1[threadIdx.x][dy];
  }
}

// multi-base direct circular autocorrelation (41 unique 9x9 lags)
// round-6/9 proven structure: scalar reads, 40 VGPR, 7 waves/SIMD
struct AArgs { const float2* base[5]; double* slots[5]; int n, lgn, nmag; };
__global__ __launch_bounds__(256) void k_ac(AArgs a){
  __shared__ float t[72][73];
  __shared__ float red[41*4];
  const int z = blockIdx.z;
  const float2* img = a.base[z];
  const bool mag = z < a.nmag;
  const int n = a.n, lgn = a.lgn;
  const int ty0 = blockIdx.y*64, tx0 = blockIdx.x*64;
  for (int idx = threadIdx.x; idx < 72*72; idx += 256){
    int ly = idx/72, lx = idx-ly*72;
    int gy = (ty0 + ly - 4) & (n-1), gx = (tx0 + lx - 4) & (n-1);
    float2 v = img[((size_t)gy<<lgn) + gx];
    t[ly][lx] = mag ? v.y : v.x;
  }
  __syncthreads();
  float acc[41];
  #pragma unroll
  for (int k=0;k<41;k++) acc[k]=0.f;
  for (int p = threadIdx.x; p < 4096; p += 256){
    int ly = (p>>6) + 4, lx = (p&63) + 4;
    float m0 = t[ly][lx];
    #pragma unroll
    for (int dj=1; dj<=4; dj++)
      #pragma unroll
      for (int di=-4; di<=4; di++)
        acc[(dj-1)*9 + di+4] += m0 * t[ly+di][lx+dj];
    #pragma unroll
    for (int di=0; di<=4; di++)
      acc[36+di] += m0 * t[ly+di][lx];
  }
  blockAccumN<41>(a.slots[z], acc, red);
}

// ---------------- misc kernels ----------------------------------------------
__global__ void k_init(double* S, float* out, int nout){
  int i = blockIdx.x*blockDim.x + threadIdx.x;
  if (i < REP*SL_TOT) S[i]=0.0;
  if (i < nout) out[i]=0.f;
}
__global__ __launch_bounds__(256) void k_imgstats(const float4* __restrict__ x, float* PB){
  float s1=0.f,s2=0.f,s3=0.f,s4=0.f, mn=3.4e38f, mx=-3.4e38f;
  const int base = blockIdx.x*1024 + threadIdx.x;
  #pragma unroll
  for (int it=0; it<4; ++it){
    float4 v = x[base + it*256];
    float vs[4]={v.x,v.y,v.z,v.w};
    #pragma unroll
    for (int k=0;k<4;k++){
      float t=vs[k], t2=t*t;
      s1+=t; s2+=t2; s3+=t2*t; s4+=t2*t2;
      mn=fminf(mn,t); mx=fmaxf(mx,t);
    }
  }
  __shared__ float wr[6][4];
  int lane=threadIdx.x&63, wid=threadIdx.x>>6;
  float sums[4]={s1,s2,s3,s4};
  #pragma unroll
  for (int k=0;k<4;k++){
    float v=sums[k];
    for (int o=32;o>0;o>>=1) v+=__shfl_down(v,o);
    if (lane==0) wr[k][wid]=v;
  }
  { float v=mn; for (int o=32;o>0;o>>=1) v=fminf(v,__shfl_down(v,o)); if(lane==0) wr[4][wid]=v; }
  { float v=mx; for (int o=32;o>0;o>>=1) v=fmaxf(v,__shfl_down(v,o)); if(lane==0) wr[5][wid]=v; }
  __syncthreads();
  if (threadIdx.x<4)  PB[blockIdx.x*8+threadIdx.x] = wr[threadIdx.x][0]+wr[threadIdx.x][1]+wr[threadIdx.x][2]+wr[threadIdx.x][3];
  if (threadIdx.x==4) PB[blockIdx.x*8+4] = fminf(fminf(wr[4][0],wr[4][1]),fminf(wr[4][2],wr[4][3]));
  if (threadIdx.x==5) PB[blockIdx.x*8+5] = fmaxf(fmaxf(wr[5][0],wr[5][1]),fmaxf(wr[5][2],wr[5][3]));
}
__global__ void k_gram(const float2* __restrict__ B, int n2, double* slots){
  float p[20];
  #pragma unroll
  for (int i=0;i<20;i++) p[i]=0.f;
  int stride = gridDim.x*blockDim.x;
  for (int i=blockIdx.x*blockDim.x+threadIdx.x; i<n2; i+=stride){
    float2 z0=B[i], z1=B[i+(size_t)n2], z2=B[i+2*(size_t)n2], z3=B[i+3*(size_t)n2];
    float m0=z0.y, m1=z1.y, m2=z2.y, m3=z3.y;
    float r0=z0.x, r1=z1.x, r2=z2.x, r3=z3.x;
    p[0]+=m0*m0; p[1]+=m0*m1; p[2]+=m0*m2; p[3]+=m0*m3;
    p[4]+=m1*m1; p[5]+=m1*m2; p[6]+=m1*m3;
    p[7]+=m2*m2; p[8]+=m2*m3; p[9]+=m3*m3;
    p[10]+=r0*r0; p[11]+=r0*r1; p[12]+=r0*r2; p[13]+=r0*r3;
    p[14]+=r1*r1; p[15]+=r1*r2; p[16]+=r1*r3;
    p[17]+=r2*r2; p[18]+=r2*r3; p[19]+=r3*r3;
  }
  __shared__ float red[20*4];
  blockAccumN<20>(slots,p,red);
}
__global__ void k_crx3(const float2* __restrict__ RP, const float2* __restrict__ B3, double* S){
  float a[35];
  #pragma unroll
  for (int i=0;i<35;i++) a[i]=0.f;
  int stride = gridDim.x*blockDim.x;
  for (int idx=blockIdx.x*blockDim.x+threadIdx.x; idx<16384; idx+=stride){
    int u=idx>>7, v=idx&127;
    float P0=RP[idx].x;
    float P1=RP[(u<<7) | ((v-1)&127)].x;
    float P2=RP[(u<<7) | ((v+1)&127)].x;
    float P3=RP[(((u-1)&127)<<7) | v].x;
    float P4=RP[(((u+1)&127)<<7) | v].x;
    float P[5]={P0,P1,P2,P3,P4};
    float R[4];
    #pragma unroll
    for (int b=0;b<4;b++) R[b]=B3[b*16384 + (v<<7) + u].x;
    #pragma unroll
    for (int i=0;i<4;i++)
      #pragma unroll
      for (int j=0;j<5;j++) a[i*5+j]+=R[i]*P[j];
    int k=20;
    #pragma unroll
    for (int i=0;i<5;i++)
      #pragma unroll
      for (int j=i;j<5;j++){ a[k]+=P[i]*P[j]; k++; }
  }
  __shared__ float red[35*4];
  float lo[20], hi[15];
  #pragma unroll
  for (int k=0;k<20;k++) lo[k]=a[k];
  #pragma unroll
  for (int k=0;k<15;k++) hi[k]=a[20+k];
  blockAccumN<20>(S+280, lo, red);
  blockAccumN<15>(S+300, hi, red);
}

// in-place unnormalized inverse 2D FFT in LDS, separated planes, stride S
template<int LG>
__device__ void ifft2_lds(float* re, float* im, const float2* tw, int S){
  constexpr int N=1<<LG, H=N>>1;
  const int tid=threadIdx.x, T=256;
  for (int ls=LG-1; ls>=0; --ls){
    const int h=1<<ls;
    __syncthreads();
    for (int t=tid; t<N*H; t+=T){
      int r=t>>(LG-1), j=t&(H-1);
      int m=j&(h-1);
      int i0=r*S + ((j>>ls)<<(ls+1)) + m, i1=i0+h;
      float ar=re[i0], ai=im[i0], br=re[i1], bi=im[i1];
      re[i0]=ar+br; im[i0]=ai+bi;
      float dr=ar-br, di=ai-bi;
      float2 w=tw[m<<(LG-1-ls)];
      re[i1]=dr*w.x - di*w.y;
      im[i1]=dr*w.y + di*w.x;
    }
  }
  __syncthreads();
  for (int t=tid;t<N*N;t+=T){
    int r=t>>LG, j=t&(N-1);
    int jb=(int)(__brev((unsigned)j)>>(32-LG));
    if (j<jb){
      int p=r*S+j, q=r*S+jb;
      float x=re[p]; re[p]=re[q]; re[q]=x;
      x=im[p]; im[p]=im[q]; im[q]=x;
    }
  }
  for (int ls=LG-1; ls>=0; --ls){
    const int h=1<<ls;
    __syncthreads();
    for (int t=tid; t<N*H; t+=T){
      int c=t>>(LG-1), j=t&(H-1);
      int m=j&(h-1);
      int i0=(((j>>ls)<<(ls+1))+m)*S + c, i1=i0+h*S;
      float ar=re[i0], ai=im[i0], br=re[i1], bi=im[i1];
      re[i0]=ar+br; im[i0]=ai+bi;
      float dr=ar-br, di=ai-bi;
      float2 w=tw[m<<(LG-1-ls)];
      re[i1]=dr*w.x - di*w.y;
      im[i1]=dr*w.y + di*w.x;
    }
  }
  __syncthreads();
  for (int t=tid;t<N*N;t+=T){
    int c=t>>LG, j=t&(N-1);
    int jb=(int)(__brev((unsigned)j)>>(32-LG));
    if (j<jb){
      int p=j*S+c, q=jb*S+c;
      float x=re[p]; re[p]=re[q]; re[q]=x;
      x=im[p]; im[p]=im[q]; im[q]=x;
    }
  }
  __syncthreads();
}

// fused 64x64 tail: lowpass (absdev) + imlp (moments + 41-lag AC)
__global__ __launch_bounds__(256) void k_tail64(const float2* __restrict__ F, double* S){
  __shared__ float re[64*65];
  __shared__ float im[64*65];
  __shared__ float2 tw[32];
  __shared__ float red[41*4];
  __shared__ float shmu;
  const int tid=threadIdx.x;
  const float sc=1.f/4096.f;
  for (int k=tid;k<32;k+=256){
    float sn,cs; __sincosf(TWOPI_F*(float)k/64.f,&sn,&cs);
    tw[k]=make_float2(cs,sn);
  }
  // ---- lowpass ----
  for (int t=tid;t<4096;t+=256){
    int a2=t>>6, b=t&63;
    int KR = b + ((b<32)?0:960);
    int KC = a2 + ((a2<32)?0:960);
    float2 v = F[(size_t)KC*1024+KR];
    float m = cumlo(lograd(b,a2,64),4);
    re[a2*65+b]=v.x*m; im[a2*65+b]=v.y*m;
  }
  ifft2_lds<6>(re,im,tw,65);
  {
    int lane=tid&63, wid=tid>>6;
    float s1=0.f;
    for (int t=tid;t<4096;t+=256) s1 += re[(t>>6)*65+(t&63)];
    float v=s1; for (int o=32;o>0;o>>=1) v+=__shfl_down(v,o);
    if (lane==0) red[wid]=v;
    __syncthreads();
    if (tid==0) shmu=(red[0]+red[1]+red[2]+red[3])*(sc*sc);
    __syncthreads();
    float mu=shmu, adc=0.f;
    for (int t=tid;t<4096;t+=256) adc += fabsf(re[(t>>6)*65+(t&63)]*sc - mu);
    v=adc; for (int o=32;o>0;o>>=1) v+=__shfl_down(v,o);
    if (lane==0) red[wid]=v;
    __syncthreads();
    if (tid==0) S[23]=(double)(red[0]+red[1]+red[2]+red[3]);
    __syncthreads();
  }
  // ---- imlp ----
  for (int t=tid;t<4096;t+=256){
    int a2=t>>6, b=t&63;
    int KR = b + ((b<32)?0:960);
    int KC = a2 + ((a2<32)?0:960);
    float2 v = F[(size_t)KC*1024+KR];
    float lr = lograd(b,a2,64);
    float m = cumlo(lr,4)*rc_cos(lr,1.f);
    if (t==0) m=0.f;
    re[a2*65+b]=v.x*m; im[a2*65+b]=v.y*m;
  }
  ifft2_lds<6>(re,im,tw,65);
  {
    float s2=0.f,s3=0.f,s4=0.f;
    float acc[41];
    #pragma unroll
    for (int k=0;k<41;k++) acc[k]=0.f;
    for (int p=tid;p<4096;p+=256){
      int y=p>>6, x=p&63;
      float m0u=re[y*65+x];
      float m0=m0u*sc, m02=m0*m0;
      s2+=m02; s3+=m02*m0; s4+=m02*m02;
      #pragma unroll
      for (int dj=1;dj<=4;dj++)
        #pragma unroll
        for (int di=-4;di<=4;di++)
          acc[(dj-1)*9+di+4] += m0u * re[((y+dj)&63)*65 + ((x+di)&63)];
      #pragma unroll
      for (int di=0;di<=4;di++)
        acc[36+di] += m0u * re[y*65 + ((x+di)&63)];
    }
    #pragma unroll
    for (int k=0;k<41;k++) acc[k]*=sc*sc;
    float mom[3]={s2,s3,s4};
    blockAccumN<3>(S+36, mom, red);
    blockAccumN<41>(S+SL_ALP, acc, red);
  }
}

__global__ __launch_bounds__(256) void k_final(const double* __restrict__ S,
                                               const float* __restrict__ PB, float* out){
  __shared__ double SD[SL_TOT];
  __shared__ double sh[6];
  __shared__ double wrD[4][4];
  __shared__ float  wrF[2][4];
  const int tid = threadIdx.x;
  for (int k=tid;k<SL_TOT;k+=256){
    double v=0.0;
    #pragma unroll
    for (int r=0;r<REP;r++) v += S[(size_t)r*SL_TOT+k];
    SD[k]=v;
  }
  {
    int lane=tid&63, wid=tid>>6;
    double p0=PB[tid*8+0], p1=PB[tid*8+1], p2=PB[tid*8+2], p3=PB[tid*8+3];
    float pn=PB[tid*8+4], px=PB[tid*8+5];
    for (int o=32;o>0;o>>=1){ p0+=__shfl_down(p0,o); p1+=__shfl_down(p1,o); p2+=__shfl_down(p2,o); p3+=__shfl_down(p3,o); }
    if (lane==0){ wrD[0][wid]=p0; wrD[1][wid]=p1; wrD[2][wid]=p2; wrD[3][wid]=p3; }
    { float v=pn; for (int o=32;o>0;o>>=1) v=fminf(v,__shfl_down(v,o)); if(lane==0) wrF[0][wid]=v; }
    { float v=px; for (int o=32;o>0;o>>=1) v=fmaxf(v,__shfl_down(v,o)); if(lane==0) wrF[1][wid]=v; }
    __syncthreads();
    if (tid==0){
      for (int k=0;k<4;k++) sh[k]=wrD[k][0]+wrD[k][1]+wrD[k][2]+wrD[k][3];
      sh[4]=(double)fminf(fminf(wrF[0][0],wrF[0][1]),fminf(wrF[0][2],wrF[0][3]));
      sh[5]=(double)fmaxf(fmaxf(wrF[1][0],wrF[1][1]),fmaxf(wrF[1][2],wrF[1][3]));
    }
    __syncthreads();
  }
  const double npix[4]={1048576.0,262144.0,65536.0,16384.0};
  for (int e=tid; e<81*16; e+=256){
    int w=e>>4, s=(e>>2)&3, b=e&3;
    int i=w/9, j=w-i*9;
    int k=lagIdx(i-4,j-4);
    double n2=npix[s];
    double mu=SD[6+s*4+b]/n2;
    out[24+(w*4+s)*4+b]=(float)(SD[SL_ACE+(s*4+b)*41+k]/n2 - mu*mu);
  }
  for (int e=tid; e<81*4; e+=256){
    int w=e>>2, s=e&3;
    int i=w/9, j=w-i*9;
    int k=lagIdx(i-4,j-4);
    out[1330+w*5+s]=(float)(SD[SL_ACR+s*41+k]/(2.0*npix[s]));
  }
  for (int w=tid; w<81; w+=256){
    int i=w/9, j=w-i*9;
    int k=lagIdx(i-4,j-4);
    out[1330+w*5+4]=(float)(SD[SL_ALP+k]/4096.0);
  }
  for (int e=tid; e<64; e+=256){
    int s=e>>4, i=(e>>2)&3, j=e&3;
    int a2=i<j?i:j, bb=i<j?j:i;
    int p=a2*(7-a2)/2+bb;
    double n2=npix[s];
    double Si=SD[6+s*4+i], Sj=SD[6+s*4+j];
    out[1735+(i*4+j)*5+s]=(float)((SD[40+s*20+p]-Si*Sj/n2)/n2);
    out[1879+(i*8+j)*5+s]=(float)(SD[40+s*20+10+p]/n2);
  }
  for (int e=tid; e<48; e+=256){
    int s=e>>4, j=(e>>2)&3, i=e&3;
    double n2=npix[s];
    int pb=120+(s*4+j)*13;
    double Smj=SD[pb];
    double Si=SD[6+s*4+i];
    out[1815+(i*4+j)*4+s]=(float)((SD[pb+1+i]-Si*Smj/n2)/n2);
    out[2199+(i*8+j)*4+s]=(float)(SD[pb+5+i]/n2);
    out[2199+(i*8+(j+4))*4+s]=(float)(SD[pb+9+i]/n2);
  }
  for (int e=tid; e<20; e+=256){
    int i=e/5, j=e%5;
    out[2199+(i*8+j)*4+3]=(float)(SD[280+i*5+j]/16384.0);
  }
  for (int e=tid; e<25; e+=256){
    int i=e/5, j=e%5;
    int a2=i<j?i:j, bb=i<j?j:i;
    int p=a2*(9-a2)/2+bb;
    out[1879+(i*8+j)*5+4]=(float)(SD[300+p]/4096.0);
  }
  if (tid==0){
    const double N0=1048576.0;
    double sum=sh[0], s2=sh[1], s3=sh[2], s4=sh[3];
    double mean0=sum/N0;
    double var0=(s2 - sum*mean0)/(N0-1.0);
    double m3 = s3 - 3.0*mean0*s2 + 2.0*N0*mean0*mean0*mean0;
    double m4 = s4 - 4.0*mean0*s3 + 6.0*mean0*mean0*s2 - 3.0*N0*mean0*mean0*mean0*mean0;
    out[0]=(float)mean0; out[1]=(float)var0;
    out[2]=(float)((m3/N0)/(var0*sqrt(var0)));
    out[3]=(float)((m4/N0)/(var0*var0));
    out[4]=(float)sh[4]; out[5]=(float)sh[5];
    out[6]=(float)(SD[4]/N0);
    for (int s=0;s<4;s++) for (int b=0;b<4;b++) out[7+s*4+b]=(float)(SD[6+s*4+b]/npix[s]);
    out[23]=(float)(SD[23]/4096.0);
    for (int s=0;s<4;s++){
      double n2=npix[s];
      double vari=SD[24+s*3]/(2.0*n2);
      int ok=(vari/var0>1e-6);
      out[1320+s]= ok? (float)(0.5*(SD[25+s*3]/n2)/(vari*sqrt(vari))) : 0.f;
      out[1325+s]= ok? (float)(0.5*(SD[26+s*3]/n2)/(vari*vari)) : 3.f;
    }
    { double vari=SD[36]/4096.0; int ok=(vari/var0>1e-6);
      out[1324]= ok? (float)((SD[37]/4096.0)/(vari*sqrt(vari))) : 0.f;
      out[1329]= ok? (float)((SD[38]/4096.0)/(vari*vari)) : 3.f; }
    out[2455]=(float)(SD[5]/N0);
  }
}

// ---------------- host orchestration -----------------------------------------
static void launchB(int n, int nimg, const BArgs& a, hipStream_t st){
  switch(n){
    case 1024: k_fftB<1024><<<dim3(1024,nimg),fftT(1024),0,st>>>(a); break;
    case 512:  k_fftB<512 ><<<dim3(512 ,nimg),fftT(512 ),0,st>>>(a); break;
    case 256:  k_fftB<256 ><<<dim3(256 ,nimg),fftT(256 ),0,st>>>(a); break;
    case 128:  k_fftB<128 ><<<dim3(128 ,nimg),fftT(128 ),0,st>>>(a); break;
  }
}

extern "C" void kernel_launch(void* const* d_in, const int* in_sizes, int n_in,
                              void* d_out, int out_size, void* d_ws, size_t ws_size,
                              hipStream_t stream){
  const float* im = (const float*)d_in[0];
  float* out = (float*)d_out;
  char* w = (char*)d_ws;
  float2* F   = (float2*)w;                         // 8 MB: imdft^T
  float2* CA4 = (float2*)(w + ((size_t)8<<20));     // 32 MB: 4 bands
  float2* CC  = (float2*)(w + ((size_t)40<<20));    // 8 MB: unor
  float2* CB4 = (float2*)(w + ((size_t)48<<20));    // 16 MB: hi0 / parents / rp
  size_t off = (size_t)64<<20;
  double* S = (double*)(w+off);
  float* PB = (float*)(w+off+(size_t)REP*SL_TOT*8);

  k_init<<<40,256,0,stream>>>(S,out,2456);
  k_imgstats<<<256,256,0,stream>>>((const float4*)im,PB);

  // forward fft2 -> F^T
  { BArgs a{}; a.rsrc=im; a.dirsign=-1.f;
    a.img[0]=ImgD{nullptr,F,nullptr,1,0,0,0,1.f,1};
    launchB(1024,1,a,stream); }
  { TArgs t{}; t.base[0]=F; t.n=1024;
    k_trip<<<dim3(32,32,1),dim3(32,8),0,stream>>>(t); }
  { BArgs a{}; a.dirsign=-1.f;
    a.img[0]=ImgD{F,F,nullptr,0,0,0,0,1.f,1};
    launchB(1024,1,a,stream); }

  for (int s=0;s<4;s++){
    const int n=1024>>s, nt=n/32, n2=n*n, lg=10-s;
    const float inv=1.f/(float)n;
    // pass1: bands (multi, mask-reuse) + unor (+ hi0 at s=0)
    { BArgs a{}; a.F=F; a.dirsign=1.f;
      a.img[0]=ImgD{nullptr,CA4,nullptr,7,0,0,s,inv,4};
      a.img[1]=ImgD{nullptr,CC,nullptr,3,0,0,s,inv,1};
      if (s==0) a.img[2]=ImgD{nullptr,CB4,nullptr,4,0,0,0,inv,1};
      launchB(n,(s==0)?3:2,a,stream); }
    { TArgs t{}; t.n=n;
      for (int b=0;b<4;b++) t.base[b]=CA4+(size_t)b*n2;
      t.base[4]=CC; if (s==0) t.base[5]=CB4;
      k_trip<<<dim3(nt,nt,(s==0)?6:5),dim3(32,8),0,stream>>>(t); }
    // pass2: column FFT + per-image reductions/stores
    { BArgs a{}; a.dirsign=1.f;
      for (int b=0;b<4;b++) a.img[b]=ImgD{CA4+(size_t)b*n2,CA4+(size_t)b*n2,S+6+s*4+b,0,2,0,0,inv,1};
      a.img[4]=ImgD{CC,CC,S+24+s*3,0,3,0,0,inv,1};
      if (s==0) a.img[5]=ImgD{CB4,nullptr,S+4,0,1,0,0,inv,1};
      launchB(n,(s==0)?6:5,a,stream); }
    k_gram<<<256,256,0,stream>>>(CA4,n2,S+40+s*20);
    { AArgs aa{}; aa.n=n; aa.lgn=lg; aa.nmag=4;
      for (int b=0;b<4;b++){ aa.base[b]=CA4+(size_t)b*n2; aa.slots[b]=S+SL_ACE+(size_t)(s*4+b)*41; }
      aa.base[4]=CC; aa.slots[4]=S+SL_ACR+(size_t)s*41;
      k_ac<<<dim3(n/64,n/64,5),256,0,stream>>>(aa); }
    if (s<3){
      const int nb = (s==0)? 2 : 4;
      for (int b0=0;b0<4;b0+=nb){
        { BArgs a{}; a.F=F; a.dirsign=1.f;
          a.img[0]=ImgD{nullptr,CB4,nullptr,8,0,b0,s,inv,nb};
          launchB(n,1,a,stream); }
        { TArgs t{}; t.n=n;
          for (int i=0;i<nb;i++) t.base[i]=CB4+(size_t)i*n2;
          k_trip<<<dim3(nt,nt,nb),dim3(32,8),0,stream>>>(t); }
        { BArgs a{}; a.dirsign=1.f; a.aux=CA4;
          for (int i=0;i<nb;i++) a.img[i]=ImgD{CB4+(size_t)i*n2,nullptr,S+120+(size_t)(s*4+b0+i)*13,0,4,0,0,inv,1};
          launchB(n,nb,a,stream); }
      }
    } else {
      k_tail64<<<1,256,0,stream>>>(F,S);
      { BArgs a{}; a.F=F; a.dirsign=1.f;
        a.img[0]=ImgD{nullptr,CB4,nullptr,6,0,0,4,1.f/128.f,1};
        launchB(128,1,a,stream); }
      { TArgs t{}; t.base[0]=CB4; t.n=128;
        k_trip<<<dim3(4,4,1),dim3(32,8),0,stream>>>(t); }
      { BArgs a{}; a.dirsign=1.f;
        a.img[0]=ImgD{CB4,CB4,nullptr,0,0,0,0,1.f/128.f,1};
        launchB(128,1,a,stream); }
      k_crx3<<<64,256,0,stream>>>(CB4,CA4,S);
    }
  }
  k_final<<<1,256,0,stream>>>(S,PB,out);
  (void)in_sizes; (void)n_in; (void)out_size; (void)ws_size;
}

// Round 12
// 512.514 us; speedup vs baseline: 1.0741x; 1.0073x over previous
//
#include <hip/hip_runtime.h>

#define PI_F     3.14159265358979323846f
#define TWOPI_F  6.28318530717958647692f
#define HPI_F    1.57079632679489661923f

constexpr int fftT(int N){ return N>=512 ? 256 : (N/2 < 64 ? 64 : N/2); }

// S-slot layout (doubles), replicated REP times (replica stride SL_TOT)
#define SL_ACE 340          // 16 x 41
#define SL_ACR 996          // 4 x 41
#define SL_ALP 1160         // 41
#define SL_TOT 1280
#define REP 8

__device__ __forceinline__ float fcoord(int k, int n){
  int s = k ^ (n>>1);
  return (float)(s - (n>>1)) / (float)(n>>1);
}
__device__ __forceinline__ float lograd(int kr, int kc, int n){
  if (kr==0 && kc==0) return log2f(2.0f/(float)n);
  float x = fcoord(kc,n), y = fcoord(kr,n);
  return 0.5f*log2f(x*x+y*y);
}
__device__ __forceinline__ float rc_sin(float lr, float shift){
  float t = fminf(fmaxf(lr+shift,0.f),1.f); return __sinf(HPI_F*t);
}
__device__ __forceinline__ float rc_cos(float lr, float shift){
  float t = fminf(fmaxf(lr+shift,0.f),1.f); return __cosf(HPI_F*t);
}
// cumulative lowpass mask to reach scale s: prod_{m=0..s} rc_cos(lr, 1-m)
__device__ __forceinline__ float cumlo(float lr, int s){
  float cl = rc_cos(lr, 1.f);
  for (int m=1;m<=s;m++) cl *= rc_cos(lr, 1.f-(float)m);
  return cl;
}
__device__ __forceinline__ float bandang(float ang, int b){
  float th = ang - 0.25f*PI_F*(float)b;
  float u = th + PI_F;
  u -= TWOPI_F*floorf(u*(1.0f/TWOPI_F));
  float thw = u - PI_F;
  float c = __cosf(th);
  return (fabsf(thw) < HPI_F) ? (1.7888543819998317f*c*c*c) : 0.0f;
}
__device__ __forceinline__ int lagIdx(int di, int dj){
  if (dj < 0 || (dj==0 && di<0)){ di=-di; dj=-dj; }
  return dj==0 ? 36+di : (dj-1)*9 + (di+4);
}
__device__ __forceinline__ void atomAddD(double* p, double v){
  unsafeAtomicAdd(p, v);
}
template<int NS>
__device__ __forceinline__ void blockAccumN(double* base, const float* vals, float* red){
  const int lane = threadIdx.x & 63, wid = threadIdx.x >> 6;
  const int nw = (int)(blockDim.x >> 6);
  #pragma unroll
  for (int k=0;k<NS;k++){
    float v = vals[k];
    #pragma unroll
    for (int o=32;o>0;o>>=1) v += __shfl_down(v,o);
    if (lane==0) red[k*nw+wid]=v;
  }
  __syncthreads();
  const int rep = (int)((blockIdx.x ^ (blockIdx.y<<1) ^ (blockIdx.z<<2)) & 7) * SL_TOT;
  if ((int)threadIdx.x < NS){
    float s=0.f;
    for (int w2=0;w2<nw;w2++) s += red[(int)threadIdx.x*nw+w2];
    atomAddD(base+rep+(int)threadIdx.x,(double)s);
  }
  __syncthreads();
}

// ---------------- batched descriptor FFT -------------------------------------
// pre: 0 cplx slab, 1 real row, 3 him from F, 4 hi0 from F, 6 padlp from F,
//      7 bands-multi from F (nb bands, mask cache reuse), 8 padband-multi from F
// post: 0 store (band-offset), 1 sum|x|,x^2, 2 store(re,mag)+summag,
//       3 store+moments, 4 parentred
struct ImgD { const float2* src; float2* dst; double* slots; int pre, post, b, ss; float scale; int nb; };
struct BArgs { ImgD img[6]; const float* rsrc; const float2* F; const float2* aux; float dirsign; };

#define TWI(k) ((k)+((k)>>4))

template<int N>
__global__ __launch_bounds__(fftT(N)) void k_fftB(BArgs a){
  constexpr int T = fftT(N);
  constexpr int LG = (N==1024)?10:(N==512)?9:(N==256)?8:(N==128)?7:6;
  constexpr int NE = N/T;
  __shared__ float2 sm[2][N];
  __shared__ float2 tw[N/2 + N/32];
  __shared__ float red[13*4];
  const ImgD d = a.img[blockIdx.y];
  const int row = blockIdx.x, tid = threadIdx.x;
  bool zrow=false;

  for (int k=tid;k<N/2;k+=T){
    float sn,cs; __sincosf(TWOPI_F*(float)k/(float)N,&sn,&cs);
    tw[TWI(k)]=make_float2(cs,sn);
  }

  const int NB = (d.pre==7 || d.pre==8) ? d.nb : 1;
  float2 vv[NE]; float lrm[NE]; float angv[NE];

  if (d.pre==7){
    const int KC = row + ((row < N/2)? 0 : (1024-N));
    const float2* Fr = a.F + (size_t)KC*1024;
    #pragma unroll
    for (int e=0;e<NE;e++){
      int i = tid + e*T;
      int KR = i + ((i < N/2)? 0 : (1024-N));
      float2 v = Fr[KR];
      float lr = lograd(i,row,N);
      lrm[e] = cumlo(lr,d.ss)*rc_sin(lr,2.f);
      angv[e] = atan2f(fcoord(i,N), fcoord(row,N));
      vv[e] = make_float2(-v.y, v.x);     // (-1j)^3 = +i
    }
  } else if (d.pre==8){
    constexpr int M=N/2, Q=N/4;
    const int fi = (row<Q)? row : (row>=N-Q ? row-M : -1);
    if (fi<0) zrow=true;
    else {
      const int KC = fi + ((fi < M/2)? 0 : (1024-M));
      const float2* Fr = a.F + (size_t)KC*1024;
      #pragma unroll
      for (int e=0;e<NE;e++){
        int i = tid + e*T;
        int fj = (i<Q)? i : (i>=N-Q ? i-M : -1);
        if (fj<0){ lrm[e]=0.f; angv[e]=0.f; vv[e]=make_float2(0.f,0.f); }
        else {
          int KR = fj + ((fj < M/2)? 0 : (1024-M));
          float2 v = Fr[KR];
          float lr = lograd(fj,fi,M);
          lrm[e] = cumlo(lr,d.ss+1)*rc_sin(lr,2.f);
          angv[e] = atan2f(fcoord(fj,M), fcoord(fi,M));
          vv[e] = make_float2(-v.y, v.x);
        }
      }
    }
  }

  for (int bi=0; bi<NB; ++bi){
    __syncthreads();
    // ---- load into sm[0]
    if (d.pre==7 || d.pre==8){
      if (!zrow){
        #pragma unroll
        for (int e=0;e<NE;e++){
          int i = tid + e*T;
          float m = lrm[e]*bandang(angv[e], d.b+bi);
          sm[0][i]=make_float2(vv[e].x*m, vv[e].y*m);
        }
      } else if (bi==0){
        for (int i=tid;i<N;i+=T) sm[0][i]=make_float2(0.f,0.f);
      }
    } else switch(d.pre){
      case 0: {
        const float2* sp = d.src + (size_t)row*N;
        for (int i=tid;i<N;i+=T) sm[0][i]=sp[i];
      } break;
      case 1: {
        const float* rp = a.rsrc + (size_t)row*N;
        for (int i=tid;i<N;i+=T) sm[0][i]=make_float2(rp[i],0.f);
      } break;
      case 3: {
        const int KC = row + ((row < N/2)? 0 : (1024-N));
        const float2* Fr = a.F + (size_t)KC*1024;
        for (int i=tid;i<N;i+=T){
          int KR = i + ((i < N/2)? 0 : (1024-N));
          float2 v = Fr[KR];
          float lr = lograd(i,row,N);
          float m = cumlo(lr,d.ss)*rc_sin(lr,2.f);
          sm[0][i]=make_float2(v.x*m, v.y*m);
        }
      } break;
      case 4: {
        const float2* Fr = a.F + (size_t)row*1024;
        for (int i=tid;i<N;i+=T){
          float2 v = Fr[i];
          float m = rc_sin(lograd(i,row,N),1.f);
          sm[0][i]=make_float2(v.x*m, v.y*m);
        }
      } break;
      case 6: {
        constexpr int M=N/2, Q=N/4;
        const int fi = (row<Q)? row : (row>=N-Q ? row-M : -1);
        if (fi<0){
          for (int i=tid;i<N;i+=T) sm[0][i]=make_float2(0.f,0.f);
          zrow=true;
        } else {
          const int KC = fi + ((fi < M/2)? 0 : (1024-M));
          const float2* Fr = a.F + (size_t)KC*1024;
          for (int i=tid;i<N;i+=T){
            int fj = (i<Q)? i : (i>=N-Q ? i-M : -1);
            float2 r = make_float2(0.f,0.f);
            if (fj>=0 && !(fi==0 && fj==0)){
              int KR = fj + ((fj < M/2)? 0 : (1024-M));
              float2 v = Fr[KR];
              float m = cumlo(lograd(fj,fi,M),4);
              r = make_float2(v.x*m, v.y*m);
            }
            sm[0][i]=r;
          }
        }
      } break;
    }

    int cur=0;
    if (!zrow){
      const float ds = a.dirsign;
      int ls2 = 0;
      for (; ls2+2<=LG; ls2+=2){
        const int Ns = 1<<ls2;
        __syncthreads();
        for (int j=tid; j<N/4; j+=T){
          const int m = j & (Ns-1);
          const int base = ((j>>ls2)<<(ls2+2)) + m;
          float2 x0 = sm[cur][j];
          float2 x1 = sm[cur][j+N/4];
          float2 x2 = sm[cur][j+N/2];
          float2 x3 = sm[cur][j+3*(N/4)];
          float2 w = tw[TWI(m<<(LG-2-ls2))];
          float w1x=w.x, w1y=ds*w.y;
          float w2x = w1x*w1x - w1y*w1y, w2y = 2.f*w1x*w1y;
          float w3x = w2x*w1x - w2y*w1y, w3y = w2x*w1y + w2y*w1x;
          float2 b = make_float2(x1.x*w1x - x1.y*w1y, x1.x*w1y + x1.y*w1x);
          float2 c = make_float2(x2.x*w2x - x2.y*w2y, x2.x*w2y + x2.y*w2x);
          float2 e = make_float2(x3.x*w3x - x3.y*w3y, x3.x*w3y + x3.y*w3x);
          float t0x=x0.x+c.x, t0y=x0.y+c.y;
          float t1x=x0.x-c.x, t1y=x0.y-c.y;
          float t2x=b.x+e.x,  t2y=b.y+e.y;
          float t3x=b.x-e.x,  t3y=b.y-e.y;
          float rtx=-ds*t3y,  rty=ds*t3x;
          sm[cur^1][base]          = make_float2(t0x+t2x, t0y+t2y);
          sm[cur^1][base+Ns]       = make_float2(t1x+rtx, t1y+rty);
          sm[cur^1][base+2*Ns]     = make_float2(t0x-t2x, t0y-t2y);
          sm[cur^1][base+3*Ns]     = make_float2(t1x-rtx, t1y-rty);
        }
        cur ^= 1;
      }
      if (LG & 1){
        const int ls = LG-1, Ns = 1<<ls;
        __syncthreads();
        for (int j=tid; j<N/2; j+=T){
          const int m = j & (Ns-1);
          const int base = ((j>>ls)<<(ls+1)) + m;
          float2 va = sm[cur][j];
          float2 vb = sm[cur][j+N/2];
          float2 w = tw[TWI(m)];
          float wy = ds*w.y;
          float2 bw = make_float2(vb.x*w.x - vb.y*wy, vb.x*wy + vb.y*w.x);
          sm[cur^1][base]    = make_float2(va.x+bw.x, va.y+bw.y);
          sm[cur^1][base+Ns] = make_float2(va.x-bw.x, va.y-bw.y);
        }
        cur ^= 1;
      }
    }
    __syncthreads();

    const float sc = d.scale;
    switch(d.post){
      case 0: {
        float2* dp = d.dst + (size_t)bi*N*N + (size_t)row*N;
        for (int i=tid;i<N;i+=T){ float2 v=sm[cur][i]; dp[i]=make_float2(v.x*sc,v.y*sc); }
      } break;
      case 1: {
        float a1=0.f,a2=0.f;
        for (int i=tid;i<N;i+=T){ float v=sm[cur][i].x*sc; a1+=fabsf(v); a2+=v*v; }
        float vals[2]={a1,a2};
        blockAccumN<2>(d.slots, vals, red);
      } break;
      case 2: {   // store (re, mag)
        float2* dp = d.dst + (size_t)row*N;
        float am=0.f;
        for (int i=tid;i<N;i+=T){
          float2 v=sm[cur][i]; v.x*=sc; v.y*=sc;
          float m = sqrtf(v.x*v.x+v.y*v.y);
          dp[i]=make_float2(v.x, m);
          am += m;
        }
        float vals[1]={am};
        blockAccumN<1>(d.slots, vals, red);
      } break;
      case 3: {
        float2* dp = d.dst + (size_t)row*N;
        float s2=0.f,s3=0.f,s4=0.f;
        for (int i=tid;i<N;i+=T){
          float2 v=sm[cur][i]; v.x*=sc; v.y*=sc; dp[i]=v;
          float x=v.x, x2=x*x; s2+=x2; s3+=x2*x; s4+=x2*x2;
        }
        float vals[3]={s2,s3,s4};
        blockAccumN<3>(d.slots, vals, red);
      } break;
      case 4: {   // parent reduction; aux bands hold (re, mag)
        const float2* B = a.aux;
        constexpr size_t N2 = (size_t)N*N;
        float acc[13];
        #pragma unroll
        for (int k=0;k<13;k++) acc[k]=0.f;
        for (int i=tid;i<N;i+=T){
          float2 p=sm[cur][i]; p.x*=sc; p.y*=sc;
          float m = sqrtf(p.x*p.x+p.y*p.y);
          float rp=0.f, ip=0.f;
          if (m>0.f){ rp=(p.y*p.y-p.x*p.x)/m; ip=2.f*p.x*p.y/m; }
          size_t pos = (size_t)row*N + i;
          acc[0]+=m;
          #pragma unroll
          for (int k=0;k<4;k++){
            float2 z = B[k*N2+pos];
            acc[1+k]+=z.y*m; acc[5+k]+=z.x*rp; acc[9+k]+=z.x*ip;
          }
        }
        blockAccumN<13>(d.slots, acc, red);
      } break;
    }
  }
}

// multi-base in-place batched square transpose
struct TArgs { float2* base[6]; int n; };
__global__ void k_trip(TArgs t){
  int bi = blockIdx.x, bj = blockIdx.y;
  if (bj < bi) return;
  const int n = t.n;
  float2* img = t.base[blockIdx.z];
  __shared__ float2 t0[32][33], t1[32][33];
  int r0=bi*32, c0=bj*32;
  for (int dy=threadIdx.y; dy<32; dy+=8){
    t0[dy][threadIdx.x] = img[(size_t)(r0+dy)*n + c0 + threadIdx.x];
    if (bi!=bj) t1[dy][threadIdx.x] = img[(size_t)(c0+dy)*n + r0 + threadIdx.x];
  }
  __syncthreads();
  for (int dy=threadIdx.y; dy<32; dy+=8){
    img[(size_t)(c0+dy)*n + r0 + threadIdx.x] = t0[threadIdx.x][dy];
    if (bi!=bj) img[(size_t)(r0+dy)*n + c0 + threadIdx.x] = t1[threadIdx.x][dy];
  }
}

// multi-base direct circular autocorrelation (41 unique 9x9 lags)
// scalar reads, horizontally-adjacent point PAIRS share window rows
struct AArgs { const float2* base[5]; double* slots[5]; int n, lgn, nmag; };
__global__ __launch_bounds__(256) void k_ac(AArgs a){
  __shared__ float t[72][73];
  __shared__ float red[41*4];
  const int z = blockIdx.z;
  const float2* img = a.base[z];
  const bool mag = z < a.nmag;
  const int n = a.n, lgn = a.lgn;
  const int ty0 = blockIdx.y*64, tx0 = blockIdx.x*64;
  for (int idx = threadIdx.x; idx < 72*72; idx += 256){
    int ly = idx/72, lx = idx-ly*72;
    int gy = (ty0 + ly - 4) & (n-1), gx = (tx0 + lx - 4) & (n-1);
    float2 v = img[((size_t)gy<<lgn) + gx];
    t[ly][lx] = mag ? v.y : v.x;
  }
  __syncthreads();
  float acc[41];
  #pragma unroll
  for (int k=0;k<41;k++) acc[k]=0.f;
  for (int p = threadIdx.x; p < 2048; p += 256){
    int ly = (p>>5) + 4;
    int lx = ((p&31)<<1) + 4;
    float mA = t[ly][lx], mB = t[ly][lx+1];
    #pragma unroll
    for (int di=-4; di<=4; ++di){
      const float* rp = &t[ly+di][lx];
      float r0=rp[0], r1=rp[1], r2=rp[2], r3=rp[3], r4=rp[4], r5=rp[5];
      if (di>=0) acc[36+di] += mA*r0 + mB*r1;
      acc[di+4]    += mA*r1 + mB*r2;
      acc[9+di+4]  += mA*r2 + mB*r3;
      acc[18+di+4] += mA*r3 + mB*r4;
      acc[27+di+4] += mA*r4 + mB*r5;
    }
  }
  blockAccumN<41>(a.slots[z], acc, red);
}

// ---------------- misc kernels ----------------------------------------------
__global__ void k_init(double* S, float* out, int nout){
  int i = blockIdx.x*blockDim.x + threadIdx.x;
  if (i < REP*SL_TOT) S[i]=0.0;
  if (i < nout) out[i]=0.f;
}
__global__ __launch_bounds__(256) void k_imgstats(const float4* __restrict__ x, float* PB){
  float s1=0.f,s2=0.f,s3=0.f,s4=0.f, mn=3.4e38f, mx=-3.4e38f;
  const int base = blockIdx.x*1024 + threadIdx.x;
  #pragma unroll
  for (int it=0; it<4; ++it){
    float4 v = x[base + it*256];
    float vs[4]={v.x,v.y,v.z,v.w};
    #pragma unroll
    for (int k=0;k<4;k++){
      float t=vs[k], t2=t*t;
      s1+=t; s2+=t2; s3+=t2*t; s4+=t2*t2;
      mn=fminf(mn,t); mx=fmaxf(mx,t);
    }
  }
  __shared__ float wr[6][4];
  int lane=threadIdx.x&63, wid=threadIdx.x>>6;
  float sums[4]={s1,s2,s3,s4};
  #pragma unroll
  for (int k=0;k<4;k++){
    float v=sums[k];
    for (int o=32;o>0;o>>=1) v+=__shfl_down(v,o);
    if (lane==0) wr[k][wid]=v;
  }
  { float v=mn; for (int o=32;o>0;o>>=1) v=fminf(v,__shfl_down(v,o)); if(lane==0) wr[4][wid]=v; }
  { float v=mx; for (int o=32;o>0;o>>=1) v=fmaxf(v,__shfl_down(v,o)); if(lane==0) wr[5][wid]=v; }
  __syncthreads();
  if (threadIdx.x<4)  PB[blockIdx.x*8+threadIdx.x] = wr[threadIdx.x][0]+wr[threadIdx.x][1]+wr[threadIdx.x][2]+wr[threadIdx.x][3];
  if (threadIdx.x==4) PB[blockIdx.x*8+4] = fminf(fminf(wr[4][0],wr[4][1]),fminf(wr[4][2],wr[4][3]));
  if (threadIdx.x==5) PB[blockIdx.x*8+5] = fmaxf(fmaxf(wr[5][0],wr[5][1]),fmaxf(wr[5][2],wr[5][3]));
}
__global__ void k_gram(const float2* __restrict__ B, int n2, double* slots){
  float p[20];
  #pragma unroll
  for (int i=0;i<20;i++) p[i]=0.f;
  int stride = gridDim.x*blockDim.x;
  for (int i=blockIdx.x*blockDim.x+threadIdx.x; i<n2; i+=stride){
    float2 z0=B[i], z1=B[i+(size_t)n2], z2=B[i+2*(size_t)n2], z3=B[i+3*(size_t)n2];
    float m0=z0.y, m1=z1.y, m2=z2.y, m3=z3.y;
    float r0=z0.x, r1=z1.x, r2=z2.x, r3=z3.x;
    p[0]+=m0*m0; p[1]+=m0*m1; p[2]+=m0*m2; p[3]+=m0*m3;
    p[4]+=m1*m1; p[5]+=m1*m2; p[6]+=m1*m3;
    p[7]+=m2*m2; p[8]+=m2*m3; p[9]+=m3*m3;
    p[10]+=r0*r0; p[11]+=r0*r1; p[12]+=r0*r2; p[13]+=r0*r3;
    p[14]+=r1*r1; p[15]+=r1*r2; p[16]+=r1*r3;
    p[17]+=r2*r2; p[18]+=r2*r3; p[19]+=r3*r3;
  }
  __shared__ float red[20*4];
  blockAccumN<20>(slots,p,red);
}
__global__ void k_crx3(const float2* __restrict__ RP, const float2* __restrict__ B3, double* S){
  float a[35];
  #pragma unroll
  for (int i=0;i<35;i++) a[i]=0.f;
  int stride = gridDim.x*blockDim.x;
  for (int idx=blockIdx.x*blockDim.x+threadIdx.x; idx<16384; idx+=stride){
    int u=idx>>7, v=idx&127;
    float P0=RP[idx].x;
    float P1=RP[(u<<7) | ((v-1)&127)].x;
    float P2=RP[(u<<7) | ((v+1)&127)].x;
    float P3=RP[(((u-1)&127)<<7) | v].x;
    float P4=RP[(((u+1)&127)<<7) | v].x;
    float P[5]={P0,P1,P2,P3,P4};
    float R[4];
    #pragma unroll
    for (int b=0;b<4;b++) R[b]=B3[b*16384 + (v<<7) + u].x;
    #pragma unroll
    for (int i=0;i<4;i++)
      #pragma unroll
      for (int j=0;j<5;j++) a[i*5+j]+=R[i]*P[j];
    int k=20;
    #pragma unroll
    for (int i=0;i<5;i++)
      #pragma unroll
      for (int j=i;j<5;j++){ a[k]+=P[i]*P[j]; k++; }
  }
  __shared__ float red[35*4];
  float lo[20], hi[15];
  #pragma unroll
  for (int k=0;k<20;k++) lo[k]=a[k];
  #pragma unroll
  for (int k=0;k<15;k++) hi[k]=a[20+k];
  blockAccumN<20>(S+280, lo, red);
  blockAccumN<15>(S+300, hi, red);
}

// in-place unnormalized inverse 2D FFT in LDS, separated planes, stride S
template<int LG>
__device__ void ifft2_lds(float* re, float* im, const float2* tw, int S){
  constexpr int N=1<<LG, H=N>>1;
  const int tid=threadIdx.x, T=256;
  for (int ls=LG-1; ls>=0; --ls){
    const int h=1<<ls;
    __syncthreads();
    for (int t=tid; t<N*H; t+=T){
      int r=t>>(LG-1), j=t&(H-1);
      int m=j&(h-1);
      int i0=r*S + ((j>>ls)<<(ls+1)) + m, i1=i0+h;
      float ar=re[i0], ai=im[i0], br=re[i1], bi=im[i1];
      re[i0]=ar+br; im[i0]=ai+bi;
      float dr=ar-br, di=ai-bi;
      float2 w=tw[m<<(LG-1-ls)];
      re[i1]=dr*w.x - di*w.y;
      im[i1]=dr*w.y + di*w.x;
    }
  }
  __syncthreads();
  for (int t=tid;t<N*N;t+=T){
    int r=t>>LG, j=t&(N-1);
    int jb=(int)(__brev((unsigned)j)>>(32-LG));
    if (j<jb){
      int p=r*S+j, q=r*S+jb;
      float x=re[p]; re[p]=re[q]; re[q]=x;
      x=im[p]; im[p]=im[q]; im[q]=x;
    }
  }
  for (int ls=LG-1; ls>=0; --ls){
    const int h=1<<ls;
    __syncthreads();
    for (int t=tid; t<N*H; t+=T){
      int c=t>>(LG-1), j=t&(H-1);
      int m=j&(h-1);
      int i0=(((j>>ls)<<(ls+1))+m)*S + c, i1=i0+h*S;
      float ar=re[i0], ai=im[i0], br=re[i1], bi=im[i1];
      re[i0]=ar+br; im[i0]=ai+bi;
      float dr=ar-br, di=ai-bi;
      float2 w=tw[m<<(LG-1-ls)];
      re[i1]=dr*w.x - di*w.y;
      im[i1]=dr*w.y + di*w.x;
    }
  }
  __syncthreads();
  for (int t=tid;t<N*N;t+=T){
    int c=t>>LG, j=t&(N-1);
    int jb=(int)(__brev((unsigned)j)>>(32-LG));
    if (j<jb){
      int p=j*S+c, q=jb*S+c;
      float x=re[p]; re[p]=re[q]; re[q]=x;
      x=im[p]; im[p]=im[q]; im[q]=x;
    }
  }
  __syncthreads();
}

// fused 64x64 tail: lowpass (absdev) + imlp (moments + 41-lag AC)
__global__ __launch_bounds__(256) void k_tail64(const float2* __restrict__ F, double* S){
  __shared__ float re[64*65];
  __shared__ float im[64*65];
  __shared__ float2 tw[32];
  __shared__ float red[41*4];
  __shared__ float shmu;
  const int tid=threadIdx.x;
  const float sc=1.f/4096.f;
  for (int k=tid;k<32;k+=256){
    float sn,cs; __sincosf(TWOPI_F*(float)k/64.f,&sn,&cs);
    tw[k]=make_float2(cs,sn);
  }
  // ---- lowpass ----
  for (int t=tid;t<4096;t+=256){
    int a2=t>>6, b=t&63;
    int KR = b + ((b<32)?0:960);
    int KC = a2 + ((a2<32)?0:960);
    float2 v = F[(size_t)KC*1024+KR];
    float m = cumlo(lograd(b,a2,64),4);
    re[a2*65+b]=v.x*m; im[a2*65+b]=v.y*m;
  }
  ifft2_lds<6>(re,im,tw,65);
  {
    int lane=tid&63, wid=tid>>6;
    float s1=0.f;
    for (int t=tid;t<4096;t+=256) s1 += re[(t>>6)*65+(t&63)];
    float v=s1; for (int o=32;o>0;o>>=1) v+=__shfl_down(v,o);
    if (lane==0) red[wid]=v;
    __syncthreads();
    if (tid==0) shmu=(red[0]+red[1]+red[2]+red[3])*(sc*sc);
    __syncthreads();
    float mu=shmu, adc=0.f;
    for (int t=tid;t<4096;t+=256) adc += fabsf(re[(t>>6)*65+(t&63)]*sc - mu);
    v=adc; for (int o=32;o>0;o>>=1) v+=__shfl_down(v,o);
    if (lane==0) red[wid]=v;
    __syncthreads();
    if (tid==0) S[23]=(double)(red[0]+red[1]+red[2]+red[3]);
    __syncthreads();
  }
  // ---- imlp ----
  for (int t=tid;t<4096;t+=256){
    int a2=t>>6, b=t&63;
    int KR = b + ((b<32)?0:960);
    int KC = a2 + ((a2<32)?0:960);
    float2 v = F[(size_t)KC*1024+KR];
    float lr = lograd(b,a2,64);
    float m = cumlo(lr,4)*rc_cos(lr,1.f);
    if (t==0) m=0.f;
    re[a2*65+b]=v.x*m; im[a2*65+b]=v.y*m;
  }
  ifft2_lds<6>(re,im,tw,65);
  {
    float s2=0.f,s3=0.f,s4=0.f;
    float acc[41];
    #pragma unroll
    for (int k=0;k<41;k++) acc[k]=0.f;
    for (int p=tid;p<4096;p+=256){
      int y=p>>6, x=p&63;
      float m0u=re[y*65+x];
      float m0=m0u*sc, m02=m0*m0;
      s2+=m02; s3+=m02*m0; s4+=m02*m02;
      #pragma unroll
      for (int dj=1;dj<=4;dj++)
        #pragma unroll
        for (int di=-4;di<=4;di++)
          acc[(dj-1)*9+di+4] += m0u * re[((y+dj)&63)*65 + ((x+di)&63)];
      #pragma unroll
      for (int di=0;di<=4;di++)
        acc[36+di] += m0u * re[y*65 + ((x+di)&63)];
    }
    #pragma unroll
    for (int k=0;k<41;k++) acc[k]*=sc*sc;
    float mom[3]={s2,s3,s4};
    blockAccumN<3>(S+36, mom, red);
    blockAccumN<41>(S+SL_ALP, acc, red);
  }
}

__global__ __launch_bounds__(256) void k_final(const double* __restrict__ S,
                                               const float* __restrict__ PB, float* out){
  __shared__ double SD[SL_TOT];
  __shared__ double sh[6];
  __shared__ double wrD[4][4];
  __shared__ float  wrF[2][4];
  const int tid = threadIdx.x;
  for (int k=tid;k<SL_TOT;k+=256){
    double v=0.0;
    #pragma unroll
    for (int r=0;r<REP;r++) v += S[(size_t)r*SL_TOT+k];
    SD[k]=v;
  }
  {
    int lane=tid&63, wid=tid>>6;
    double p0=PB[tid*8+0], p1=PB[tid*8+1], p2=PB[tid*8+2], p3=PB[tid*8+3];
    float pn=PB[tid*8+4], px=PB[tid*8+5];
    for (int o=32;o>0;o>>=1){ p0+=__shfl_down(p0,o); p1+=__shfl_down(p1,o); p2+=__shfl_down(p2,o); p3+=__shfl_down(p3,o); }
    if (lane==0){ wrD[0][wid]=p0; wrD[1][wid]=p1; wrD[2][wid]=p2; wrD[3][wid]=p3; }
    { float v=pn; for (int o=32;o>0;o>>=1) v=fminf(v,__shfl_down(v,o)); if(lane==0) wrF[0][wid]=v; }
    { float v=px; for (int o=32;o>0;o>>=1) v=fmaxf(v,__shfl_down(v,o)); if(lane==0) wrF[1][wid]=v; }
    __syncthreads();
    if (tid==0){
      for (int k=0;k<4;k++) sh[k]=wrD[k][0]+wrD[k][1]+wrD[k][2]+wrD[k][3];
      sh[4]=(double)fminf(fminf(wrF[0][0],wrF[0][1]),fminf(wrF[0][2],wrF[0][3]));
      sh[5]=(double)fmaxf(fmaxf(wrF[1][0],wrF[1][1]),fmaxf(wrF[1][2],wrF[1][3]));
    }
    __syncthreads();
  }
  const double npix[4]={1048576.0,262144.0,65536.0,16384.0};
  for (int e=tid; e<81*16; e+=256){
    int w=e>>4, s=(e>>2)&3, b=e&3;
    int i=w/9, j=w-i*9;
    int k=lagIdx(i-4,j-4);
    double n2=npix[s];
    double mu=SD[6+s*4+b]/n2;
    out[24+(w*4+s)*4+b]=(float)(SD[SL_ACE+(s*4+b)*41+k]/n2 - mu*mu);
  }
  for (int e=tid; e<81*4; e+=256){
    int w=e>>2, s=e&3;
    int i=w/9, j=w-i*9;
    int k=lagIdx(i-4,j-4);
    out[1330+w*5+s]=(float)(SD[SL_ACR+s*41+k]/(2.0*npix[s]));
  }
  for (int w=tid; w<81; w+=256){
    int i=w/9, j=w-i*9;
    int k=lagIdx(i-4,j-4);
    out[1330+w*5+4]=(float)(SD[SL_ALP+k]/4096.0);
  }
  for (int e=tid; e<64; e+=256){
    int s=e>>4, i=(e>>2)&3, j=e&3;
    int a2=i<j?i:j, bb=i<j?j:i;
    int p=a2*(7-a2)/2+bb;
    double n2=npix[s];
    double Si=SD[6+s*4+i], Sj=SD[6+s*4+j];
    out[1735+(i*4+j)*5+s]=(float)((SD[40+s*20+p]-Si*Sj/n2)/n2);
    out[1879+(i*8+j)*5+s]=(float)(SD[40+s*20+10+p]/n2);
  }
  for (int e=tid; e<48; e+=256){
    int s=e>>4, j=(e>>2)&3, i=e&3;
    double n2=npix[s];
    int pb=120+(s*4+j)*13;
    double Smj=SD[pb];
    double Si=SD[6+s*4+i];
    out[1815+(i*4+j)*4+s]=(float)((SD[pb+1+i]-Si*Smj/n2)/n2);
    out[2199+(i*8+j)*4+s]=(float)(SD[pb+5+i]/n2);
    out[2199+(i*8+(j+4))*4+s]=(float)(SD[pb+9+i]/n2);
  }
  for (int e=tid; e<20; e+=256){
    int i=e/5, j=e%5;
    out[2199+(i*8+j)*4+3]=(float)(SD[280+i*5+j]/16384.0);
  }
  for (int e=tid; e<25; e+=256){
    int i=e/5, j=e%5;
    int a2=i<j?i:j, bb=i<j?j:i;
    int p=a2*(9-a2)/2+bb;
    out[1879+(i*8+j)*5+4]=(float)(SD[300+p]/4096.0);
  }
  if (tid==0){
    const double N0=1048576.0;
    double sum=sh[0], s2=sh[1], s3=sh[2], s4=sh[3];
    double mean0=sum/N0;
    double var0=(s2 - sum*mean0)/(N0-1.0);
    double m3 = s3 - 3.0*mean0*s2 + 2.0*N0*mean0*mean0*mean0;
    double m4 = s4 - 4.0*mean0*s3 + 6.0*mean0*mean0*s2 - 3.0*N0*mean0*mean0*mean0*mean0;
    out[0]=(float)mean0; out[1]=(float)var0;
    out[2]=(float)((m3/N0)/(var0*sqrt(var0)));
    out[3]=(float)((m4/N0)/(var0*var0));
    out[4]=(float)sh[4]; out[5]=(float)sh[5];
    out[6]=(float)(SD[4]/N0);
    for (int s=0;s<4;s++) for (int b=0;b<4;b++) out[7+s*4+b]=(float)(SD[6+s*4+b]/npix[s]);
    out[23]=(float)(SD[23]/4096.0);
    for (int s=0;s<4;s++){
      double n2=npix[s];
      double vari=SD[24+s*3]/(2.0*n2);
      int ok=(vari/var0>1e-6);
      out[1320+s]= ok? (float)(0.5*(SD[25+s*3]/n2)/(vari*sqrt(vari))) : 0.f;
      out[1325+s]= ok? (float)(0.5*(SD[26+s*3]/n2)/(vari*vari)) : 3.f;
    }
    { double vari=SD[36]/4096.0; int ok=(vari/var0>1e-6);
      out[1324]= ok? (float)((SD[37]/4096.0)/(vari*sqrt(vari))) : 0.f;
      out[1329]= ok? (float)((SD[38]/4096.0)/(vari*vari)) : 3.f; }
    out[2455]=(float)(SD[5]/N0);
  }
}

// ---------------- host orchestration -----------------------------------------
static void launchB(int n, int nimg, const BArgs& a, hipStream_t st){
  switch(n){
    case 1024: k_fftB<1024><<<dim3(1024,nimg),fftT(1024),0,st>>>(a); break;
    case 512:  k_fftB<512 ><<<dim3(512 ,nimg),fftT(512 ),0,st>>>(a); break;
    case 256:  k_fftB<256 ><<<dim3(256 ,nimg),fftT(256 ),0,st>>>(a); break;
    case 128:  k_fftB<128 ><<<dim3(128 ,nimg),fftT(128 ),0,st>>>(a); break;
  }
}

extern "C" void kernel_launch(void* const* d_in, const int* in_sizes, int n_in,
                              void* d_out, int out_size, void* d_ws, size_t ws_size,
                              hipStream_t stream){
  const float* im = (const float*)d_in[0];
  float* out = (float*)d_out;
  char* w = (char*)d_ws;
  float2* F   = (float2*)w;                         // 8 MB: imdft^T
  float2* CA4 = (float2*)(w + ((size_t)8<<20));     // 32 MB: 4 bands
  float2* CC  = (float2*)(w + ((size_t)40<<20));    // 8 MB: unor
  float2* CB4 = (float2*)(w + ((size_t)48<<20));    // 16 MB: hi0 / parents / rp
  size_t off = (size_t)64<<20;
  double* S = (double*)(w+off);
  float* PB = (float*)(w+off+(size_t)REP*SL_TOT*8);

  k_init<<<40,256,0,stream>>>(S,out,2456);
  k_imgstats<<<256,256,0,stream>>>((const float4*)im,PB);

  // forward fft2 -> F^T
  { BArgs a{}; a.rsrc=im; a.dirsign=-1.f;
    a.img[0]=ImgD{nullptr,F,nullptr,1,0,0,0,1.f,1};
    launchB(1024,1,a,stream); }
  { TArgs t{}; t.base[0]=F; t.n=1024;
    k_trip<<<dim3(32,32,1),dim3(32,8),0,stream>>>(t); }
  { BArgs a{}; a.dirsign=-1.f;
    a.img[0]=ImgD{F,F,nullptr,0,0,0,0,1.f,1};
    launchB(1024,1,a,stream); }

  for (int s=0;s<4;s++){
    const int n=1024>>s, nt=n/32, n2=n*n, lg=10-s;
    const float inv=1.f/(float)n;
    // pass1: bands (multi, mask-reuse) + unor (+ hi0 at s=0)
    { BArgs a{}; a.F=F; a.dirsign=1.f;
      a.img[0]=ImgD{nullptr,CA4,nullptr,7,0,0,s,inv,4};
      a.img[1]=ImgD{nullptr,CC,nullptr,3,0,0,s,inv,1};
      if (s==0) a.img[2]=ImgD{nullptr,CB4,nullptr,4,0,0,0,inv,1};
      launchB(n,(s==0)?3:2,a,stream); }
    { TArgs t{}; t.n=n;
      for (int b=0;b<4;b++) t.base[b]=CA4+(size_t)b*n2;
      t.base[4]=CC; if (s==0) t.base[5]=CB4;
      k_trip<<<dim3(nt,nt,(s==0)?6:5),dim3(32,8),0,stream>>>(t); }
    // pass2: column FFT + per-image reductions/stores
    { BArgs a{}; a.dirsign=1.f;
      for (int b=0;b<4;b++) a.img[b]=ImgD{CA4+(size_t)b*n2,CA4+(size_t)b*n2,S+6+s*4+b,0,2,0,0,inv,1};
      a.img[4]=ImgD{CC,CC,S+24+s*3,0,3,0,0,inv,1};
      if (s==0) a.img[5]=ImgD{CB4,nullptr,S+4,0,1,0,0,inv,1};
      launchB(n,(s==0)?6:5,a,stream); }
    k_gram<<<256,256,0,stream>>>(CA4,n2,S+40+s*20);
    { AArgs aa{}; aa.n=n; aa.lgn=lg; aa.nmag=4;
      for (int b=0;b<4;b++){ aa.base[b]=CA4+(size_t)b*n2; aa.slots[b]=S+SL_ACE+(size_t)(s*4+b)*41; }
      aa.base[4]=CC; aa.slots[4]=S+SL_ACR+(size_t)s*41;
      k_ac<<<dim3(n/64,n/64,5),256,0,stream>>>(aa); }
    if (s<3){
      if (s==0){
        for (int b0=0;b0<4;b0+=2){
          { BArgs a{}; a.F=F; a.dirsign=1.f;
            a.img[0]=ImgD{nullptr,CB4,nullptr,8,0,b0,s,inv,2};
            launchB(n,1,a,stream); }
          { TArgs t{}; t.n=n;
            for (int i=0;i<2;i++) t.base[i]=CB4+(size_t)i*n2;
            k_trip<<<dim3(nt,nt,2),dim3(32,8),0,stream>>>(t); }
          { BArgs a{}; a.dirsign=1.f; a.aux=CA4;
            for (int i=0;i<2;i++) a.img[i]=ImgD{CB4+(size_t)i*n2,nullptr,S+120+(size_t)(s*4+b0+i)*13,0,4,0,0,inv,1};
            launchB(n,2,a,stream); }
        }
      } else {
        // balanced: 2 img slots x 2 bands each, single pad/trip/red launches
        { BArgs a{}; a.F=F; a.dirsign=1.f;
          a.img[0]=ImgD{nullptr,CB4,nullptr,8,0,0,s,inv,2};
          a.img[1]=ImgD{nullptr,CB4+(size_t)2*n2,nullptr,8,0,2,s,inv,2};
          launchB(n,2,a,stream); }
        { TArgs t{}; t.n=n;
          for (int i=0;i<4;i++) t.base[i]=CB4+(size_t)i*n2;
          k_trip<<<dim3(nt,nt,4),dim3(32,8),0,stream>>>(t); }
        { BArgs a{}; a.dirsign=1.f; a.aux=CA4;
          for (int i=0;i<4;i++) a.img[i]=ImgD{CB4+(size_t)i*n2,nullptr,S+120+(size_t)(s*4+i)*13,0,4,0,0,inv,1};
          launchB(n,4,a,stream); }
      }
    } else {
      k_tail64<<<1,256,0,stream>>>(F,S);
      { BArgs a{}; a.F=F; a.dirsign=1.f;
        a.img[0]=ImgD{nullptr,CB4,nullptr,6,0,0,4,1.f/128.f,1};
        launchB(128,1,a,stream); }
      { TArgs t{}; t.base[0]=CB4; t.n=128;
        k_trip<<<dim3(4,4,1),dim3(32,8),0,stream>>>(t); }
      { BArgs a{}; a.dirsign=1.f;
        a.img[0]=ImgD{CB4,CB4,nullptr,0,0,0,0,1.f/128.f,1};
        launchB(128,1,a,stream); }
      k_crx3<<<64,256,0,stream>>>(CB4,CA4,S);
    }
  }
  k_final<<<1,256,0,stream>>>(S,PB,out);
  (void)in_sizes; (void)n_in; (void)out_size; (void)ws_size;
}

// Round 13
// 458.789 us; speedup vs baseline: 1.1999x; 1.1171x over previous
//
#include <hip/hip_runtime.h>

#define PI_F     3.14159265358979323846f
#define TWOPI_F  6.28318530717958647692f
#define HPI_F    1.57079632679489661923f

constexpr int fftT(int N){ return N>=512 ? 256 : (N/2 < 64 ? 64 : N/2); }

// S-slot layout (doubles), replicated REP times (replica stride SL_TOT)
#define SL_ACE 340          // 16 x 41
#define SL_ACR 996          // 4 x 41
#define SL_ALP 1160         // 41
#define SL_TOT 1280
#define REP 8

__device__ __forceinline__ float fcoord(int k, int n){
  int s = k ^ (n>>1);
  return (float)(s - (n>>1)) / (float)(n>>1);
}
__device__ __forceinline__ float lograd(int kr, int kc, int n){
  if (kr==0 && kc==0) return log2f(2.0f/(float)n);
  float x = fcoord(kc,n), y = fcoord(kr,n);
  return 0.5f*log2f(x*x+y*y);
}
__device__ __forceinline__ float rc_sin(float lr, float shift){
  float t = fminf(fmaxf(lr+shift,0.f),1.f); return __sinf(HPI_F*t);
}
__device__ __forceinline__ float rc_cos(float lr, float shift){
  float t = fminf(fmaxf(lr+shift,0.f),1.f); return __cosf(HPI_F*t);
}
// cumulative lowpass mask to reach scale s: prod_{m=0..s} rc_cos(lr, 1-m)
__device__ __forceinline__ float cumlo(float lr, int s){
  float cl = rc_cos(lr, 1.f);
  for (int m=1;m<=s;m++) cl *= rc_cos(lr, 1.f-(float)m);
  return cl;
}
__device__ __forceinline__ float bandmask(int kr, int kc, int n, int b){
  float x = fcoord(kc,n), y = fcoord(kr,n);
  float ang = atan2f(y,x);
  float lr = lograd(kr,kc,n);
  float him = rc_sin(lr,2.0f);
  float th = ang - 0.25f*PI_F*(float)b;
  float u = th + PI_F;
  u -= TWOPI_F*floorf(u*(1.0f/TWOPI_F));
  float thw = u - PI_F;
  float c = __cosf(th);
  float am = (fabsf(thw) < HPI_F) ? (1.7888543819998317f*c*c*c) : 0.0f;
  return am*him;
}
__device__ __forceinline__ int lagIdx(int di, int dj){
  if (dj < 0 || (dj==0 && di<0)){ di=-di; dj=-dj; }
  return dj==0 ? 36+di : (dj-1)*9 + (di+4);
}
__device__ __forceinline__ void atomAddD(double* p, double v){
  unsafeAtomicAdd(p, v);
}
template<int NS>
__device__ __forceinline__ void blockAccumN(double* base, const float* vals, float* red){
  const int lane = threadIdx.x & 63, wid = threadIdx.x >> 6;
  const int nw = (int)(blockDim.x >> 6);
  #pragma unroll
  for (int k=0;k<NS;k++){
    float v = vals[k];
    #pragma unroll
    for (int o=32;o>0;o>>=1) v += __shfl_down(v,o);
    if (lane==0) red[k*nw+wid]=v;
  }
  __syncthreads();
  const int rep = (int)((blockIdx.x ^ (blockIdx.y<<1) ^ (blockIdx.z<<2)) & 7) * SL_TOT;
  if ((int)threadIdx.x < NS){
    float s=0.f;
    for (int w2=0;w2<nw;w2++) s += red[(int)threadIdx.x*nw+w2];
    atomAddD(base+rep+(int)threadIdx.x,(double)s);
  }
  __syncthreads();
}

// ---------------- batched descriptor FFT -------------------------------------
// pre: 0 cplx slab, 1 real row, 2 band from F, 3 him from F, 4 hi0 from F,
//      5 padband from F, 6 padlp from F
// post: 0 store, 1 sum|x|,x^2, 2 store(re,mag)+summag, 3 store+moments, 4 parentred
struct ImgD { const float2* src; float2* dst; double* slots; int pre, post, b, ss; float scale; };
struct BArgs { ImgD img[6]; const float* rsrc; const float2* F; const float2* aux; float dirsign; };

#define TWI(k) ((k)+((k)>>4))

template<int N>
__global__ __launch_bounds__(fftT(N)) void k_fftB(BArgs a){
  constexpr int T = fftT(N);
  constexpr int LG = (N==1024)?10:(N==512)?9:(N==256)?8:(N==128)?7:6;
  __shared__ float2 sm[2][N];
  __shared__ float2 tw[N/2 + N/32];
  __shared__ float red[13*4];
  const ImgD d = a.img[blockIdx.y];
  const int row = blockIdx.x, tid = threadIdx.x;
  bool zrow=false;

  for (int k=tid;k<N/2;k+=T){
    float sn,cs; __sincosf(TWOPI_F*(float)k/(float)N,&sn,&cs);
    tw[TWI(k)]=make_float2(cs,sn);
  }

  switch(d.pre){
    case 0: {
      const float2* sp = d.src + (size_t)row*N;
      for (int i=tid;i<N;i+=T) sm[0][i]=sp[i];
    } break;
    case 1: {
      const float* rp = a.rsrc + (size_t)row*N;
      for (int i=tid;i<N;i+=T) sm[0][i]=make_float2(rp[i],0.f);
    } break;
    case 2: {
      const int KC = row + ((row < N/2)? 0 : (1024-N));
      const float2* Fr = a.F + (size_t)KC*1024;
      for (int i=tid;i<N;i+=T){
        int KR = i + ((i < N/2)? 0 : (1024-N));
        float2 v = Fr[KR];
        float lr = lograd(i,row,N);
        float m = cumlo(lr,d.ss)*bandmask(i,row,N,d.b);
        sm[0][i]=make_float2(-v.y*m, v.x*m);   // (-1j)^3 = +i
      }
    } break;
    case 3: {
      const int KC = row + ((row < N/2)? 0 : (1024-N));
      const float2* Fr = a.F + (size_t)KC*1024;
      for (int i=tid;i<N;i+=T){
        int KR = i + ((i < N/2)? 0 : (1024-N));
        float2 v = Fr[KR];
        float lr = lograd(i,row,N);
        float m = cumlo(lr,d.ss)*rc_sin(lr,2.f);
        sm[0][i]=make_float2(v.x*m, v.y*m);
      }
    } break;
    case 4: {
      const float2* Fr = a.F + (size_t)row*1024;
      for (int i=tid;i<N;i+=T){
        float2 v = Fr[i];
        float m = rc_sin(lograd(i,row,N),1.f);
        sm[0][i]=make_float2(v.x*m, v.y*m);
      }
    } break;
    case 5: case 6: {
      constexpr int M=N/2, Q=N/4;
      const int fi = (row<Q)? row : (row>=N-Q ? row-M : -1);
      if (fi<0){
        for (int i=tid;i<N;i+=T) sm[0][i]=make_float2(0.f,0.f);
        zrow=true;
      } else {
        const int KC = fi + ((fi < M/2)? 0 : (1024-M));
        const float2* Fr = a.F + (size_t)KC*1024;
        for (int i=tid;i<N;i+=T){
          int fj = (i<Q)? i : (i>=N-Q ? i-M : -1);
          float2 r = make_float2(0.f,0.f);
          if (fj>=0){
            int KR = fj + ((fj < M/2)? 0 : (1024-M));
            float2 v = Fr[KR];
            float lr = lograd(fj,fi,M);
            if (d.pre==5){
              float m = cumlo(lr,d.ss+1)*bandmask(fj,fi,M,d.b);
              r = make_float2(-v.y*m, v.x*m);
            } else {
              if (!(fi==0 && fj==0)){
                float m = cumlo(lr,4);
                r = make_float2(v.x*m, v.y*m);
              }
            }
          }
          sm[0][i]=r;
        }
      }
    } break;
  }

  int cur=0;
  if (!zrow){
    const float ds = a.dirsign;
    int ls2 = 0;
    // radix-4 stages
    for (; ls2+2<=LG; ls2+=2){
      const int Ns = 1<<ls2;
      __syncthreads();
      for (int j=tid; j<N/4; j+=T){
        const int m = j & (Ns-1);
        const int base = ((j>>ls2)<<(ls2+2)) + m;
        float2 x0 = sm[cur][j];
        float2 x1 = sm[cur][j+N/4];
        float2 x2 = sm[cur][j+N/2];
        float2 x3 = sm[cur][j+3*(N/4)];
        float2 w = tw[TWI(m<<(LG-2-ls2))];
        float w1x=w.x, w1y=ds*w.y;
        float w2x = w1x*w1x - w1y*w1y, w2y = 2.f*w1x*w1y;
        float w3x = w2x*w1x - w2y*w1y, w3y = w2x*w1y + w2y*w1x;
        float2 b = make_float2(x1.x*w1x - x1.y*w1y, x1.x*w1y + x1.y*w1x);
        float2 c = make_float2(x2.x*w2x - x2.y*w2y, x2.x*w2y + x2.y*w2x);
        float2 e = make_float2(x3.x*w3x - x3.y*w3y, x3.x*w3y + x3.y*w3x);
        float t0x=x0.x+c.x, t0y=x0.y+c.y;
        float t1x=x0.x-c.x, t1y=x0.y-c.y;
        float t2x=b.x+e.x,  t2y=b.y+e.y;
        float t3x=b.x-e.x,  t3y=b.y-e.y;
        float rtx=-ds*t3y,  rty=ds*t3x;      // (-i|+i)*t3 per direction
        sm[cur^1][base]          = make_float2(t0x+t2x, t0y+t2y);
        sm[cur^1][base+Ns]       = make_float2(t1x+rtx, t1y+rty);
        sm[cur^1][base+2*Ns]     = make_float2(t0x-t2x, t0y-t2y);
        sm[cur^1][base+3*Ns]     = make_float2(t1x-rtx, t1y-rty);
      }
      cur ^= 1;
    }
    if (LG & 1){
      const int ls = LG-1, Ns = 1<<ls;
      __syncthreads();
      for (int j=tid; j<N/2; j+=T){
        const int m = j & (Ns-1);
        const int base = ((j>>ls)<<(ls+1)) + m;
        float2 va = sm[cur][j];
        float2 vb = sm[cur][j+N/2];
        float2 w = tw[TWI(m)];
        float wy = ds*w.y;
        float2 bw = make_float2(vb.x*w.x - vb.y*wy, vb.x*wy + vb.y*w.x);
        sm[cur^1][base]    = make_float2(va.x+bw.x, va.y+bw.y);
        sm[cur^1][base+Ns] = make_float2(va.x-bw.x, va.y-bw.y);
      }
      cur ^= 1;
    }
  }
  __syncthreads();

  const float sc = d.scale;
  switch(d.post){
    case 0: {
      float2* dp = d.dst + (size_t)row*N;
      for (int i=tid;i<N;i+=T){ float2 v=sm[cur][i]; dp[i]=make_float2(v.x*sc,v.y*sc); }
    } break;
    case 1: {
      float a1=0.f,a2=0.f;
      for (int i=tid;i<N;i+=T){ float v=sm[cur][i].x*sc; a1+=fabsf(v); a2+=v*v; }
      float vals[2]={a1,a2};
      blockAccumN<2>(d.slots, vals, red);
    } break;
    case 2: {   // store (re, mag)
      float2* dp = d.dst + (size_t)row*N;
      float am=0.f;
      for (int i=tid;i<N;i+=T){
        float2 v=sm[cur][i]; v.x*=sc; v.y*=sc;
        float m = sqrtf(v.x*v.x+v.y*v.y);
        dp[i]=make_float2(v.x, m);
        am += m;
      }
      float vals[1]={am};
      blockAccumN<1>(d.slots, vals, red);
    } break;
    case 3: {
      float2* dp = d.dst + (size_t)row*N;
      float s2=0.f,s3=0.f,s4=0.f;
      for (int i=tid;i<N;i+=T){
        float2 v=sm[cur][i]; v.x*=sc; v.y*=sc; dp[i]=v;
        float x=v.x, x2=x*x; s2+=x2; s3+=x2*x; s4+=x2*x2;
      }
      float vals[3]={s2,s3,s4};
      blockAccumN<3>(d.slots, vals, red);
    } break;
    case 4: {   // parent reduction; aux bands hold (re, mag)
      const float2* B = a.aux;
      constexpr size_t N2 = (size_t)N*N;
      float acc[13];
      #pragma unroll
      for (int k=0;k<13;k++) acc[k]=0.f;
      for (int i=tid;i<N;i+=T){
        float2 p=sm[cur][i]; p.x*=sc; p.y*=sc;
        float m = sqrtf(p.x*p.x+p.y*p.y);
        float rp=0.f, ip=0.f;
        if (m>0.f){ rp=(p.y*p.y-p.x*p.x)/m; ip=2.f*p.x*p.y/m; }
        size_t pos = (size_t)row*N + i;
        acc[0]+=m;
        #pragma unroll
        for (int k=0;k<4;k++){
          float2 z = B[k*N2+pos];
          acc[1+k]+=z.y*m; acc[5+k]+=z.x*rp; acc[9+k]+=z.x*ip;
        }
      }
      blockAccumN<13>(d.slots, acc, red);
    } break;
  }
}

// multi-base in-place batched square transpose
struct TArgs { float2* base[6]; int n; };
__global__ void k_trip(TArgs t){
  int bi = blockIdx.x, bj = blockIdx.y;
  if (bj < bi) return;
  const int n = t.n;
  float2* img = t.base[blockIdx.z];
  __shared__ float2 t0[32][33], t1[32][33];
  int r0=bi*32, c0=bj*32;
  for (int dy=threadIdx.y; dy<32; dy+=8){
    t0[dy][threadIdx.x] = img[(size_t)(r0+dy)*n + c0 + threadIdx.x];
    if (bi!=bj) t1[dy][threadIdx.x] = img[(size_t)(c0+dy)*n + r0 + threadIdx.x];
  }
  __syncthreads();
  for (int dy=threadIdx.y; dy<32; dy+=8){
    img[(size_t)(c0+dy)*n + r0 + threadIdx.x] = t0[threadIdx.x][dy];
    if (bi!=bj) img[(size_t)(r0+dy)*n + c0 + threadIdx.x] = t1[threadIdx.x][dy];
  }
}

// multi-base direct circular autocorrelation (41 unique 9x9 lags)
// z=0..3: band magnitudes (.y), z=4: unor (.x), z=5: fused gram (grid-stride)
struct AArgs { const float2* base[6]; double* slots[6]; int n, lgn, nmag; };
__global__ __launch_bounds__(256) void k_ac(AArgs a){
  __shared__ float t[72][73];
  __shared__ float red[41*4];
  const int z = blockIdx.z;
  const int n = a.n;
  if (z==5){
    const float2* B = a.base[5];
    const size_t n2 = (size_t)n*n;
    float p[20];
    #pragma unroll
    for (int i=0;i<20;i++) p[i]=0.f;
    const size_t nbk = (size_t)gridDim.x*gridDim.y;
    const size_t bid = (size_t)blockIdx.y*gridDim.x + blockIdx.x;
    for (size_t i = bid*256 + threadIdx.x; i<n2; i += nbk*256){
      float2 z0=B[i], z1=B[i+n2], z2=B[i+2*n2], z3=B[i+3*n2];
      float m0=z0.y, m1=z1.y, m2=z2.y, m3=z3.y;
      float r0=z0.x, r1=z1.x, r2=z2.x, r3=z3.x;
      p[0]+=m0*m0; p[1]+=m0*m1; p[2]+=m0*m2; p[3]+=m0*m3;
      p[4]+=m1*m1; p[5]+=m1*m2; p[6]+=m1*m3;
      p[7]+=m2*m2; p[8]+=m2*m3; p[9]+=m3*m3;
      p[10]+=r0*r0; p[11]+=r0*r1; p[12]+=r0*r2; p[13]+=r0*r3;
      p[14]+=r1*r1; p[15]+=r1*r2; p[16]+=r1*r3;
      p[17]+=r2*r2; p[18]+=r2*r3; p[19]+=r3*r3;
    }
    blockAccumN<20>(a.slots[5], p, red);
    return;
  }
  const float2* img = a.base[z];
  const bool mag = z < a.nmag;
  const int lgn = a.lgn;
  const int ty0 = blockIdx.y*64, tx0 = blockIdx.x*64;
  for (int idx = threadIdx.x; idx < 72*72; idx += 256){
    int ly = idx/72, lx = idx-ly*72;
    int gy = (ty0 + ly - 4) & (n-1), gx = (tx0 + lx - 4) & (n-1);
    float2 v = img[((size_t)gy<<lgn) + gx];
    t[ly][lx] = mag ? v.y : v.x;
  }
  __syncthreads();
  float acc[41];
  #pragma unroll
  for (int k=0;k<41;k++) acc[k]=0.f;
  for (int p = threadIdx.x; p < 4096; p += 256){
    int ly = (p>>6) + 4, lx = (p&63) + 4;
    float m0 = t[ly][lx];
    #pragma unroll
    for (int dj=1; dj<=4; dj++)
      #pragma unroll
      for (int di=-4; di<=4; di++)
        acc[(dj-1)*9 + di+4] += m0 * t[ly+di][lx+dj];
    #pragma unroll
    for (int di=0; di<=4; di++)
      acc[36+di] += m0 * t[ly+di][lx];
  }
  blockAccumN<41>(a.slots[z], acc, red);
}

// ---------------- misc kernels ----------------------------------------------
__global__ void k_init(double* S, float* out, int nout){
  int i = blockIdx.x*blockDim.x + threadIdx.x;
  if (i < REP*SL_TOT) S[i]=0.0;
  if (i < nout) out[i]=0.f;
}
__global__ __launch_bounds__(256) void k_imgstats(const float4* __restrict__ x, float* PB){
  float s1=0.f,s2=0.f,s3=0.f,s4=0.f, mn=3.4e38f, mx=-3.4e38f;
  const int base = blockIdx.x*1024 + threadIdx.x;
  #pragma unroll
  for (int it=0; it<4; ++it){
    float4 v = x[base + it*256];
    float vs[4]={v.x,v.y,v.z,v.w};
    #pragma unroll
    for (int k=0;k<4;k++){
      float t=vs[k], t2=t*t;
      s1+=t; s2+=t2; s3+=t2*t; s4+=t2*t2;
      mn=fminf(mn,t); mx=fmaxf(mx,t);
    }
  }
  __shared__ float wr[6][4];
  int lane=threadIdx.x&63, wid=threadIdx.x>>6;
  float sums[4]={s1,s2,s3,s4};
  #pragma unroll
  for (int k=0;k<4;k++){
    float v=sums[k];
    for (int o=32;o>0;o>>=1) v+=__shfl_down(v,o);
    if (lane==0) wr[k][wid]=v;
  }
  { float v=mn; for (int o=32;o>0;o>>=1) v=fminf(v,__shfl_down(v,o)); if(lane==0) wr[4][wid]=v; }
  { float v=mx; for (int o=32;o>0;o>>=1) v=fmaxf(v,__shfl_down(v,o)); if(lane==0) wr[5][wid]=v; }
  __syncthreads();
  if (threadIdx.x<4)  PB[blockIdx.x*8+threadIdx.x] = wr[threadIdx.x][0]+wr[threadIdx.x][1]+wr[threadIdx.x][2]+wr[threadIdx.x][3];
  if (threadIdx.x==4) PB[blockIdx.x*8+4] = fminf(fminf(wr[4][0],wr[4][1]),fminf(wr[4][2],wr[4][3]));
  if (threadIdx.x==5) PB[blockIdx.x*8+5] = fmaxf(fmaxf(wr[5][0],wr[5][1]),fmaxf(wr[5][2],wr[5][3]));
}
__global__ void k_crx3(const float2* __restrict__ RP, const float2* __restrict__ B3, double* S){
  float a[35];
  #pragma unroll
  for (int i=0;i<35;i++) a[i]=0.f;
  int stride = gridDim.x*blockDim.x;
  for (int idx=blockIdx.x*blockDim.x+threadIdx.x; idx<16384; idx+=stride){
    int u=idx>>7, v=idx&127;
    float P0=RP[idx].x;
    float P1=RP[(u<<7) | ((v-1)&127)].x;
    float P2=RP[(u<<7) | ((v+1)&127)].x;
    float P3=RP[(((u-1)&127)<<7) | v].x;
    float P4=RP[(((u+1)&127)<<7) | v].x;
    float P[5]={P0,P1,P2,P3,P4};
    float R[4];
    #pragma unroll
    for (int b=0;b<4;b++) R[b]=B3[b*16384 + (v<<7) + u].x;
    #pragma unroll
    for (int i=0;i<4;i++)
      #pragma unroll
      for (int j=0;j<5;j++) a[i*5+j]+=R[i]*P[j];
    int k=20;
    #pragma unroll
    for (int i=0;i<5;i++)
      #pragma unroll
      for (int j=i;j<5;j++){ a[k]+=P[i]*P[j]; k++; }
  }
  __shared__ float red[35*4];
  float lo[20], hi[15];
  #pragma unroll
  for (int k=0;k<20;k++) lo[k]=a[k];
  #pragma unroll
  for (int k=0;k<15;k++) hi[k]=a[20+k];
  blockAccumN<20>(S+280, lo, red);
  blockAccumN<15>(S+300, hi, red);
}

// in-place unnormalized inverse 2D FFT in LDS, separated planes, stride S
template<int LG>
__device__ void ifft2_lds(float* re, float* im, const float2* tw, int S){
  constexpr int N=1<<LG, H=N>>1;
  const int tid=threadIdx.x, T=256;
  for (int ls=LG-1; ls>=0; --ls){
    const int h=1<<ls;
    __syncthreads();
    for (int t=tid; t<N*H; t+=T){
      int r=t>>(LG-1), j=t&(H-1);
      int m=j&(h-1);
      int i0=r*S + ((j>>ls)<<(ls+1)) + m, i1=i0+h;
      float ar=re[i0], ai=im[i0], br=re[i1], bi=im[i1];
      re[i0]=ar+br; im[i0]=ai+bi;
      float dr=ar-br, di=ai-bi;
      float2 w=tw[m<<(LG-1-ls)];
      re[i1]=dr*w.x - di*w.y;
      im[i1]=dr*w.y + di*w.x;
    }
  }
  __syncthreads();
  for (int t=tid;t<N*N;t+=T){
    int r=t>>LG, j=t&(N-1);
    int jb=(int)(__brev((unsigned)j)>>(32-LG));
    if (j<jb){
      int p=r*S+j, q=r*S+jb;
      float x=re[p]; re[p]=re[q]; re[q]=x;
      x=im[p]; im[p]=im[q]; im[q]=x;
    }
  }
  for (int ls=LG-1; ls>=0; --ls){
    const int h=1<<ls;
    __syncthreads();
    for (int t=tid; t<N*H; t+=T){
      int c=t>>(LG-1), j=t&(H-1);
      int m=j&(h-1);
      int i0=(((j>>ls)<<(ls+1))+m)*S + c, i1=i0+h*S;
      float ar=re[i0], ai=im[i0], br=re[i1], bi=im[i1];
      re[i0]=ar+br; im[i0]=ai+bi;
      float dr=ar-br, di=ai-bi;
      float2 w=tw[m<<(LG-1-ls)];
      re[i1]=dr*w.x - di*w.y;
      im[i1]=dr*w.y + di*w.x;
    }
  }
  __syncthreads();
  for (int t=tid;t<N*N;t+=T){
    int c=t>>LG, j=t&(N-1);
    int jb=(int)(__brev((unsigned)j)>>(32-LG));
    if (j<jb){
      int p=j*S+c, q=jb*S+c;
      float x=re[p]; re[p]=re[q]; re[q]=x;
      x=im[p]; im[p]=im[q]; im[q]=x;
    }
  }
  __syncthreads();
}

// fused 64x64 tail: lowpass (absdev) + imlp (moments + 41-lag AC)
__global__ __launch_bounds__(256) void k_tail64(const float2* __restrict__ F, double* S){
  __shared__ float re[64*65];
  __shared__ float im[64*65];
  __shared__ float2 tw[32];
  __shared__ float red[41*4];
  __shared__ float shmu;
  const int tid=threadIdx.x;
  const float sc=1.f/4096.f;
  for (int k=tid;k<32;k+=256){
    float sn,cs; __sincosf(TWOPI_F*(float)k/64.f,&sn,&cs);
    tw[k]=make_float2(cs,sn);
  }
  // ---- lowpass ----
  for (int t=tid;t<4096;t+=256){
    int a2=t>>6, b=t&63;
    int KR = b + ((b<32)?0:960);
    int KC = a2 + ((a2<32)?0:960);
    float2 v = F[(size_t)KC*1024+KR];
    float m = cumlo(lograd(b,a2,64),4);
    re[a2*65+b]=v.x*m; im[a2*65+b]=v.y*m;
  }
  ifft2_lds<6>(re,im,tw,65);
  {
    int lane=tid&63, wid=tid>>6;
    float s1=0.f;
    for (int t=tid;t<4096;t+=256) s1 += re[(t>>6)*65+(t&63)];
    float v=s1; for (int o=32;o>0;o>>=1) v+=__shfl_down(v,o);
    if (lane==0) red[wid]=v;
    __syncthreads();
    if (tid==0) shmu=(red[0]+red[1]+red[2]+red[3])*(sc*sc);
    __syncthreads();
    float mu=shmu, adc=0.f;
    for (int t=tid;t<4096;t+=256) adc += fabsf(re[(t>>6)*65+(t&63)]*sc - mu);
    v=adc; for (int o=32;o>0;o>>=1) v+=__shfl_down(v,o);
    if (lane==0) red[wid]=v;
    __syncthreads();
    if (tid==0) S[23]=(double)(red[0]+red[1]+red[2]+red[3]);
    __syncthreads();
  }
  // ---- imlp ----
  for (int t=tid;t<4096;t+=256){
    int a2=t>>6, b=t&63;
    int KR = b + ((b<32)?0:960);
    int KC = a2 + ((a2<32)?0:960);
    float2 v = F[(size_t)KC*1024+KR];
    float lr = lograd(b,a2,64);
    float m = cumlo(lr,4)*rc_cos(lr,1.f);
    if (t==0) m=0.f;
    re[a2*65+b]=v.x*m; im[a2*65+b]=v.y*m;
  }
  ifft2_lds<6>(re,im,tw,65);
  {
    float s2=0.f,s3=0.f,s4=0.f;
    float acc[41];
    #pragma unroll
    for (int k=0;k<41;k++) acc[k]=0.f;
    for (int p=tid;p<4096;p+=256){
      int y=p>>6, x=p&63;
      float m0u=re[y*65+x];
      float m0=m0u*sc, m02=m0*m0;
      s2+=m02; s3+=m02*m0; s4+=m02*m02;
      #pragma unroll
      for (int dj=1;dj<=4;dj++)
        #pragma unroll
        for (int di=-4;di<=4;di++)
          acc[(dj-1)*9+di+4] += m0u * re[((y+dj)&63)*65 + ((x+di)&63)];
      #pragma unroll
      for (int di=0;di<=4;di++)
        acc[36+di] += m0u * re[y*65 + ((x+di)&63)];
    }
    #pragma unroll
    for (int k=0;k<41;k++) acc[k]*=sc*sc;
    float mom[3]={s2,s3,s4};
    blockAccumN<3>(S+36, mom, red);
    blockAccumN<41>(S+SL_ALP, acc, red);
  }
}

__global__ __launch_bounds__(256) void k_final(const double* __restrict__ S,
                                               const float* __restrict__ PB, float* out){
  __shared__ double SD[SL_TOT];
  __shared__ double sh[6];
  __shared__ double wrD[4][4];
  __shared__ float  wrF[2][4];
  const int tid = threadIdx.x;
  for (int k=tid;k<SL_TOT;k+=256){
    double v=0.0;
    #pragma unroll
    for (int r=0;r<REP;r++) v += S[(size_t)r*SL_TOT+k];
    SD[k]=v;
  }
  {
    int lane=tid&63, wid=tid>>6;
    double p0=PB[tid*8+0], p1=PB[tid*8+1], p2=PB[tid*8+2], p3=PB[tid*8+3];
    float pn=PB[tid*8+4], px=PB[tid*8+5];
    for (int o=32;o>0;o>>=1){ p0+=__shfl_down(p0,o); p1+=__shfl_down(p1,o); p2+=__shfl_down(p2,o); p3+=__shfl_down(p3,o); }
    if (lane==0){ wrD[0][wid]=p0; wrD[1][wid]=p1; wrD[2][wid]=p2; wrD[3][wid]=p3; }
    { float v=pn; for (int o=32;o>0;o>>=1) v=fminf(v,__shfl_down(v,o)); if(lane==0) wrF[0][wid]=v; }
    { float v=px; for (int o=32;o>0;o>>=1) v=fmaxf(v,__shfl_down(v,o)); if(lane==0) wrF[1][wid]=v; }
    __syncthreads();
    if (tid==0){
      for (int k=0;k<4;k++) sh[k]=wrD[k][0]+wrD[k][1]+wrD[k][2]+wrD[k][3];
      sh[4]=(double)fminf(fminf(wrF[0][0],wrF[0][1]),fminf(wrF[0][2],wrF[0][3]));
      sh[5]=(double)fmaxf(fmaxf(wrF[1][0],wrF[1][1]),fmaxf(wrF[1][2],wrF[1][3]));
    }
    __syncthreads();
  }
  const double npix[4]={1048576.0,262144.0,65536.0,16384.0};
  for (int e=tid; e<81*16; e+=256){
    int w=e>>4, s=(e>>2)&3, b=e&3;
    int i=w/9, j=w-i*9;
    int k=lagIdx(i-4,j-4);
    double n2=npix[s];
    double mu=SD[6+s*4+b]/n2;
    out[24+(w*4+s)*4+b]=(float)(SD[SL_ACE+(s*4+b)*41+k]/n2 - mu*mu);
  }
  for (int e=tid; e<81*4; e+=256){
    int w=e>>2, s=e&3;
    int i=w/9, j=w-i*9;
    int k=lagIdx(i-4,j-4);
    out[1330+w*5+s]=(float)(SD[SL_ACR+s*41+k]/(2.0*npix[s]));
  }
  for (int w=tid; w<81; w+=256){
    int i=w/9, j=w-i*9;
    int k=lagIdx(i-4,j-4);
    out[1330+w*5+4]=(float)(SD[SL_ALP+k]/4096.0);
  }
  for (int e=tid; e<64; e+=256){
    int s=e>>4, i=(e>>2)&3, j=e&3;
    int a2=i<j?i:j, bb=i<j?j:i;
    int p=a2*(7-a2)/2+bb;
    double n2=npix[s];
    double Si=SD[6+s*4+i], Sj=SD[6+s*4+j];
    out[1735+(i*4+j)*5+s]=(float)((SD[40+s*20+p]-Si*Sj/n2)/n2);
    out[1879+(i*8+j)*5+s]=(float)(SD[40+s*20+10+p]/n2);
  }
  for (int e=tid; e<48; e+=256){
    int s=e>>4, j=(e>>2)&3, i=e&3;
    double n2=npix[s];
    int pb=120+(s*4+j)*13;
    double Smj=SD[pb];
    double Si=SD[6+s*4+i];
    out[1815+(i*4+j)*4+s]=(float)((SD[pb+1+i]-Si*Smj/n2)/n2);
    out[2199+(i*8+j)*4+s]=(float)(SD[pb+5+i]/n2);
    out[2199+(i*8+(j+4))*4+s]=(float)(SD[pb+9+i]/n2);
  }
  for (int e=tid; e<20; e+=256){
    int i=e/5, j=e%5;
    out[2199+(i*8+j)*4+3]=(float)(SD[280+i*5+j]/16384.0);
  }
  for (int e=tid; e<25; e+=256){
    int i=e/5, j=e%5;
    int a2=i<j?i:j, bb=i<j?j:i;
    int p=a2*(9-a2)/2+bb;
    out[1879+(i*8+j)*5+4]=(float)(SD[300+p]/4096.0);
  }
  if (tid==0){
    const double N0=1048576.0;
    double sum=sh[0], s2=sh[1], s3=sh[2], s4=sh[3];
    double mean0=sum/N0;
    double var0=(s2 - sum*mean0)/(N0-1.0);
    double m3 = s3 - 3.0*mean0*s2 + 2.0*N0*mean0*mean0*mean0;
    double m4 = s4 - 4.0*mean0*s3 + 6.0*mean0*mean0*s2 - 3.0*N0*mean0*mean0*mean0*mean0;
    out[0]=(float)mean0; out[1]=(float)var0;
    out[2]=(float)((m3/N0)/(var0*sqrt(var0)));
    out[3]=(float)((m4/N0)/(var0*var0));
    out[4]=(float)sh[4]; out[5]=(float)sh[5];
    out[6]=(float)(SD[4]/N0);
    for (int s=0;s<4;s++) for (int b=0;b<4;b++) out[7+s*4+b]=(float)(SD[6+s*4+b]/npix[s]);
    out[23]=(float)(SD[23]/4096.0);
    for (int s=0;s<4;s++){
      double n2=npix[s];
      double vari=SD[24+s*3]/(2.0*n2);
      int ok=(vari/var0>1e-6);
      out[1320+s]= ok? (float)(0.5*(SD[25+s*3]/n2)/(vari*sqrt(vari))) : 0.f;
      out[1325+s]= ok? (float)(0.5*(SD[26+s*3]/n2)/(vari*vari)) : 3.f;
    }
    { double vari=SD[36]/4096.0; int ok=(vari/var0>1e-6);
      out[1324]= ok? (float)((SD[37]/4096.0)/(vari*sqrt(vari))) : 0.f;
      out[1329]= ok? (float)((SD[38]/4096.0)/(vari*vari)) : 3.f; }
    out[2455]=(float)(SD[5]/N0);
  }
}

// ---------------- host orchestration -----------------------------------------
static void launchB(int n, int nimg, const BArgs& a, hipStream_t st){
  switch(n){
    case 1024: k_fftB<1024><<<dim3(1024,nimg),fftT(1024),0,st>>>(a); break;
    case 512:  k_fftB<512 ><<<dim3(512 ,nimg),fftT(512 ),0,st>>>(a); break;
    case 256:  k_fftB<256 ><<<dim3(256 ,nimg),fftT(256 ),0,st>>>(a); break;
    case 128:  k_fftB<128 ><<<dim3(128 ,nimg),fftT(128 ),0,st>>>(a); break;
  }
}

extern "C" void kernel_launch(void* const* d_in, const int* in_sizes, int n_in,
                              void* d_out, int out_size, void* d_ws, size_t ws_size,
                              hipStream_t stream){
  const float* im = (const float*)d_in[0];
  float* out = (float*)d_out;
  char* w = (char*)d_ws;
  float2* F   = (float2*)w;                         // 8 MB: imdft^T
  float2* CA4 = (float2*)(w + ((size_t)8<<20));     // 32 MB: 4 bands
  float2* CC  = (float2*)(w + ((size_t)40<<20));    // 8 MB: unor
  float2* CB4 = (float2*)(w + ((size_t)48<<20));    // 16 MB: hi0 / parents / rp
  size_t off = (size_t)64<<20;
  double* S = (double*)(w+off);
  float* PB = (float*)(w+off+(size_t)REP*SL_TOT*8);

  k_init<<<40,256,0,stream>>>(S,out,2456);
  k_imgstats<<<256,256,0,stream>>>((const float4*)im,PB);

  // forward fft2 -> F^T
  { BArgs a{}; a.rsrc=im; a.dirsign=-1.f;
    a.img[0]=ImgD{nullptr,F,nullptr,1,0,0,0,1.f};
    launchB(1024,1,a,stream); }
  { TArgs t{}; t.base[0]=F; t.n=1024;
    k_trip<<<dim3(32,32,1),dim3(32,8),0,stream>>>(t); }
  { BArgs a{}; a.dirsign=-1.f;
    a.img[0]=ImgD{F,F,nullptr,0,0,0,0,1.f};
    launchB(1024,1,a,stream); }

  for (int s=0;s<4;s++){
    const int n=1024>>s, nt=n/32, n2=n*n, lg=10-s;
    const float inv=1.f/(float)n;
    const int nimg = (s==0)? 6 : 5;
    // pass1: bands + unor (+ hi0 at s=0)
    { BArgs a{}; a.F=F; a.dirsign=1.f;
      for (int b=0;b<4;b++) a.img[b]=ImgD{nullptr,CA4+(size_t)b*n2,nullptr,2,0,b,s,inv};
      a.img[4]=ImgD{nullptr,CC,nullptr,3,0,0,s,inv};
      if (s==0) a.img[5]=ImgD{nullptr,CB4,nullptr,4,0,0,0,inv};
      launchB(n,nimg,a,stream); }
    { TArgs t{}; t.n=n;
      for (int b=0;b<4;b++) t.base[b]=CA4+(size_t)b*n2;
      t.base[4]=CC; if (s==0) t.base[5]=CB4;
      k_trip<<<dim3(nt,nt,nimg),dim3(32,8),0,stream>>>(t); }
    { BArgs a{}; a.dirsign=1.f;
      for (int b=0;b<4;b++) a.img[b]=ImgD{CA4+(size_t)b*n2,CA4+(size_t)b*n2,S+6+s*4+b,0,2,0,0,inv};
      a.img[4]=ImgD{CC,CC,S+24+s*3,0,3,0,0,inv};
      if (s==0) a.img[5]=ImgD{CB4,nullptr,S+4,0,1,0,0,inv};
      launchB(n,nimg,a,stream); }
    // autocorr (bands z=0..3, unor z=4) + fused gram (z=5)
    { AArgs aa{}; aa.n=n; aa.lgn=lg; aa.nmag=4;
      for (int b=0;b<4;b++){ aa.base[b]=CA4+(size_t)b*n2; aa.slots[b]=S+SL_ACE+(size_t)(s*4+b)*41; }
      aa.base[4]=CC; aa.slots[4]=S+SL_ACR+(size_t)s*41;
      aa.base[5]=CA4; aa.slots[5]=S+40+(size_t)s*20;
      k_ac<<<dim3(n/64,n/64,6),256,0,stream>>>(aa); }
    if (s<3){
      const int nb = (s==0)? 2 : 4;
      for (int b0=0;b0<4;b0+=nb){
        { BArgs a{}; a.F=F; a.dirsign=1.f;
          for (int i=0;i<nb;i++) a.img[i]=ImgD{nullptr,CB4+(size_t)i*n2,nullptr,5,0,b0+i,s,inv};
          launchB(n,nb,a,stream); }
        { TArgs t{}; t.n=n;
          for (int i=0;i<nb;i++) t.base[i]=CB4+(size_t)i*n2;
          k_trip<<<dim3(nt,nt,nb),dim3(32,8),0,stream>>>(t); }
        { BArgs a{}; a.dirsign=1.f; a.aux=CA4;
          for (int i=0;i<nb;i++) a.img[i]=ImgD{CB4+(size_t)i*n2,nullptr,S+120+(size_t)(s*4+b0+i)*13,0,4,0,0,inv};
          launchB(n,nb,a,stream); }
      }
    } else {
      k_tail64<<<1,256,0,stream>>>(F,S);
      { BArgs a{}; a.F=F; a.dirsign=1.f;
        a.img[0]=ImgD{nullptr,CB4,nullptr,6,0,0,4,1.f/128.f};
        launchB(128,1,a,stream); }
      { TArgs t{}; t.base[0]=CB4; t.n=128;
        k_trip<<<dim3(4,4,1),dim3(32,8),0,stream>>>(t); }
      { BArgs a{}; a.dirsign=1.f;
        a.img[0]=ImgD{CB4,CB4,nullptr,0,0,0,0,1.f/128.f};
        launchB(128,1,a,stream); }
      k_crx3<<<64,256,0,stream>>>(CB4,CA4,S);
    }
  }
  k_final<<<1,256,0,stream>>>(S,PB,out);
  (void)in_sizes; (void)n_in; (void)out_size; (void)ws_size;
}

// Round 14
// 456.894 us; speedup vs baseline: 1.2049x; 1.0041x over previous
//
#include <hip/hip_runtime.h>

#define PI_F     3.14159265358979323846f
#define TWOPI_F  6.28318530717958647692f
#define HPI_F    1.57079632679489661923f

constexpr int fftT(int N){ return N>=512 ? 256 : (N/2 < 64 ? 64 : N/2); }

// S-slot layout (doubles), replicated REP times (replica stride SL_TOT)
#define SL_ACE 340          // 16 x 41
#define SL_ACR 996          // 4 x 41
#define SL_ALP 1160         // 41
#define SL_TOT 1280
#define REP 8

__device__ __forceinline__ float fcoord(int k, int n){
  int s = k ^ (n>>1);
  return (float)(s - (n>>1)) / (float)(n>>1);
}
__device__ __forceinline__ float lograd(int kr, int kc, int n){
  if (kr==0 && kc==0) return log2f(2.0f/(float)n);
  float x = fcoord(kc,n), y = fcoord(kr,n);
  return 0.5f*log2f(x*x+y*y);
}
__device__ __forceinline__ float rc_sin(float lr, float shift){
  float t = fminf(fmaxf(lr+shift,0.f),1.f); return __sinf(HPI_F*t);
}
__device__ __forceinline__ float rc_cos(float lr, float shift){
  float t = fminf(fmaxf(lr+shift,0.f),1.f); return __cosf(HPI_F*t);
}
// cumulative lowpass mask to reach scale s: prod_{m=0..s} rc_cos(lr, 1-m)
__device__ __forceinline__ float cumlo(float lr, int s){
  float cl = rc_cos(lr, 1.f);
  for (int m=1;m<=s;m++) cl *= rc_cos(lr, 1.f-(float)m);
  return cl;
}
// oriented factor via cos-addition: cos(ang - b*pi/4) = (x*cb + y*sb)/r.
// |wrap(th)|<pi/2  <=>  cos(th)>0.  K = 2*sqrt(0.8).
__device__ __forceinline__ float bandang2(float x, float y, float cb, float sb){
  float r2 = x*x + y*y;
  float c = (r2>0.f) ? (x*cb + y*sb)*rsqrtf(r2) : cb;
  return (c>0.f) ? (1.7888543819998317f*c*c*c) : 0.f;
}
__device__ __forceinline__ int lagIdx(int di, int dj){
  if (dj < 0 || (dj==0 && di<0)){ di=-di; dj=-dj; }
  return dj==0 ? 36+di : (dj-1)*9 + (di+4);
}
__device__ __forceinline__ void atomAddD(double* p, double v){
  unsafeAtomicAdd(p, v);
}
template<int NS>
__device__ __forceinline__ void blockAccumN(double* base, const float* vals, float* red){
  const int lane = threadIdx.x & 63, wid = threadIdx.x >> 6;
  const int nw = (int)(blockDim.x >> 6);
  #pragma unroll
  for (int k=0;k<NS;k++){
    float v = vals[k];
    #pragma unroll
    for (int o=32;o>0;o>>=1) v += __shfl_down(v,o);
    if (lane==0) red[k*nw+wid]=v;
  }
  __syncthreads();
  const int rep = (int)((blockIdx.x ^ (blockIdx.y<<1) ^ (blockIdx.z<<2)) & 7) * SL_TOT;
  if ((int)threadIdx.x < NS){
    float s=0.f;
    for (int w2=0;w2<nw;w2++) s += red[(int)threadIdx.x*nw+w2];
    atomAddD(base+rep+(int)threadIdx.x,(double)s);
  }
  __syncthreads();
}

// ---------------- batched descriptor FFT -------------------------------------
// pre: 0 cplx slab, 1 real row, 2 band from F, 3 him from F, 4 hi0 from F,
//      5 padband from F, 6 padlp from F
// post: 0 store, 1 sum|x|,x^2, 2 store(re,mag)+summag, 3 store+moments, 4 parentred
struct ImgD { const float2* src; float2* dst; double* slots; int pre, post, b, ss; float scale; };
struct BArgs { ImgD img[6]; const float* rsrc; const float2* F; const float2* aux; float dirsign; };

#define TWI(k) ((k)+((k)>>4))

template<int N>
__global__ __launch_bounds__(fftT(N)) void k_fftB(BArgs a){
  constexpr int T = fftT(N);
  constexpr int LG = (N==1024)?10:(N==512)?9:(N==256)?8:(N==128)?7:6;
  __shared__ float2 sm[2][N];
  __shared__ float2 tw[N/2 + N/32];
  __shared__ float red[13*4];
  const ImgD d = a.img[blockIdx.y];
  const int row = blockIdx.x, tid = threadIdx.x;
  bool zrow=false;

  for (int k=tid;k<N/2;k+=T){
    float sn,cs; __sincosf(TWOPI_F*(float)k/(float)N,&sn,&cs);
    tw[TWI(k)]=make_float2(cs,sn);
  }

  switch(d.pre){
    case 0: {
      const float2* sp = d.src + (size_t)row*N;
      for (int i=tid;i<N;i+=T) sm[0][i]=sp[i];
    } break;
    case 1: {
      const float* rp = a.rsrc + (size_t)row*N;
      for (int i=tid;i<N;i+=T) sm[0][i]=make_float2(rp[i],0.f);
    } break;
    case 2: {
      const int KC = row + ((row < N/2)? 0 : (1024-N));
      const float2* Fr = a.F + (size_t)KC*1024;
      float sbv, cbv; __sincosf(0.25f*PI_F*(float)d.b, &sbv, &cbv);
      const float yv = fcoord(row,N);
      for (int i=tid;i<N;i+=T){
        int KR = i + ((i < N/2)? 0 : (1024-N));
        float2 v = Fr[KR];
        float lr = lograd(i,row,N);
        float xv = fcoord(i,N);
        float m = cumlo(lr,d.ss)*rc_sin(lr,2.f)*bandang2(yv,xv,cbv,sbv);
        sm[0][i]=make_float2(-v.y*m, v.x*m);   // (-1j)^3 = +i
      }
    } break;
    case 3: {
      const int KC = row + ((row < N/2)? 0 : (1024-N));
      const float2* Fr = a.F + (size_t)KC*1024;
      for (int i=tid;i<N;i+=T){
        int KR = i + ((i < N/2)? 0 : (1024-N));
        float2 v = Fr[KR];
        float lr = lograd(i,row,N);
        float m = cumlo(lr,d.ss)*rc_sin(lr,2.f);
        sm[0][i]=make_float2(v.x*m, v.y*m);
      }
    } break;
    case 4: {
      const float2* Fr = a.F + (size_t)row*1024;
      for (int i=tid;i<N;i+=T){
        float2 v = Fr[i];
        float m = rc_sin(lograd(i,row,N),1.f);
        sm[0][i]=make_float2(v.x*m, v.y*m);
      }
    } break;
    case 5: case 6: {
      constexpr int M=N/2, Q=N/4;
      const int fi = (row<Q)? row : (row>=N-Q ? row-M : -1);
      if (fi<0){
        for (int i=tid;i<N;i+=T) sm[0][i]=make_float2(0.f,0.f);
        zrow=true;
      } else {
        const int KC = fi + ((fi < M/2)? 0 : (1024-M));
        const float2* Fr = a.F + (size_t)KC*1024;
        float sbv, cbv; __sincosf(0.25f*PI_F*(float)d.b, &sbv, &cbv);
        const float yv = fcoord(fi,M);
        for (int i=tid;i<N;i+=T){
          int fj = (i<Q)? i : (i>=N-Q ? i-M : -1);
          float2 r = make_float2(0.f,0.f);
          if (fj>=0){
            int KR = fj + ((fj < M/2)? 0 : (1024-M));
            float2 v = Fr[KR];
            float lr = lograd(fj,fi,M);
            if (d.pre==5){
              float xv = fcoord(fj,M);
              float m = cumlo(lr,d.ss+1)*rc_sin(lr,2.f)*bandang2(yv,xv,cbv,sbv);
              r = make_float2(-v.y*m, v.x*m);
            } else {
              if (!(fi==0 && fj==0)){
                float m = cumlo(lr,4);
                r = make_float2(v.x*m, v.y*m);
              }
            }
          }
          sm[0][i]=r;
        }
      }
    } break;
  }

  int cur=0;
  if (!zrow){
    const float ds = a.dirsign;
    int ls2 = 0;
    // radix-4 stages
    for (; ls2+2<=LG; ls2+=2){
      const int Ns = 1<<ls2;
      __syncthreads();
      for (int j=tid; j<N/4; j+=T){
        const int m = j & (Ns-1);
        const int base = ((j>>ls2)<<(ls2+2)) + m;
        float2 x0 = sm[cur][j];
        float2 x1 = sm[cur][j+N/4];
        float2 x2 = sm[cur][j+N/2];
        float2 x3 = sm[cur][j+3*(N/4)];
        float2 w = tw[TWI(m<<(LG-2-ls2))];
        float w1x=w.x, w1y=ds*w.y;
        float w2x = w1x*w1x - w1y*w1y, w2y = 2.f*w1x*w1y;
        float w3x = w2x*w1x - w2y*w1y, w3y = w2x*w1y + w2y*w1x;
        float2 b = make_float2(x1.x*w1x - x1.y*w1y, x1.x*w1y + x1.y*w1x);
        float2 c = make_float2(x2.x*w2x - x2.y*w2y, x2.x*w2y + x2.y*w2x);
        float2 e = make_float2(x3.x*w3x - x3.y*w3y, x3.x*w3y + x3.y*w3x);
        float t0x=x0.x+c.x, t0y=x0.y+c.y;
        float t1x=x0.x-c.x, t1y=x0.y-c.y;
        float t2x=b.x+e.x,  t2y=b.y+e.y;
        float t3x=b.x-e.x,  t3y=b.y-e.y;
        float rtx=-ds*t3y,  rty=ds*t3x;      // (-i|+i)*t3 per direction
        sm[cur^1][base]          = make_float2(t0x+t2x, t0y+t2y);
        sm[cur^1][base+Ns]       = make_float2(t1x+rtx, t1y+rty);
        sm[cur^1][base+2*Ns]     = make_float2(t0x-t2x, t0y-t2y);
        sm[cur^1][base+3*Ns]     = make_float2(t1x-rtx, t1y-rty);
      }
      cur ^= 1;
    }
    if (LG & 1){
      const int ls = LG-1, Ns = 1<<ls;
      __syncthreads();
      for (int j=tid; j<N/2; j+=T){
        const int m = j & (Ns-1);
        const int base = ((j>>ls)<<(ls+1)) + m;
        float2 va = sm[cur][j];
        float2 vb = sm[cur][j+N/2];
        float2 w = tw[TWI(m)];
        float wy = ds*w.y;
        float2 bw = make_float2(vb.x*w.x - vb.y*wy, vb.x*wy + vb.y*w.x);
        sm[cur^1][base]    = make_float2(va.x+bw.x, va.y+bw.y);
        sm[cur^1][base+Ns] = make_float2(va.x-bw.x, va.y-bw.y);
      }
      cur ^= 1;
    }
  }
  __syncthreads();

  const float sc = d.scale;
  switch(d.post){
    case 0: {
      float2* dp = d.dst + (size_t)row*N;
      for (int i=tid;i<N;i+=T){ float2 v=sm[cur][i]; dp[i]=make_float2(v.x*sc,v.y*sc); }
    } break;
    case 1: {
      float a1=0.f,a2=0.f;
      for (int i=tid;i<N;i+=T){ float v=sm[cur][i].x*sc; a1+=fabsf(v); a2+=v*v; }
      float vals[2]={a1,a2};
      blockAccumN<2>(d.slots, vals, red);
    } break;
    case 2: {   // store (re, mag)
      float2* dp = d.dst + (size_t)row*N;
      float am=0.f;
      for (int i=tid;i<N;i+=T){
        float2 v=sm[cur][i]; v.x*=sc; v.y*=sc;
        float m = sqrtf(v.x*v.x+v.y*v.y);
        dp[i]=make_float2(v.x, m);
        am += m;
      }
      float vals[1]={am};
      blockAccumN<1>(d.slots, vals, red);
    } break;
    case 3: {
      float2* dp = d.dst + (size_t)row*N;
      float s2=0.f,s3=0.f,s4=0.f;
      for (int i=tid;i<N;i+=T){
        float2 v=sm[cur][i]; v.x*=sc; v.y*=sc; dp[i]=v;
        float x=v.x, x2=x*x; s2+=x2; s3+=x2*x; s4+=x2*x2;
      }
      float vals[3]={s2,s3,s4};
      blockAccumN<3>(d.slots, vals, red);
    } break;
    case 4: {   // parent reduction; aux bands hold (re, mag)
      const float2* B = a.aux;
      constexpr size_t N2 = (size_t)N*N;
      float acc[13];
      #pragma unroll
      for (int k=0;k<13;k++) acc[k]=0.f;
      for (int i=tid;i<N;i+=T){
        float2 p=sm[cur][i]; p.x*=sc; p.y*=sc;
        float m = sqrtf(p.x*p.x+p.y*p.y);
        float rp=0.f, ip=0.f;
        if (m>0.f){ rp=(p.y*p.y-p.x*p.x)/m; ip=2.f*p.x*p.y/m; }
        size_t pos = (size_t)row*N + i;
        acc[0]+=m;
        #pragma unroll
        for (int k=0;k<4;k++){
          float2 z = B[k*N2+pos];
          acc[1+k]+=z.y*m; acc[5+k]+=z.x*rp; acc[9+k]+=z.x*ip;
        }
      }
      blockAccumN<13>(d.slots, acc, red);
    } break;
  }
}

// multi-base in-place batched square transpose
struct TArgs { float2* base[6]; int n; };
__global__ void k_trip(TArgs t){
  int bi = blockIdx.x, bj = blockIdx.y;
  if (bj < bi) return;
  const int n = t.n;
  float2* img = t.base[blockIdx.z];
  __shared__ float2 t0[32][33], t1[32][33];
  int r0=bi*32, c0=bj*32;
  for (int dy=threadIdx.y; dy<32; dy+=8){
    t0[dy][threadIdx.x] = img[(size_t)(r0+dy)*n + c0 + threadIdx.x];
    if (bi!=bj) t1[dy][threadIdx.x] = img[(size_t)(c0+dy)*n + r0 + threadIdx.x];
  }
  __syncthreads();
  for (int dy=threadIdx.y; dy<32; dy+=8){
    img[(size_t)(c0+dy)*n + r0 + threadIdx.x] = t0[threadIdx.x][dy];
    if (bi!=bj) img[(size_t)(r0+dy)*n + c0 + threadIdx.x] = t1[threadIdx.x][dy];
  }
}

// multi-base direct circular autocorrelation (41 unique 9x9 lags)
// z=0..3: band magnitudes (.y), z=4: unor (.x), z=5: fused gram (grid-stride)
struct AArgs { const float2* base[6]; double* slots[6]; int n, lgn, nmag; };
__global__ __launch_bounds__(256) void k_ac(AArgs a){
  __shared__ float t[72][73];
  __shared__ float red[41*4];
  const int z = blockIdx.z;
  const int n = a.n;
  if (z==5){
    const float2* B = a.base[5];
    const size_t n2 = (size_t)n*n;
    float p[20];
    #pragma unroll
    for (int i=0;i<20;i++) p[i]=0.f;
    const size_t nbk = (size_t)gridDim.x*gridDim.y;
    const size_t bid = (size_t)blockIdx.y*gridDim.x + blockIdx.x;
    for (size_t i = bid*256 + threadIdx.x; i<n2; i += nbk*256){
      float2 z0=B[i], z1=B[i+n2], z2=B[i+2*n2], z3=B[i+3*n2];
      float m0=z0.y, m1=z1.y, m2=z2.y, m3=z3.y;
      float r0=z0.x, r1=z1.x, r2=z2.x, r3=z3.x;
      p[0]+=m0*m0; p[1]+=m0*m1; p[2]+=m0*m2; p[3]+=m0*m3;
      p[4]+=m1*m1; p[5]+=m1*m2; p[6]+=m1*m3;
      p[7]+=m2*m2; p[8]+=m2*m3; p[9]+=m3*m3;
      p[10]+=r0*r0; p[11]+=r0*r1; p[12]+=r0*r2; p[13]+=r0*r3;
      p[14]+=r1*r1; p[15]+=r1*r2; p[16]+=r1*r3;
      p[17]+=r2*r2; p[18]+=r2*r3; p[19]+=r3*r3;
    }
    blockAccumN<20>(a.slots[5], p, red);
    return;
  }
  const float2* img = a.base[z];
  const bool mag = z < a.nmag;
  const int lgn = a.lgn;
  const int ty0 = blockIdx.y*64, tx0 = blockIdx.x*64;
  for (int idx = threadIdx.x; idx < 72*72; idx += 256){
    int ly = idx/72, lx = idx-ly*72;
    int gy = (ty0 + ly - 4) & (n-1), gx = (tx0 + lx - 4) & (n-1);
    float2 v = img[((size_t)gy<<lgn) + gx];
    t[ly][lx] = mag ? v.y : v.x;
  }
  __syncthreads();
  float acc[41];
  #pragma unroll
  for (int k=0;k<41;k++) acc[k]=0.f;
  for (int p = threadIdx.x; p < 4096; p += 256){
    int ly = (p>>6) + 4, lx = (p&63) + 4;
    float m0 = t[ly][lx];
    #pragma unroll
    for (int dj=1; dj<=4; dj++)
      #pragma unroll
      for (int di=-4; di<=4; di++)
        acc[(dj-1)*9 + di+4] += m0 * t[ly+di][lx+dj];
    #pragma unroll
    for (int di=0; di<=4; di++)
      acc[36+di] += m0 * t[ly+di][lx];
  }
  blockAccumN<41>(a.slots[z], acc, red);
}

// ---------------- misc kernels ----------------------------------------------
__global__ void k_init(double* S, float* out, int nout){
  int i = blockIdx.x*blockDim.x + threadIdx.x;
  if (i < REP*SL_TOT) S[i]=0.0;
  if (i < nout) out[i]=0.f;
}
__global__ __launch_bounds__(256) void k_imgstats(const float4* __restrict__ x, float* PB){
  float s1=0.f,s2=0.f,s3=0.f,s4=0.f, mn=3.4e38f, mx=-3.4e38f;
  const int base = blockIdx.x*1024 + threadIdx.x;
  #pragma unroll
  for (int it=0; it<4; ++it){
    float4 v = x[base + it*256];
    float vs[4]={v.x,v.y,v.z,v.w};
    #pragma unroll
    for (int k=0;k<4;k++){
      float t=vs[k], t2=t*t;
      s1+=t; s2+=t2; s3+=t2*t; s4+=t2*t2;
      mn=fminf(mn,t); mx=fmaxf(mx,t);
    }
  }
  __shared__ float wr[6][4];
  int lane=threadIdx.x&63, wid=threadIdx.x>>6;
  float sums[4]={s1,s2,s3,s4};
  #pragma unroll
  for (int k=0;k<4;k++){
    float v=sums[k];
    for (int o=32;o>0;o>>=1) v+=__shfl_down(v,o);
    if (lane==0) wr[k][wid]=v;
  }
  { float v=mn; for (int o=32;o>0;o>>=1) v=fminf(v,__shfl_down(v,o)); if(lane==0) wr[4][wid]=v; }
  { float v=mx; for (int o=32;o>0;o>>=1) v=fmaxf(v,__shfl_down(v,o)); if(lane==0) wr[5][wid]=v; }
  __syncthreads();
  if (threadIdx.x<4)  PB[blockIdx.x*8+threadIdx.x] = wr[threadIdx.x][0]+wr[threadIdx.x][1]+wr[threadIdx.x][2]+wr[threadIdx.x][3];
  if (threadIdx.x==4) PB[blockIdx.x*8+4] = fminf(fminf(wr[4][0],wr[4][1]),fminf(wr[4][2],wr[4][3]));
  if (threadIdx.x==5) PB[blockIdx.x*8+5] = fmaxf(fmaxf(wr[5][0],wr[5][1]),fmaxf(wr[5][2],wr[5][3]));
}
__global__ void k_crx3(const float2* __restrict__ RP, const float2* __restrict__ B3, double* S){
  float a[35];
  #pragma unroll
  for (int i=0;i<35;i++) a[i]=0.f;
  int stride = gridDim.x*blockDim.x;
  for (int idx=blockIdx.x*blockDim.x+threadIdx.x; idx<16384; idx+=stride){
    int u=idx>>7, v=idx&127;
    float P0=RP[idx].x;
    float P1=RP[(u<<7) | ((v-1)&127)].x;
    float P2=RP[(u<<7) | ((v+1)&127)].x;
    float P3=RP[(((u-1)&127)<<7) | v].x;
    float P4=RP[(((u+1)&127)<<7) | v].x;
    float P[5]={P0,P1,P2,P3,P4};
    float R[4];
    #pragma unroll
    for (int b=0;b<4;b++) R[b]=B3[b*16384 + (v<<7) + u].x;
    #pragma unroll
    for (int i=0;i<4;i++)
      #pragma unroll
      for (int j=0;j<5;j++) a[i*5+j]+=R[i]*P[j];
    int k=20;
    #pragma unroll
    for (int i=0;i<5;i++)
      #pragma unroll
      for (int j=i;j<5;j++){ a[k]+=P[i]*P[j]; k++; }
  }
  __shared__ float red[35*4];
  float lo[20], hi[15];
  #pragma unroll
  for (int k=0;k<20;k++) lo[k]=a[k];
  #pragma unroll
  for (int k=0;k<15;k++) hi[k]=a[20+k];
  blockAccumN<20>(S+280, lo, red);
  blockAccumN<15>(S+300, hi, red);
}

// in-place unnormalized inverse 2D FFT in LDS, separated planes, stride S
template<int LG>
__device__ void ifft2_lds(float* re, float* im, const float2* tw, int S){
  constexpr int N=1<<LG, H=N>>1;
  const int tid=threadIdx.x, T=256;
  for (int ls=LG-1; ls>=0; --ls){
    const int h=1<<ls;
    __syncthreads();
    for (int t=tid; t<N*H; t+=T){
      int r=t>>(LG-1), j=t&(H-1);
      int m=j&(h-1);
      int i0=r*S + ((j>>ls)<<(ls+1)) + m, i1=i0+h;
      float ar=re[i0], ai=im[i0], br=re[i1], bi=im[i1];
      re[i0]=ar+br; im[i0]=ai+bi;
      float dr=ar-br, di=ai-bi;
      float2 w=tw[m<<(LG-1-ls)];
      re[i1]=dr*w.x - di*w.y;
      im[i1]=dr*w.y + di*w.x;
    }
  }
  __syncthreads();
  for (int t=tid;t<N*N;t+=T){
    int r=t>>LG, j=t&(N-1);
    int jb=(int)(__brev((unsigned)j)>>(32-LG));
    if (j<jb){
      int p=r*S+j, q=r*S+jb;
      float x=re[p]; re[p]=re[q]; re[q]=x;
      x=im[p]; im[p]=im[q]; im[q]=x;
    }
  }
  for (int ls=LG-1; ls>=0; --ls){
    const int h=1<<ls;
    __syncthreads();
    for (int t=tid; t<N*H; t+=T){
      int c=t>>(LG-1), j=t&(H-1);
      int m=j&(h-1);
      int i0=(((j>>ls)<<(ls+1))+m)*S + c, i1=i0+h*S;
      float ar=re[i0], ai=im[i0], br=re[i1], bi=im[i1];
      re[i0]=ar+br; im[i0]=ai+bi;
      float dr=ar-br, di=ai-bi;
      float2 w=tw[m<<(LG-1-ls)];
      re[i1]=dr*w.x - di*w.y;
      im[i1]=dr*w.y + di*w.x;
    }
  }
  __syncthreads();
  for (int t=tid;t<N*N;t+=T){
    int c=t>>LG, j=t&(N-1);
    int jb=(int)(__brev((unsigned)j)>>(32-LG));
    if (j<jb){
      int p=j*S+c, q=jb*S+c;
      float x=re[p]; re[p]=re[q]; re[q]=x;
      x=im[p]; im[p]=im[q]; im[q]=x;
    }
  }
  __syncthreads();
}

// fused 64x64 tail: lowpass (absdev) + imlp (moments + 41-lag AC)
__global__ __launch_bounds__(256) void k_tail64(const float2* __restrict__ F, double* S){
  __shared__ float re[64*65];
  __shared__ float im[64*65];
  __shared__ float2 tw[32];
  __shared__ float red[41*4];
  __shared__ float shmu;
  const int tid=threadIdx.x;
  const float sc=1.f/4096.f;
  for (int k=tid;k<32;k+=256){
    float sn,cs; __sincosf(TWOPI_F*(float)k/64.f,&sn,&cs);
    tw[k]=make_float2(cs,sn);
  }
  // ---- lowpass ----
  for (int t=tid;t<4096;t+=256){
    int a2=t>>6, b=t&63;
    int KR = b + ((b<32)?0:960);
    int KC = a2 + ((a2<32)?0:960);
    float2 v = F[(size_t)KC*1024+KR];
    float m = cumlo(lograd(b,a2,64),4);
    re[a2*65+b]=v.x*m; im[a2*65+b]=v.y*m;
  }
  ifft2_lds<6>(re,im,tw,65);
  {
    int lane=tid&63, wid=tid>>6;
    float s1=0.f;
    for (int t=tid;t<4096;t+=256) s1 += re[(t>>6)*65+(t&63)];
    float v=s1; for (int o=32;o>0;o>>=1) v+=__shfl_down(v,o);
    if (lane==0) red[wid]=v;
    __syncthreads();
    if (tid==0) shmu=(red[0]+red[1]+red[2]+red[3])*(sc*sc);
    __syncthreads();
    float mu=shmu, adc=0.f;
    for (int t=tid;t<4096;t+=256) adc += fabsf(re[(t>>6)*65+(t&63)]*sc - mu);
    v=adc; for (int o=32;o>0;o>>=1) v+=__shfl_down(v,o);
    if (lane==0) red[wid]=v;
    __syncthreads();
    if (tid==0) S[23]=(double)(red[0]+red[1]+red[2]+red[3]);
    __syncthreads();
  }
  // ---- imlp ----
  for (int t=tid;t<4096;t+=256){
    int a2=t>>6, b=t&63;
    int KR = b + ((b<32)?0:960);
    int KC = a2 + ((a2<32)?0:960);
    float2 v = F[(size_t)KC*1024+KR];
    float lr = lograd(b,a2,64);
    float m = cumlo(lr,4)*rc_cos(lr,1.f);
    if (t==0) m=0.f;
    re[a2*65+b]=v.x*m; im[a2*65+b]=v.y*m;
  }
  ifft2_lds<6>(re,im,tw,65);
  {
    float s2=0.f,s3=0.f,s4=0.f;
    float acc[41];
    #pragma unroll
    for (int k=0;k<41;k++) acc[k]=0.f;
    for (int p=tid;p<4096;p+=256){
      int y=p>>6, x=p&63;
      float m0u=re[y*65+x];
      float m0=m0u*sc, m02=m0*m0;
      s2+=m02; s3+=m02*m0; s4+=m02*m02;
      #pragma unroll
      for (int dj=1;dj<=4;dj++)
        #pragma unroll
        for (int di=-4;di<=4;di++)
          acc[(dj-1)*9+di+4] += m0u * re[((y+dj)&63)*65 + ((x+di)&63)];
      #pragma unroll
      for (int di=0;di<=4;di++)
        acc[36+di] += m0u * re[y*65 + ((x+di)&63)];
    }
    #pragma unroll
    for (int k=0;k<41;k++) acc[k]*=sc*sc;
    float mom[3]={s2,s3,s4};
    blockAccumN<3>(S+36, mom, red);
    blockAccumN<41>(S+SL_ALP, acc, red);
  }
}

__global__ __launch_bounds__(256) void k_final(const double* __restrict__ S,
                                               const float* __restrict__ PB, float* out){
  __shared__ double SD[SL_TOT];
  __shared__ double sh[6];
  __shared__ double wrD[4][4];
  __shared__ float  wrF[2][4];
  const int tid = threadIdx.x;
  for (int k=tid;k<SL_TOT;k+=256){
    double v=0.0;
    #pragma unroll
    for (int r=0;r<REP;r++) v += S[(size_t)r*SL_TOT+k];
    SD[k]=v;
  }
  {
    int lane=tid&63, wid=tid>>6;
    double p0=PB[tid*8+0], p1=PB[tid*8+1], p2=PB[tid*8+2], p3=PB[tid*8+3];
    float pn=PB[tid*8+4], px=PB[tid*8+5];
    for (int o=32;o>0;o>>=1){ p0+=__shfl_down(p0,o); p1+=__shfl_down(p1,o); p2+=__shfl_down(p2,o); p3+=__shfl_down(p3,o); }
    if (lane==0){ wrD[0][wid]=p0; wrD[1][wid]=p1; wrD[2][wid]=p2; wrD[3][wid]=p3; }
    { float v=pn; for (int o=32;o>0;o>>=1) v=fminf(v,__shfl_down(v,o)); if(lane==0) wrF[0][wid]=v; }
    { float v=px; for (int o=32;o>0;o>>=1) v=fmaxf(v,__shfl_down(v,o)); if(lane==0) wrF[1][wid]=v; }
    __syncthreads();
    if (tid==0){
      for (int k=0;k<4;k++) sh[k]=wrD[k][0]+wrD[k][1]+wrD[k][2]+wrD[k][3];
      sh[4]=(double)fminf(fminf(wrF[0][0],wrF[0][1]),fminf(wrF[0][2],wrF[0][3]));
      sh[5]=(double)fmaxf(fmaxf(wrF[1][0],wrF[1][1]),fmaxf(wrF[1][2],wrF[1][3]));
    }
    __syncthreads();
  }
  const double npix[4]={1048576.0,262144.0,65536.0,16384.0};
  for (int e=tid; e<81*16; e+=256){
    int w=e>>4, s=(e>>2)&3, b=e&3;
    int i=w/9, j=w-i*9;
    int k=lagIdx(i-4,j-4);
    double n2=npix[s];
    double mu=SD[6+s*4+b]/n2;
    out[24+(w*4+s)*4+b]=(float)(SD[SL_ACE+(s*4+b)*41+k]/n2 - mu*mu);
  }
  for (int e=tid; e<81*4; e+=256){
    int w=e>>2, s=e&3;
    int i=w/9, j=w-i*9;
    int k=lagIdx(i-4,j-4);
    out[1330+w*5+s]=(float)(SD[SL_ACR+s*41+k]/(2.0*npix[s]));
  }
  for (int w=tid; w<81; w+=256){
    int i=w/9, j=w-i*9;
    int k=lagIdx(i-4,j-4);
    out[1330+w*5+4]=(float)(SD[SL_ALP+k]/4096.0);
  }
  for (int e=tid; e<64; e+=256){
    int s=e>>4, i=(e>>2)&3, j=e&3;
    int a2=i<j?i:j, bb=i<j?j:i;
    int p=a2*(7-a2)/2+bb;
    double n2=npix[s];
    double Si=SD[6+s*4+i], Sj=SD[6+s*4+j];
    out[1735+(i*4+j)*5+s]=(float)((SD[40+s*20+p]-Si*Sj/n2)/n2);
    out[1879+(i*8+j)*5+s]=(float)(SD[40+s*20+10+p]/n2);
  }
  for (int e=tid; e<48; e+=256){
    int s=e>>4, j=(e>>2)&3, i=e&3;
    double n2=npix[s];
    int pb=120+(s*4+j)*13;
    double Smj=SD[pb];
    double Si=SD[6+s*4+i];
    out[1815+(i*4+j)*4+s]=(float)((SD[pb+1+i]-Si*Smj/n2)/n2);
    out[2199+(i*8+j)*4+s]=(float)(SD[pb+5+i]/n2);
    out[2199+(i*8+(j+4))*4+s]=(float)(SD[pb+9+i]/n2);
  }
  for (int e=tid; e<20; e+=256){
    int i=e/5, j=e%5;
    out[2199+(i*8+j)*4+3]=(float)(SD[280+i*5+j]/16384.0);
  }
  for (int e=tid; e<25; e+=256){
    int i=e/5, j=e%5;
    int a2=i<j?i:j, bb=i<j?j:i;
    int p=a2*(9-a2)/2+bb;
    out[1879+(i*8+j)*5+4]=(float)(SD[300+p]/4096.0);
  }
  if (tid==0){
    const double N0=1048576.0;
    double sum=sh[0], s2=sh[1], s3=sh[2], s4=sh[3];
    double mean0=sum/N0;
    double var0=(s2 - sum*mean0)/(N0-1.0);
    double m3 = s3 - 3.0*mean0*s2 + 2.0*N0*mean0*mean0*mean0;
    double m4 = s4 - 4.0*mean0*s3 + 6.0*mean0*mean0*s2 - 3.0*N0*mean0*mean0*mean0*mean0;
    out[0]=(float)mean0; out[1]=(float)var0;
    out[2]=(float)((m3/N0)/(var0*sqrt(var0)));
    out[3]=(float)((m4/N0)/(var0*var0));
    out[4]=(float)sh[4]; out[5]=(float)sh[5];
    out[6]=(float)(SD[4]/N0);
    for (int s=0;s<4;s++) for (int b=0;b<4;b++) out[7+s*4+b]=(float)(SD[6+s*4+b]/npix[s]);
    out[23]=(float)(SD[23]/4096.0);
    for (int s=0;s<4;s++){
      double n2=npix[s];
      double vari=SD[24+s*3]/(2.0*n2);
      int ok=(vari/var0>1e-6);
      out[1320+s]= ok? (float)(0.5*(SD[25+s*3]/n2)/(vari*sqrt(vari))) : 0.f;
      out[1325+s]= ok? (float)(0.5*(SD[26+s*3]/n2)/(vari*vari)) : 3.f;
    }
    { double vari=SD[36]/4096.0; int ok=(vari/var0>1e-6);
      out[1324]= ok? (float)((SD[37]/4096.0)/(vari*sqrt(vari))) : 0.f;
      out[1329]= ok? (float)((SD[38]/4096.0)/(vari*vari)) : 3.f; }
    out[2455]=(float)(SD[5]/N0);
  }
}

// ---------------- host orchestration -----------------------------------------
static void launchB(int n, int nimg, const BArgs& a, hipStream_t st){
  switch(n){
    case 1024: k_fftB<1024><<<dim3(1024,nimg),fftT(1024),0,st>>>(a); break;
    case 512:  k_fftB<512 ><<<dim3(512 ,nimg),fftT(512 ),0,st>>>(a); break;
    case 256:  k_fftB<256 ><<<dim3(256 ,nimg),fftT(256 ),0,st>>>(a); break;
    case 128:  k_fftB<128 ><<<dim3(128 ,nimg),fftT(128 ),0,st>>>(a); break;
  }
}

extern "C" void kernel_launch(void* const* d_in, const int* in_sizes, int n_in,
                              void* d_out, int out_size, void* d_ws, size_t ws_size,
                              hipStream_t stream){
  const float* im = (const float*)d_in[0];
  float* out = (float*)d_out;
  char* w = (char*)d_ws;
  float2* F   = (float2*)w;                         // 8 MB: imdft^T
  float2* CA4 = (float2*)(w + ((size_t)8<<20));     // 32 MB: 4 bands
  float2* CC  = (float2*)(w + ((size_t)40<<20));    // 8 MB: unor
  float2* CB4 = (float2*)(w + ((size_t)48<<20));    // 16 MB: hi0 / parents / rp
  size_t off = (size_t)64<<20;
  double* S = (double*)(w+off);
  float* PB = (float*)(w+off+(size_t)REP*SL_TOT*8);

  k_init<<<40,256,0,stream>>>(S,out,2456);
  k_imgstats<<<256,256,0,stream>>>((const float4*)im,PB);

  // forward fft2 -> F^T
  { BArgs a{}; a.rsrc=im; a.dirsign=-1.f;
    a.img[0]=ImgD{nullptr,F,nullptr,1,0,0,0,1.f};
    launchB(1024,1,a,stream); }
  { TArgs t{}; t.base[0]=F; t.n=1024;
    k_trip<<<dim3(32,32,1),dim3(32,8),0,stream>>>(t); }
  { BArgs a{}; a.dirsign=-1.f;
    a.img[0]=ImgD{F,F,nullptr,0,0,0,0,1.f};
    launchB(1024,1,a,stream); }

  for (int s=0;s<4;s++){
    const int n=1024>>s, nt=n/32, n2=n*n, lg=10-s;
    const float inv=1.f/(float)n;
    const int nimg = (s==0)? 6 : 5;
    // pass1: bands + unor (+ hi0 at s=0)
    { BArgs a{}; a.F=F; a.dirsign=1.f;
      for (int b=0;b<4;b++) a.img[b]=ImgD{nullptr,CA4+(size_t)b*n2,nullptr,2,0,b,s,inv};
      a.img[4]=ImgD{nullptr,CC,nullptr,3,0,0,s,inv};
      if (s==0) a.img[5]=ImgD{nullptr,CB4,nullptr,4,0,0,0,inv};
      launchB(n,nimg,a,stream); }
    { TArgs t{}; t.n=n;
      for (int b=0;b<4;b++) t.base[b]=CA4+(size_t)b*n2;
      t.base[4]=CC; if (s==0) t.base[5]=CB4;
      k_trip<<<dim3(nt,nt,nimg),dim3(32,8),0,stream>>>(t); }
    { BArgs a{}; a.dirsign=1.f;
      for (int b=0;b<4;b++) a.img[b]=ImgD{CA4+(size_t)b*n2,CA4+(size_t)b*n2,S+6+s*4+b,0,2,0,0,inv};
      a.img[4]=ImgD{CC,CC,S+24+s*3,0,3,0,0,inv};
      if (s==0) a.img[5]=ImgD{CB4,nullptr,S+4,0,1,0,0,inv};
      launchB(n,nimg,a,stream); }
    // autocorr (bands z=0..3, unor z=4) + fused gram (z=5)
    { AArgs aa{}; aa.n=n; aa.lgn=lg; aa.nmag=4;
      for (int b=0;b<4;b++){ aa.base[b]=CA4+(size_t)b*n2; aa.slots[b]=S+SL_ACE+(size_t)(s*4+b)*41; }
      aa.base[4]=CC; aa.slots[4]=S+SL_ACR+(size_t)s*41;
      aa.base[5]=CA4; aa.slots[5]=S+40+(size_t)s*20;
      k_ac<<<dim3(n/64,n/64,6),256,0,stream>>>(aa); }
    if (s<3){
      const int nb = (s==0)? 2 : 4;
      for (int b0=0;b0<4;b0+=nb){
        { BArgs a{}; a.F=F; a.dirsign=1.f;
          for (int i=0;i<nb;i++) a.img[i]=ImgD{nullptr,CB4+(size_t)i*n2,nullptr,5,0,b0+i,s,inv};
          launchB(n,nb,a,stream); }
        { TArgs t{}; t.n=n;
          for (int i=0;i<nb;i++) t.base[i]=CB4+(size_t)i*n2;
          k_trip<<<dim3(nt,nt,nb),dim3(32,8),0,stream>>>(t); }
        { BArgs a{}; a.dirsign=1.f; a.aux=CA4;
          for (int i=0;i<nb;i++) a.img[i]=ImgD{CB4+(size_t)i*n2,nullptr,S+120+(size_t)(s*4+b0+i)*13,0,4,0,0,inv};
          launchB(n,nb,a,stream); }
      }
    } else {
      k_tail64<<<1,256,0,stream>>>(F,S);
      { BArgs a{}; a.F=F; a.dirsign=1.f;
        a.img[0]=ImgD{nullptr,CB4,nullptr,6,0,0,4,1.f/128.f};
        launchB(128,1,a,stream); }
      { TArgs t{}; t.base[0]=CB4; t.n=128;
        k_trip<<<dim3(4,4,1),dim3(32,8),0,stream>>>(t); }
      { BArgs a{}; a.dirsign=1.f;
        a.img[0]=ImgD{CB4,CB4,nullptr,0,0,0,0,1.f/128.f};
        launchB(128,1,a,stream); }
      k_crx3<<<64,256,0,stream>>>(CB4,CA4,S);
    }
  }
  k_final<<<1,256,0,stream>>>(S,PB,out);
  (void)in_sizes; (void)n_in; (void)out_size; (void)ws_size;
}